// Round 1
// baseline (1440.169 us; speedup 1.0000x reference)
//
#include <hip/hip_runtime.h>
#include <math.h>
#include <float.h>

#define B_ 32
#define N_ 4097
#define C_ 256
#define F_ 2049
#define N2_ 241
#define INV_SQRT_N 0.0156230927f      // 1/sqrt(4097)
#define W_N 0.0015336063f             // 2*pi/4097
#define W_17 0.36959913571644626f     // 2*pi/17

__device__ __forceinline__ float bf2f(unsigned short u) {
    return __uint_as_float(((unsigned)u) << 16);
}
__device__ __forceinline__ unsigned short f2bf(float v) {
    unsigned u = __float_as_uint(v);
    u += 0x7FFFu + ((u >> 16) & 1u);
    return (unsigned short)(u >> 16);
}

// ---------------------------------------------------------------------------
// Stage A: 17-point real DFTs.  x[B][N][C] f32 -> y planes [B][17][241][C] f32
// planes 0..8 = Re y[k1], planes 9..16 = Im y[k1] (k1=1..8).  1/sqrt(N) folded.
// y lives in d_out (exactly the same size: 17*241 == 4097).
// ---------------------------------------------------------------------------
__global__ __launch_bounds__(256) void k_stageA(const float* __restrict__ x,
                                                float* __restrict__ y) {
    int bid = blockIdx.x;                 // B*61
    int b = bid / 61, n2q = bid % 61;
    int tid = threadIdx.x;
    int cq = tid & 63, sub = tid >> 6;
    int n2 = n2q * 4 + sub;
    if (n2 >= N2_) return;
    int c = cq * 4;

    float C17[17], S17[17];
#pragma unroll
    for (int r = 0; r < 17; ++r) {
        float s, cth; sincosf(W_17 * (float)r, &s, &cth);
        C17[r] = cth; S17[r] = s;
    }

    float4 accr[9], acci[9];
#pragma unroll
    for (int k = 0; k < 9; ++k) {
        accr[k] = make_float4(0.f, 0.f, 0.f, 0.f);
        acci[k] = make_float4(0.f, 0.f, 0.f, 0.f);
    }

    const float* xb = x + (size_t)b * N_ * C_ + c;
#pragma unroll
    for (int n1 = 0; n1 < 17; ++n1) {
        float4 xv = *(const float4*)(xb + (size_t)(n1 * N2_ + n2) * C_);
#pragma unroll
        for (int k1 = 0; k1 < 9; ++k1) {
            int r = (k1 * n1) % 17;       // compile-time after unroll
            float cc = C17[r], ss = S17[r];
            accr[k1].x += xv.x * cc; accr[k1].y += xv.y * cc;
            accr[k1].z += xv.z * cc; accr[k1].w += xv.w * cc;
            if (k1 > 0) {
                acci[k1].x += xv.x * ss; acci[k1].y += xv.y * ss;
                acci[k1].z += xv.z * ss; acci[k1].w += xv.w * ss;
            }
        }
    }

    float* yb = y + ((size_t)(b * 17) * N2_ + n2) * C_ + c;
#pragma unroll
    for (int k1 = 0; k1 < 9; ++k1) {
        float4 o;
        o.x = accr[k1].x * INV_SQRT_N; o.y = accr[k1].y * INV_SQRT_N;
        o.z = accr[k1].z * INV_SQRT_N; o.w = accr[k1].w * INV_SQRT_N;
        *(float4*)(yb + (size_t)k1 * N2_ * C_) = o;
    }
#pragma unroll
    for (int k1 = 1; k1 < 9; ++k1) {      // Im = -(1/sqrtN) * sum x*sin
        float4 o;
        o.x = -acci[k1].x * INV_SQRT_N; o.y = -acci[k1].y * INV_SQRT_N;
        o.z = -acci[k1].z * INV_SQRT_N; o.w = -acci[k1].w * INV_SQRT_N;
        *(float4*)(yb + (size_t)(8 + k1) * N2_ * C_) = o;
    }
}

// ---------------------------------------------------------------------------
// Stage B: 241-point DFT with fused twiddle.  For f = k1 + 17*t <= 2048:
//   X[f] = sum_n2 y_eff[k1,n2] * e^{-2pi i f n2 / N},  y_eff = conj for k1>8.
// Writes X bf16 [B][F][2][C]; also energy[b][f] from f32 accumulators.
// grid: B*17*4 (t-tiles of 32). block: 64 c-quads x 4 t-groups.
// ---------------------------------------------------------------------------
__global__ __launch_bounds__(256) void k_stageB(const float* __restrict__ y,
                                                unsigned short* __restrict__ X,
                                                float* __restrict__ energy) {
    int bid = blockIdx.x;
    int b = bid / 68;
    int rem = bid % 68;
    int k1 = rem >> 2;
    int tt = rem & 3;
    int tid = threadIdx.x;
    int cq = tid & 63, tg = tid >> 6;
    int c = cq * 4;
    int t0 = tt * 32 + tg * 8;

    int j = (k1 <= 8) ? k1 : 17 - k1;
    float sgn = (k1 <= 8) ? 1.0f : -1.0f;
    bool has_i = (j != 0);

    const float* yrp = y + ((size_t)(b * 17 + j) * N2_) * C_ + c;
    const float* yip = y + ((size_t)(b * 17 + 8 + j) * N2_) * C_ + c;

    float4 ar[8], ai[8];
#pragma unroll
    for (int t8 = 0; t8 < 8; ++t8) {
        ar[t8] = make_float4(0.f, 0.f, 0.f, 0.f);
        ai[t8] = make_float4(0.f, 0.f, 0.f, 0.f);
    }

    __shared__ float twc[8][32], tws[8][32];

    for (int k2b = 0; k2b < N2_; k2b += 8) {
        int bk = (N2_ - k2b < 8) ? (N2_ - k2b) : 8;
        __syncthreads();
        if (tid < bk * 32) {
            int kk = tid >> 5, tcol = tid & 31;
            int t = tt * 32 + tcol;
            int f = k1 + 17 * t;
            int rr = (f * (k2b + kk)) % N_;
            float s, cth; sincosf(W_N * (float)rr, &s, &cth);
            twc[kk][tcol] = cth; tws[kk][tcol] = s;
        }
        __syncthreads();
        for (int kk = 0; kk < bk; ++kk) {
            int n2 = k2b + kk;
            float4 ur = *(const float4*)(yrp + (size_t)n2 * C_);
            float4 ui;
            if (has_i) {
                ui = *(const float4*)(yip + (size_t)n2 * C_);
                ui.x *= sgn; ui.y *= sgn; ui.z *= sgn; ui.w *= sgn;
            } else {
                ui = make_float4(0.f, 0.f, 0.f, 0.f);
            }
#pragma unroll
            for (int t8 = 0; t8 < 8; ++t8) {
                float cc = twc[kk][tg * 8 + t8];
                float ss = tws[kk][tg * 8 + t8];
                // X += (ur + i*ui) * (cc - i*ss)
                ar[t8].x += ur.x * cc + ui.x * ss;
                ar[t8].y += ur.y * cc + ui.y * ss;
                ar[t8].z += ur.z * cc + ui.z * ss;
                ar[t8].w += ur.w * cc + ui.w * ss;
                ai[t8].x += ui.x * cc - ur.x * ss;
                ai[t8].y += ui.y * cc - ur.y * ss;
                ai[t8].z += ui.z * cc - ur.z * ss;
                ai[t8].w += ui.w * cc - ur.w * ss;
            }
        }
    }

#pragma unroll
    for (int t8 = 0; t8 < 8; ++t8) {
        int t = t0 + t8;
        int f = k1 + 17 * t;
        float e = ar[t8].x * ar[t8].x + ar[t8].y * ar[t8].y +
                  ar[t8].z * ar[t8].z + ar[t8].w * ar[t8].w +
                  ai[t8].x * ai[t8].x + ai[t8].y * ai[t8].y +
                  ai[t8].z * ai[t8].z + ai[t8].w * ai[t8].w;
#pragma unroll
        for (int off = 32; off > 0; off >>= 1) e += __shfl_xor(e, off, 64);
        if (f < F_) {
            if (cq == 0) energy[b * F_ + f] = e;
            size_t base = ((size_t)(b * F_ + f) * 2) * C_ + c;
            ushort4 pr, pi;
            pr.x = f2bf(ar[t8].x); pr.y = f2bf(ar[t8].y);
            pr.z = f2bf(ar[t8].z); pr.w = f2bf(ar[t8].w);
            pi.x = f2bf(ai[t8].x); pi.y = f2bf(ai[t8].y);
            pi.z = f2bf(ai[t8].z); pi.w = f2bf(ai[t8].w);
            *(ushort4*)(X + base) = pr;
            *(ushort4*)(X + base + C_) = pi;
        }
    }
}

// ---------------------------------------------------------------------------
// Median per batch: bitonic sort 2049 energies (padded to 4096), take [1024].
// ---------------------------------------------------------------------------
__global__ __launch_bounds__(256) void k_median(const float* __restrict__ energy,
                                                float* __restrict__ med) {
    __shared__ float buf[4096];
    int b = blockIdx.x;
    int tid = threadIdx.x;
    for (int i = tid; i < 4096; i += 256)
        buf[i] = (i < F_) ? energy[b * F_ + i] : FLT_MAX;
    __syncthreads();
    for (int k = 2; k <= 4096; k <<= 1) {
        for (int jj = k >> 1; jj > 0; jj >>= 1) {
            for (int i = tid; i < 4096; i += 256) {
                int ixj = i ^ jj;
                if (ixj > i) {
                    float a = buf[i], bv = buf[ixj];
                    bool up = ((i & k) == 0);
                    if (up ? (a > bv) : (a < bv)) { buf[i] = bv; buf[ixj] = a; }
                }
            }
            __syncthreads();
        }
    }
    if (tid == 0) med[b] = buf[1024];   // 1025th smallest of 2049 (np exact middle)
}

// ---------------------------------------------------------------------------
// v-builder: mask + weights + inverse inner 17-point stage.
//   Z[f] = X[f]*(w + m*wh) * (f==0?1:2)/sqrt(N)
//   v[k2,m2] = sum_s Z[k2+241 s] * e^{+2pi i s m2/17}
// grid B*241, one thread per channel c.
// ---------------------------------------------------------------------------
__global__ __launch_bounds__(256) void k_vbuild(const unsigned short* __restrict__ X,
                                                const float* __restrict__ energy,
                                                const float* __restrict__ med,
                                                const float* __restrict__ thr,
                                                const float* __restrict__ cw,
                                                const float* __restrict__ cwh,
                                                unsigned short* __restrict__ v) {
    int bid = blockIdx.x;
    int b = bid / N2_;
    int k2 = bid % N2_;
    int c = threadIdx.x;

    float wr = cw[2 * c], wi = cw[2 * c + 1];
    float whr = cwh[2 * c], whi = cwh[2 * c + 1];
    float denom = med[b] + 1e-6f;

    float C17[17], S17[17];
#pragma unroll
    for (int r = 0; r < 17; ++r) {
        float s, cth; sincosf(W_17 * (float)r, &s, &cth);
        C17[r] = cth; S17[r] = s;
    }

    float vr[17], vi[17];
#pragma unroll
    for (int m = 0; m < 17; ++m) { vr[m] = 0.f; vi[m] = 0.f; }

#pragma unroll
    for (int s = 0; s < 9; ++s) {
        int f = k2 + 241 * s;
        if (f < F_) {
            float e = energy[b * F_ + f];
            float m = (e / denom > thr[f]) ? 1.0f : 0.0f;
            float wer = wr + m * whr, wei = wi + m * whi;
            float cf = ((f == 0) ? 1.0f : 2.0f) * INV_SQRT_N;
            const unsigned short* Xrow = X + ((size_t)(b * F_ + f) * 2) * C_;
            float Xr = bf2f(Xrow[c]), Xi = bf2f(Xrow[C_ + c]);
            float Zr = (Xr * wer - Xi * wei) * cf;
            float Zi = (Xr * wei + Xi * wer) * cf;
#pragma unroll
            for (int m2 = 0; m2 < 17; ++m2) {
                int r = (s * m2) % 17;    // compile-time after unroll
                vr[m2] += Zr * C17[r] - Zi * S17[r];
                vi[m2] += Zr * S17[r] + Zi * C17[r];
            }
        }
    }
#pragma unroll
    for (int m2 = 0; m2 < 17; ++m2) {
        size_t base = (((size_t)(b * 17 + m2) * N2_ + k2) * 2) * C_ + c;
        v[base] = f2bf(vr[m2]);
        v[base + C_] = f2bf(vi[m2]);
    }
}

// ---------------------------------------------------------------------------
// Stage C: inverse outer 241-point stage, real output.
//   out[17 m1 + m2] = sum_k2 vr*cos(2pi k2 n/N) - vi*sin(2pi k2 n/N)
// grid: B*17*4 (m1-tiles of 64). block: 64 c-quads x 4 m1-groups of 16.
// ---------------------------------------------------------------------------
__global__ __launch_bounds__(256) void k_stageC(const unsigned short* __restrict__ v,
                                                float* __restrict__ out) {
    int bid = blockIdx.x;
    int b = bid / 68;
    int rem = bid % 68;
    int m2 = rem >> 2;
    int mt = rem & 3;
    int tid = threadIdx.x;
    int cq = tid & 63, g = tid >> 6;
    int c = cq * 4;
    int m1base = mt * 64 + g * 16;

    float4 acc[16];
#pragma unroll
    for (int j2 = 0; j2 < 16; ++j2) acc[j2] = make_float4(0.f, 0.f, 0.f, 0.f);

    __shared__ float twc[8][64], tws[8][64];
    const unsigned short* vb = v + ((size_t)(b * 17 + m2) * N2_ * 2) * C_ + c;

    for (int k2b = 0; k2b < N2_; k2b += 8) {
        int bk = (N2_ - k2b < 8) ? (N2_ - k2b) : 8;
        __syncthreads();
#pragma unroll
        for (int q = 0; q < 2; ++q) {
            int idx = tid * 2 + q;
            if (idx < bk * 64) {
                int kk = idx >> 6, mm = idx & 63;
                int m1 = mt * 64 + mm;
                int n = 17 * m1 + m2;
                int rr = ((k2b + kk) * n) % N_;
                float s, cth; sincosf(W_N * (float)rr, &s, &cth);
                twc[kk][mm] = cth; tws[kk][mm] = s;
            }
        }
        __syncthreads();
        for (int kk = 0; kk < bk; ++kk) {
            int k2 = k2b + kk;
            ushort4 pr = *(const ushort4*)(vb + (size_t)(k2 * 2) * C_);
            ushort4 pi = *(const ushort4*)(vb + (size_t)(k2 * 2 + 1) * C_);
            float vr0 = bf2f(pr.x), vr1 = bf2f(pr.y), vr2 = bf2f(pr.z), vr3 = bf2f(pr.w);
            float vi0 = bf2f(pi.x), vi1 = bf2f(pi.y), vi2 = bf2f(pi.z), vi3 = bf2f(pi.w);
#pragma unroll
            for (int j2 = 0; j2 < 16; ++j2) {
                float cc = twc[kk][g * 16 + j2];
                float ss = tws[kk][g * 16 + j2];
                acc[j2].x += vr0 * cc - vi0 * ss;
                acc[j2].y += vr1 * cc - vi1 * ss;
                acc[j2].z += vr2 * cc - vi2 * ss;
                acc[j2].w += vr3 * cc - vi3 * ss;
            }
        }
    }

#pragma unroll
    for (int j2 = 0; j2 < 16; ++j2) {
        int m1 = m1base + j2;
        if (m1 < N2_) {
            int n = 17 * m1 + m2;
            *(float4*)(out + ((size_t)b * N_ + n) * C_ + c) = acc[j2];
        }
    }
}

// ---------------------------------------------------------------------------
extern "C" void kernel_launch(void* const* d_in, const int* in_sizes, int n_in,
                              void* d_out, int out_size, void* d_ws, size_t ws_size,
                              hipStream_t stream) {
    const float* x   = (const float*)d_in[0];
    const float* cw  = (const float*)d_in[1];
    const float* cwh = (const float*)d_in[2];
    const float* thr = (const float*)d_in[3];
    float* out = (float*)d_out;

    // workspace layout (total ~201.7 MB):
    //   X  bf16 [B][F][2][C]      : 67,141,632 B
    //   v  bf16 [B][17][241][2][C]: 134,250,496 B
    //   energy f32 [B][F]         : 262,272 B
    //   med    f32 [B]            : 128 B
    char* ws = (char*)d_ws;
    unsigned short* Xb = (unsigned short*)ws;
    unsigned short* vb = (unsigned short*)(ws + 67141632ull);
    float* energy = (float*)(ws + 67141632ull + 134250496ull);
    float* med = (float*)(ws + 67141632ull + 134250496ull + 262272ull);

    // y (f32, 17 planes) lives in d_out; dead before k_stageC writes out.
    k_stageA<<<B_ * 61, 256, 0, stream>>>(x, out);
    k_stageB<<<B_ * 68, 256, 0, stream>>>(out, Xb, energy);
    k_median<<<B_, 256, 0, stream>>>(energy, med);
    k_vbuild<<<B_ * N2_, 256, 0, stream>>>(Xb, energy, med, thr, cw, cwh, vb);
    k_stageC<<<B_ * 68, 256, 0, stream>>>(vb, out);
}

// Round 2
// 1093.657 us; speedup vs baseline: 1.3168x; 1.3168x over previous
//
#include <hip/hip_runtime.h>
#include <math.h>
#include <float.h>

#define B_ 32
#define N_ 4097
#define C_ 256
#define F_ 2049
#define N2_ 241
#define VSTRIDE 488                   // q-stride of v_t (bf16 elems), 16B-aligned rows
#define TWROWS 4352                   // 4097 rounded up to cover m1-tail (17*255+16), zero-padded
#define INV_SQRT_N 0.0156230927f      // 1/sqrt(4097)
#define W_N 0.0015336063f             // 2*pi/4097
#define W_17 0.36959913571644626f     // 2*pi/17

typedef __attribute__((ext_vector_type(8))) short short8v;
typedef __attribute__((ext_vector_type(4))) float f32x4;

__device__ __forceinline__ float bf2f(unsigned short u) {
    return __uint_as_float(((unsigned)u) << 16);
}
__device__ __forceinline__ unsigned short f2bf(float v) {
    unsigned u = __float_as_uint(v);
    u += 0x7FFFu + ((u >> 16) & 1u);
    return (unsigned short)(u >> 16);
}

// ---------------------------------------------------------------------------
// Stage A: 17-point real DFTs.  x[B][N][C] f32 -> y planes [B][17][241][C] f32
// planes 0..8 = Re y[k1], planes 9..16 = Im y[k1] (k1=1..8).  1/sqrt(N) folded.
// y lives in d_out (exactly the same size: 17*241 == 4097).
// ---------------------------------------------------------------------------
__global__ __launch_bounds__(256) void k_stageA(const float* __restrict__ x,
                                                float* __restrict__ y) {
    int bid = blockIdx.x;                 // B*61
    int b = bid / 61, n2q = bid % 61;
    int tid = threadIdx.x;
    int cq = tid & 63, sub = tid >> 6;
    int n2 = n2q * 4 + sub;
    if (n2 >= N2_) return;
    int c = cq * 4;

    float C17[17], S17[17];
#pragma unroll
    for (int r = 0; r < 17; ++r) {
        float s, cth; sincosf(W_17 * (float)r, &s, &cth);
        C17[r] = cth; S17[r] = s;
    }

    float4 accr[9], acci[9];
#pragma unroll
    for (int k = 0; k < 9; ++k) {
        accr[k] = make_float4(0.f, 0.f, 0.f, 0.f);
        acci[k] = make_float4(0.f, 0.f, 0.f, 0.f);
    }

    const float* xb = x + (size_t)b * N_ * C_ + c;
#pragma unroll
    for (int n1 = 0; n1 < 17; ++n1) {
        float4 xv = *(const float4*)(xb + (size_t)(n1 * N2_ + n2) * C_);
#pragma unroll
        for (int k1 = 0; k1 < 9; ++k1) {
            int r = (k1 * n1) % 17;       // compile-time after unroll
            float cc = C17[r], ss = S17[r];
            accr[k1].x += xv.x * cc; accr[k1].y += xv.y * cc;
            accr[k1].z += xv.z * cc; accr[k1].w += xv.w * cc;
            if (k1 > 0) {
                acci[k1].x += xv.x * ss; acci[k1].y += xv.y * ss;
                acci[k1].z += xv.z * ss; acci[k1].w += xv.w * ss;
            }
        }
    }

    float* yb = y + ((size_t)(b * 17) * N2_ + n2) * C_ + c;
#pragma unroll
    for (int k1 = 0; k1 < 9; ++k1) {
        float4 o;
        o.x = accr[k1].x * INV_SQRT_N; o.y = accr[k1].y * INV_SQRT_N;
        o.z = accr[k1].z * INV_SQRT_N; o.w = accr[k1].w * INV_SQRT_N;
        *(float4*)(yb + (size_t)k1 * N2_ * C_) = o;
    }
#pragma unroll
    for (int k1 = 1; k1 < 9; ++k1) {      // Im = -(1/sqrtN) * sum x*sin
        float4 o;
        o.x = -acci[k1].x * INV_SQRT_N; o.y = -acci[k1].y * INV_SQRT_N;
        o.z = -acci[k1].z * INV_SQRT_N; o.w = -acci[k1].w * INV_SQRT_N;
        *(float4*)(yb + (size_t)(8 + k1) * N2_ * C_) = o;
    }
}

// ---------------------------------------------------------------------------
// Stage B: 241-point DFT with fused twiddle.  For f = k1 + 17*t <= 2048:
//   X[f] = sum_n2 y_eff[k1,n2] * e^{-2pi i f n2 / N},  y_eff = conj for k1>8.
// Writes X bf16 [B][F][2][C]; also energy[b][f] from f32 accumulators.
// ---------------------------------------------------------------------------
__global__ __launch_bounds__(256) void k_stageB(const float* __restrict__ y,
                                                unsigned short* __restrict__ X,
                                                float* __restrict__ energy) {
    int bid = blockIdx.x;
    int b = bid / 68;
    int rem = bid % 68;
    int k1 = rem >> 2;
    int tt = rem & 3;
    int tid = threadIdx.x;
    int cq = tid & 63, tg = tid >> 6;
    int c = cq * 4;
    int t0 = tt * 32 + tg * 8;

    int j = (k1 <= 8) ? k1 : 17 - k1;
    float sgn = (k1 <= 8) ? 1.0f : -1.0f;
    bool has_i = (j != 0);

    const float* yrp = y + ((size_t)(b * 17 + j) * N2_) * C_ + c;
    const float* yip = y + ((size_t)(b * 17 + 8 + j) * N2_) * C_ + c;

    float4 ar[8], ai[8];
#pragma unroll
    for (int t8 = 0; t8 < 8; ++t8) {
        ar[t8] = make_float4(0.f, 0.f, 0.f, 0.f);
        ai[t8] = make_float4(0.f, 0.f, 0.f, 0.f);
    }

    __shared__ float twc[8][32], tws[8][32];

    for (int k2b = 0; k2b < N2_; k2b += 8) {
        int bk = (N2_ - k2b < 8) ? (N2_ - k2b) : 8;
        __syncthreads();
        if (tid < bk * 32) {
            int kk = tid >> 5, tcol = tid & 31;
            int t = tt * 32 + tcol;
            int f = k1 + 17 * t;
            int rr = (f * (k2b + kk)) % N_;
            float s, cth; sincosf(W_N * (float)rr, &s, &cth);
            twc[kk][tcol] = cth; tws[kk][tcol] = s;
        }
        __syncthreads();
        for (int kk = 0; kk < bk; ++kk) {
            int n2 = k2b + kk;
            float4 ur = *(const float4*)(yrp + (size_t)n2 * C_);
            float4 ui;
            if (has_i) {
                ui = *(const float4*)(yip + (size_t)n2 * C_);
                ui.x *= sgn; ui.y *= sgn; ui.z *= sgn; ui.w *= sgn;
            } else {
                ui = make_float4(0.f, 0.f, 0.f, 0.f);
            }
#pragma unroll
            for (int t8 = 0; t8 < 8; ++t8) {
                float cc = twc[kk][tg * 8 + t8];
                float ss = tws[kk][tg * 8 + t8];
                ar[t8].x += ur.x * cc + ui.x * ss;
                ar[t8].y += ur.y * cc + ui.y * ss;
                ar[t8].z += ur.z * cc + ui.z * ss;
                ar[t8].w += ur.w * cc + ui.w * ss;
                ai[t8].x += ui.x * cc - ur.x * ss;
                ai[t8].y += ui.y * cc - ur.y * ss;
                ai[t8].z += ui.z * cc - ur.z * ss;
                ai[t8].w += ui.w * cc - ur.w * ss;
            }
        }
    }

#pragma unroll
    for (int t8 = 0; t8 < 8; ++t8) {
        int t = t0 + t8;
        int f = k1 + 17 * t;
        float e = ar[t8].x * ar[t8].x + ar[t8].y * ar[t8].y +
                  ar[t8].z * ar[t8].z + ar[t8].w * ar[t8].w +
                  ai[t8].x * ai[t8].x + ai[t8].y * ai[t8].y +
                  ai[t8].z * ai[t8].z + ai[t8].w * ai[t8].w;
#pragma unroll
        for (int off = 32; off > 0; off >>= 1) e += __shfl_xor(e, off, 64);
        if (f < F_) {
            if (cq == 0) energy[b * F_ + f] = e;
            size_t base = ((size_t)(b * F_ + f) * 2) * C_ + c;
            ushort4 pr, pi;
            pr.x = f2bf(ar[t8].x); pr.y = f2bf(ar[t8].y);
            pr.z = f2bf(ar[t8].z); pr.w = f2bf(ar[t8].w);
            pi.x = f2bf(ai[t8].x); pi.y = f2bf(ai[t8].y);
            pi.z = f2bf(ai[t8].z); pi.w = f2bf(ai[t8].w);
            *(ushort4*)(X + base) = pr;
            *(ushort4*)(X + base + C_) = pi;
        }
    }
}

// ---------------------------------------------------------------------------
// Median per batch: bitonic sort 2049 energies (padded to 4096), take [1024].
// ---------------------------------------------------------------------------
__global__ __launch_bounds__(256) void k_median(const float* __restrict__ energy,
                                                float* __restrict__ med) {
    __shared__ float buf[4096];
    int b = blockIdx.x;
    int tid = threadIdx.x;
    for (int i = tid; i < 4096; i += 256)
        buf[i] = (i < F_) ? energy[b * F_ + i] : FLT_MAX;
    __syncthreads();
    for (int k = 2; k <= 4096; k <<= 1) {
        for (int jj = k >> 1; jj > 0; jj >>= 1) {
            for (int i = tid; i < 4096; i += 256) {
                int ixj = i ^ jj;
                if (ixj > i) {
                    float a = buf[i], bv = buf[ixj];
                    bool up = ((i & k) == 0);
                    if (up ? (a > bv) : (a < bv)) { buf[i] = bv; buf[ixj] = a; }
                }
            }
            __syncthreads();
        }
    }
    if (tid == 0) med[b] = buf[1024];   // 1025th smallest of 2049 (np exact middle)
}

// ---------------------------------------------------------------------------
// Twiddle table for stage C MFMA:  twA[n][q], n=0..4351, q=0..511, bf16.
//   q = 2*k2   -> cos(2*pi*n*k2/N)
//   q = 2*k2+1 -> -sin(2*pi*n*k2/N)
// zero for n > 4096 or k2 > 240  (handles K-pad and m1-tail rows).
// ---------------------------------------------------------------------------
__global__ __launch_bounds__(256) void k_twfill(unsigned short* __restrict__ twA) {
    int n = blockIdx.x;          // 0..4351
    int k2 = threadIdx.x;        // 0..255
    unsigned pack = 0u;
    if (n <= 4096 && k2 <= 240) {
        int rr = (n * k2) % N_;
        float s, cth; sincosf(W_N * (float)rr, &s, &cth);
        pack = (unsigned)f2bf(cth) | ((unsigned)f2bf(-s) << 16);
    }
    *(unsigned*)(twA + (size_t)n * 512 + 2 * k2) = pack;
}

// ---------------------------------------------------------------------------
// v-builder: mask + weights + inverse inner 17-point stage.
//   Z[f] = X[f]*(w + m*wh) * (f==0?1:2)/sqrt(N)
//   v[k2,m2] = sum_s Z[k2+241 s] * e^{+2pi i s m2/17}
// Output TRANSPOSED for MFMA:  v_t[b][m2][c][q=2*k2+p]  bf16 (stride VSTRIDE).
// grid B*241 (chunk-swizzled so 8 adjacent k2 share an XCD L2 for the
// 64B-line scatter writes), one thread per channel c.
// ---------------------------------------------------------------------------
__global__ __launch_bounds__(256) void k_vbuild(const unsigned short* __restrict__ X,
                                                const float* __restrict__ energy,
                                                const float* __restrict__ med,
                                                const float* __restrict__ thr,
                                                const float* __restrict__ cw,
                                                const float* __restrict__ cwh,
                                                unsigned short* __restrict__ vt) {
    int bid = (blockIdx.x & 7) * 964 + (blockIdx.x >> 3);   // 7712 = 8*964
    int b = bid / N2_;
    int k2 = bid % N2_;
    int c = threadIdx.x;

    float wr = cw[2 * c], wi = cw[2 * c + 1];
    float whr = cwh[2 * c], whi = cwh[2 * c + 1];
    float denom = med[b] + 1e-6f;

    float C17[17], S17[17];
#pragma unroll
    for (int r = 0; r < 17; ++r) {
        float s, cth; sincosf(W_17 * (float)r, &s, &cth);
        C17[r] = cth; S17[r] = s;
    }

    float vr[17], vi[17];
#pragma unroll
    for (int m = 0; m < 17; ++m) { vr[m] = 0.f; vi[m] = 0.f; }

#pragma unroll
    for (int s = 0; s < 9; ++s) {
        int f = k2 + 241 * s;
        if (f < F_) {
            float e = energy[b * F_ + f];
            float m = (e / denom > thr[f]) ? 1.0f : 0.0f;
            float wer = wr + m * whr, wei = wi + m * whi;
            float cf = ((f == 0) ? 1.0f : 2.0f) * INV_SQRT_N;
            const unsigned short* Xrow = X + ((size_t)(b * F_ + f) * 2) * C_;
            float Xr = bf2f(Xrow[c]), Xi = bf2f(Xrow[C_ + c]);
            float Zr = (Xr * wer - Xi * wei) * cf;
            float Zi = (Xr * wei + Xi * wer) * cf;
#pragma unroll
            for (int m2 = 0; m2 < 17; ++m2) {
                int r = (s * m2) % 17;    // compile-time after unroll
                vr[m2] += Zr * C17[r] - Zi * S17[r];
                vi[m2] += Zr * S17[r] + Zi * C17[r];
            }
        }
    }
#pragma unroll
    for (int m2 = 0; m2 < 17; ++m2) {
        unsigned pack = (unsigned)f2bf(vr[m2]) | ((unsigned)f2bf(vi[m2]) << 16);
        size_t base = ((size_t)((b * 17 + m2) * 256 + c)) * VSTRIDE + 2 * k2;
        *(unsigned*)(vt + base) = pack;
    }
}

// ---------------------------------------------------------------------------
// Stage C via MFMA:  per (b,m2):  OUT[m1][c] = sum_q twA[17*m1+m2][q]*v_t[c][q]
// Block = 4 waves (2x2), each wave 64(m1) x 64(c) via 4x4 mfma 16x16x32 tiles.
// Both operand fragments are direct 16B global loads (K-contiguous layouts).
// grid 2176 = B*17*2(m1t)*2(ct), chunk-swizzled.
// ---------------------------------------------------------------------------
__global__ __launch_bounds__(256) void k_stageC_mfma(const short* __restrict__ vt,
                                                     const short* __restrict__ twA,
                                                     float* __restrict__ out) {
    int bid = (blockIdx.x & 7) * 272 + (blockIdx.x >> 3);   // 2176 = 8*272
    int ct = bid & 1;
    int m1t = (bid >> 1) & 1;
    int bm = bid >> 2;                 // 0..543
    int b = bm / 17, m2 = bm % 17;

    int tid = threadIdx.x;
    int lane = tid & 63;
    int wid = tid >> 6;
    int wr = wid >> 1, wc = wid & 1;
    int l15 = lane & 15, lg = lane >> 4;

    int m1w = m1t * 128 + wr * 64;
    int cw = ct * 128 + wc * 64;

    const short* vtb = vt + ((size_t)(b * 17 + m2) * 256) * VSTRIDE;

    const short* aptr[4];
#pragma unroll
    for (int rt = 0; rt < 4; ++rt) {
        int m1 = m1w + rt * 16 + l15;
        int n = 17 * m1 + m2;          // < 4352 always (m1 <= 255)
        aptr[rt] = twA + (size_t)n * 512 + lg * 8;
    }
    const short* bptr[4];
#pragma unroll
    for (int nt = 0; nt < 4; ++nt) {
        int c = cw + nt * 16 + l15;
        bptr[nt] = vtb + (size_t)c * VSTRIDE + lg * 8;
    }

    f32x4 acc[4][4];
#pragma unroll
    for (int rt = 0; rt < 4; ++rt)
#pragma unroll
        for (int nt = 0; nt < 4; ++nt) acc[rt][nt] = (f32x4){0.f, 0.f, 0.f, 0.f};

    for (int q0 = 0; q0 < 512; q0 += 32) {
        short8v a[4], bb[4];
#pragma unroll
        for (int rt = 0; rt < 4; ++rt) a[rt] = *(const short8v*)(aptr[rt] + q0);
#pragma unroll
        for (int nt = 0; nt < 4; ++nt) bb[nt] = *(const short8v*)(bptr[nt] + q0);
#pragma unroll
        for (int rt = 0; rt < 4; ++rt)
#pragma unroll
            for (int nt = 0; nt < 4; ++nt)
                acc[rt][nt] = __builtin_amdgcn_mfma_f32_16x16x32_bf16(
                    a[rt], bb[nt], acc[rt][nt], 0, 0, 0);
    }

    // store: lane holds D[row=lg*4+j][col=l15] of each 16x16 tile
#pragma unroll
    for (int rt = 0; rt < 4; ++rt) {
#pragma unroll
        for (int j = 0; j < 4; ++j) {
            int m1 = m1w + rt * 16 + lg * 4 + j;
            if (m1 < N2_) {
                int n = 17 * m1 + m2;
                float* orow = out + ((size_t)b * N_ + n) * C_ + cw;
#pragma unroll
                for (int nt = 0; nt < 4; ++nt)
                    orow[nt * 16 + l15] = acc[rt][nt][j];
            }
        }
    }
}

// ---------------------------------------------------------------------------
extern "C" void kernel_launch(void* const* d_in, const int* in_sizes, int n_in,
                              void* d_out, int out_size, void* d_ws, size_t ws_size,
                              hipStream_t stream) {
    const float* x   = (const float*)d_in[0];
    const float* cw  = (const float*)d_in[1];
    const float* cwh = (const float*)d_in[2];
    const float* thr = (const float*)d_in[3];
    float* out = (float*)d_out;

    // workspace layout (~207.8 MB):
    //   X    bf16 [B][F][2][C]        :  67,141,632 B
    //   v_t  bf16 [B][17][256][488]   : 135,921,664 B
    //   twA  bf16 [4352][512]         :   4,456,448 B
    //   energy f32 [B][F]             :     262,272 B
    //   med    f32 [B]                :         128 B
    char* ws = (char*)d_ws;
    unsigned short* Xb = (unsigned short*)ws;
    unsigned short* vtb = (unsigned short*)(ws + 67141632ull);
    unsigned short* twA = (unsigned short*)(ws + 67141632ull + 135921664ull);
    float* energy = (float*)(ws + 67141632ull + 135921664ull + 4456448ull);
    float* med = (float*)(ws + 67141632ull + 135921664ull + 4456448ull + 262272ull);

    k_twfill<<<TWROWS, 256, 0, stream>>>(twA);
    // y (f32, 17 planes) lives in d_out; dead before k_stageC_mfma writes out.
    k_stageA<<<B_ * 61, 256, 0, stream>>>(x, out);
    k_stageB<<<B_ * 68, 256, 0, stream>>>(out, Xb, energy);
    k_median<<<B_, 256, 0, stream>>>(energy, med);
    k_vbuild<<<B_ * N2_, 256, 0, stream>>>(Xb, energy, med, thr, cw, cwh, vtb);
    k_stageC_mfma<<<B_ * 68, 256, 0, stream>>>((const short*)vtb, (const short*)twA, out);
}

// Round 3
// 844.101 us; speedup vs baseline: 1.7062x; 1.2956x over previous
//
#include <hip/hip_runtime.h>
#include <math.h>
#include <float.h>

#define B_ 32
#define N_ 4097
#define C_ 256
#define F_ 2049
#define N2_ 241
#define Q_ 512                        // padded K (q = 2*n2 + p, zeros q>=482)
#define TWROWS 4352                   // stageC twiddle rows (m1-tail padded)
#define INV_SQRT_N 0.0156230927f      // 1/sqrt(4097)
#define W_N 0.0015336063f             // 2*pi/4097
#define W_17 0.36959913571644626f     // 2*pi/17

typedef __attribute__((ext_vector_type(8))) short short8v;
typedef __attribute__((ext_vector_type(4))) float f32x4;

__device__ __forceinline__ float bf2f(unsigned short u) {
    return __uint_as_float(((unsigned)u) << 16);
}
__device__ __forceinline__ unsigned short f2bf(float v) {
    unsigned u = __float_as_uint(v);
    u += 0x7FFFu + ((u >> 16) & 1u);
    return (unsigned short)(u >> 16);
}

// ---------------------------------------------------------------------------
// Stage A: 17-point real DFTs.  x[B][N][C] f32 -> y planes [B][17][241][C] f32
// planes 0..8 = Re y[k1], planes 9..16 = Im y[k1] (k1=1..8).  1/sqrt(N) folded.
// y lives in d_out (17*241 == 4097).
// ---------------------------------------------------------------------------
__global__ __launch_bounds__(256) void k_stageA(const float* __restrict__ x,
                                                float* __restrict__ y) {
    int bid = blockIdx.x;                 // B*61
    int b = bid / 61, n2q = bid % 61;
    int tid = threadIdx.x;
    int cq = tid & 63, sub = tid >> 6;
    int n2 = n2q * 4 + sub;
    if (n2 >= N2_) return;
    int c = cq * 4;

    float C17[17], S17[17];
#pragma unroll
    for (int r = 0; r < 17; ++r) {
        float s, cth; sincosf(W_17 * (float)r, &s, &cth);
        C17[r] = cth; S17[r] = s;
    }

    float4 accr[9], acci[9];
#pragma unroll
    for (int k = 0; k < 9; ++k) {
        accr[k] = make_float4(0.f, 0.f, 0.f, 0.f);
        acci[k] = make_float4(0.f, 0.f, 0.f, 0.f);
    }

    const float* xb = x + (size_t)b * N_ * C_ + c;
#pragma unroll
    for (int n1 = 0; n1 < 17; ++n1) {
        float4 xv = *(const float4*)(xb + (size_t)(n1 * N2_ + n2) * C_);
#pragma unroll
        for (int k1 = 0; k1 < 9; ++k1) {
            int r = (k1 * n1) % 17;       // compile-time after unroll
            float cc = C17[r], ss = S17[r];
            accr[k1].x += xv.x * cc; accr[k1].y += xv.y * cc;
            accr[k1].z += xv.z * cc; accr[k1].w += xv.w * cc;
            if (k1 > 0) {
                acci[k1].x += xv.x * ss; acci[k1].y += xv.y * ss;
                acci[k1].z += xv.z * ss; acci[k1].w += xv.w * ss;
            }
        }
    }

    float* yb = y + ((size_t)(b * 17) * N2_ + n2) * C_ + c;
#pragma unroll
    for (int k1 = 0; k1 < 9; ++k1) {
        float4 o;
        o.x = accr[k1].x * INV_SQRT_N; o.y = accr[k1].y * INV_SQRT_N;
        o.z = accr[k1].z * INV_SQRT_N; o.w = accr[k1].w * INV_SQRT_N;
        *(float4*)(yb + (size_t)k1 * N2_ * C_) = o;
    }
#pragma unroll
    for (int k1 = 1; k1 < 9; ++k1) {
        float4 o;
        o.x = -acci[k1].x * INV_SQRT_N; o.y = -acci[k1].y * INV_SQRT_N;
        o.z = -acci[k1].z * INV_SQRT_N; o.w = -acci[k1].w * INV_SQRT_N;
        *(float4*)(yb + (size_t)(8 + k1) * N2_ * C_) = o;
    }
}

// ---------------------------------------------------------------------------
// ytrans: y f32 planes -> y_t hi/lo bf16 [b][j 0..8][c][q], q=2n2+p, zero pad.
// LDS-tiled transpose; coalesced reads and 32B-chunk writes.
// grid 32*9*8*4, 256 thr.
// ---------------------------------------------------------------------------
__global__ __launch_bounds__(256) void k_ytrans(const float* __restrict__ y,
                                                unsigned short* __restrict__ yhi,
                                                unsigned short* __restrict__ ylo) {
    int bid = blockIdx.x;
    int b = bid / 288; int rem = bid % 288;
    int j = rem / 32; int rem2 = rem % 32;
    int kt = rem2 >> 2, ct = rem2 & 3;
    int tid = threadIdx.x;
    __shared__ float lre[32 * 65], lim[32 * 65];
    int cl = tid & 63, rs = tid >> 6;
#pragma unroll
    for (int it = 0; it < 8; ++it) {
        int rowl = it * 4 + rs;           // 0..31
        int n2 = kt * 32 + rowl;
        int cg = ct * 64 + cl;
        float re = 0.f, im = 0.f;
        if (n2 <= 240) {
            re = y[((size_t)((b * 17 + j) * N2_ + n2)) * C_ + cg];
            if (j > 0) im = y[((size_t)((b * 17 + 8 + j) * N2_ + n2)) * C_ + cg];
        }
        lre[rowl * 65 + cl] = re; lim[rowl * 65 + cl] = im;
    }
    __syncthreads();
    int c = tid >> 2, qg = tid & 3;
    unsigned wh[8], wl[8];
#pragma unroll
    for (int i = 0; i < 8; ++i) {
        int rowl = qg * 8 + i;
        float re = lre[rowl * 65 + c], im = lim[rowl * 65 + c];
        unsigned short rh = f2bf(re); float rl = re - bf2f(rh);
        unsigned short ih = f2bf(im); float il = im - bf2f(ih);
        wh[i] = (unsigned)rh | ((unsigned)ih << 16);
        wl[i] = (unsigned)f2bf(rl) | ((unsigned)f2bf(il) << 16);
    }
    size_t ubase = ((size_t)((b * 9 + j) * 256 + ct * 64 + c)) * 256 + kt * 32 + qg * 8;
    uint4 v0; v0.x = wh[0]; v0.y = wh[1]; v0.z = wh[2]; v0.w = wh[3];
    uint4 v1; v1.x = wh[4]; v1.y = wh[5]; v1.z = wh[6]; v1.w = wh[7];
    *(uint4*)((unsigned*)yhi + ubase) = v0;
    *(uint4*)((unsigned*)yhi + ubase + 4) = v1;
    uint4 u0; u0.x = wl[0]; u0.y = wl[1]; u0.z = wl[2]; u0.w = wl[3];
    uint4 u1; u1.x = wl[4]; u1.y = wl[5]; u1.z = wl[6]; u1.w = wl[7];
    *(uint4*)((unsigned*)ylo + ubase) = u0;
    *(uint4*)((unsigned*)ylo + ubase + 4) = u1;
}

// ---------------------------------------------------------------------------
// twB: stageB twiddle A-operand, [k1][m=2t+r][q], bf16 hi/lo.
//   r=0 (Xr): q=2n2 -> cos, q=2n2+1 -> s*sin
//   r=1 (Xi): q=2n2 -> -sin, q=2n2+1 -> s*cos     (s = +1 k1<=8, -1 else)
// zero rows m>=242 / f>2048, zero cols n2>240.
// ---------------------------------------------------------------------------
__global__ __launch_bounds__(256) void k_twfillB(unsigned short* __restrict__ hi,
                                                 unsigned short* __restrict__ lo) {
    int m = blockIdx.x & 255; int k1 = blockIdx.x >> 8;   // grid 17*256
    int n2 = threadIdx.x;
    int t = m >> 1, r = m & 1;
    int f = k1 + 17 * t;
    unsigned ph = 0u, pl = 0u;
    if (t <= 120 && f < F_ && n2 <= 240) {
        float s_ = (k1 <= 8) ? 1.f : -1.f;
        int rr = (f * n2) % N_;
        float sn, cs; sincosf(W_N * (float)rr, &sn, &cs);
        float a0 = (r == 0) ? cs : -sn;
        float a1 = (r == 0) ? s_ * sn : s_ * cs;
        unsigned short h0 = f2bf(a0); float l0 = a0 - bf2f(h0);
        unsigned short h1 = f2bf(a1); float l1 = a1 - bf2f(h1);
        ph = (unsigned)h0 | ((unsigned)h1 << 16);
        pl = (unsigned)f2bf(l0) | ((unsigned)f2bf(l1) << 16);
    }
    size_t ub = ((size_t)(k1 * 256 + m)) * 256 + n2;
    *((unsigned*)hi + ub) = ph;
    *((unsigned*)lo + ub) = pl;
}

// ---------------------------------------------------------------------------
// Stage B via split-bf16 MFMA.  Per (b,k1): OUT[m][c] = sum_q twB[k1][m][q]*y_t[b][j][c][q]
// acc += Ahi*Bhi + Alo*Bhi + Ahi*Blo  (f32, ~1e-5 rel accurate).
// Block: 4 waves (1x4 in N), covers M=64 (mt of 4) x N=256. Energy reduced
// in-block (shfl over c-lanes + LDS over waves), X stored bf16.
// grid 2176 = B*17*4, chunk-swizzled.
// ---------------------------------------------------------------------------
__global__ __launch_bounds__(256) void k_stageB_mfma(
        const short* __restrict__ yt_hi, const short* __restrict__ yt_lo,
        const short* __restrict__ twb_hi, const short* __restrict__ twb_lo,
        unsigned short* __restrict__ X, float* __restrict__ energy) {
    int bid = (blockIdx.x & 7) * 272 + (blockIdx.x >> 3);   // 2176 = 8*272
    int b = bid / 68, rem = bid % 68;
    int k1 = rem >> 2, mt = rem & 3;
    int j = (k1 <= 8) ? k1 : 17 - k1;
    int tid = threadIdx.x, lane = tid & 63, wid = tid >> 6;
    int l15 = lane & 15, lg = lane >> 4;
    int mbase = mt * 64;

    int offA[4], offB[4];
#pragma unroll
    for (int rt = 0; rt < 4; ++rt) {
        int row = mbase + rt * 16 + l15;
        offA[rt] = (k1 * 256 + row) * Q_ + lg * 8;
    }
#pragma unroll
    for (int nt = 0; nt < 4; ++nt) {
        int c = wid * 64 + nt * 16 + l15;
        offB[nt] = ((b * 9 + j) * 256 + c) * Q_ + lg * 8;
    }

    f32x4 acc[4][4];
#pragma unroll
    for (int rt = 0; rt < 4; ++rt)
#pragma unroll
        for (int nt = 0; nt < 4; ++nt) acc[rt][nt] = (f32x4){0.f, 0.f, 0.f, 0.f};

    for (int q0 = 0; q0 < Q_; q0 += 32) {
        short8v Ah[4], Al[4], Bh[4], Bl[4];
#pragma unroll
        for (int rt = 0; rt < 4; ++rt) {
            Ah[rt] = *(const short8v*)(twb_hi + offA[rt] + q0);
            Al[rt] = *(const short8v*)(twb_lo + offA[rt] + q0);
        }
#pragma unroll
        for (int nt = 0; nt < 4; ++nt) {
            Bh[nt] = *(const short8v*)(yt_hi + offB[nt] + q0);
            Bl[nt] = *(const short8v*)(yt_lo + offB[nt] + q0);
        }
#pragma unroll
        for (int rt = 0; rt < 4; ++rt)
#pragma unroll
            for (int nt = 0; nt < 4; ++nt) {
                acc[rt][nt] = __builtin_amdgcn_mfma_f32_16x16x32_bf16(
                    Ah[rt], Bh[nt], acc[rt][nt], 0, 0, 0);
                acc[rt][nt] = __builtin_amdgcn_mfma_f32_16x16x32_bf16(
                    Al[rt], Bh[nt], acc[rt][nt], 0, 0, 0);
                acc[rt][nt] = __builtin_amdgcn_mfma_f32_16x16x32_bf16(
                    Ah[rt], Bl[nt], acc[rt][nt], 0, 0, 0);
            }
    }

    // ---- energy: sum over all c of Xr^2 + Xi^2 per t ----
    __shared__ float eL[4][4][4][2];
#pragma unroll
    for (int rt = 0; rt < 4; ++rt) {
        float e0 = 0.f, e1 = 0.f;
#pragma unroll
        for (int nt = 0; nt < 4; ++nt) {
            e0 += acc[rt][nt][0] * acc[rt][nt][0] + acc[rt][nt][1] * acc[rt][nt][1];
            e1 += acc[rt][nt][2] * acc[rt][nt][2] + acc[rt][nt][3] * acc[rt][nt][3];
        }
#pragma unroll
        for (int off = 1; off < 16; off <<= 1) {
            e0 += __shfl_xor(e0, off, 64);
            e1 += __shfl_xor(e1, off, 64);
        }
        if (l15 == 0) { eL[wid][rt][lg][0] = e0; eL[wid][rt][lg][1] = e1; }
    }
    __syncthreads();
    if (tid < 32) {
        int rt = tid >> 3, r2 = tid & 7;
        int lg2 = r2 >> 1, pr = r2 & 1;
        int t = ((mbase + rt * 16 + lg2 * 4) >> 1) + pr;
        int f = k1 + 17 * t;
        if (f < F_) {
            float e = eL[0][rt][lg2][pr] + eL[1][rt][lg2][pr] +
                      eL[2][rt][lg2][pr] + eL[3][rt][lg2][pr];
            energy[b * F_ + f] = e;
        }
    }

    // ---- X store (bf16) ----
#pragma unroll
    for (int rt = 0; rt < 4; ++rt) {
#pragma unroll
        for (int jj = 0; jj < 4; ++jj) {
            int row = mbase + rt * 16 + lg * 4 + jj;
            int t = row >> 1, p = row & 1;
            int f = k1 + 17 * t;
            if (f < F_) {
                size_t base = ((size_t)((b * F_ + f) * 2 + p)) * C_ + wid * 64 + l15;
#pragma unroll
                for (int nt = 0; nt < 4; ++nt)
                    X[base + nt * 16] = f2bf(acc[rt][nt][jj]);
            }
        }
    }
}

// ---------------------------------------------------------------------------
// Median per batch: bitonic sort 2049 energies (padded to 4096), take [1024].
// ---------------------------------------------------------------------------
__global__ __launch_bounds__(256) void k_median(const float* __restrict__ energy,
                                                float* __restrict__ med) {
    __shared__ float buf[4096];
    int b = blockIdx.x;
    int tid = threadIdx.x;
    for (int i = tid; i < 4096; i += 256)
        buf[i] = (i < F_) ? energy[b * F_ + i] : FLT_MAX;
    __syncthreads();
    for (int k = 2; k <= 4096; k <<= 1) {
        for (int jj = k >> 1; jj > 0; jj >>= 1) {
            for (int i = tid; i < 4096; i += 256) {
                int ixj = i ^ jj;
                if (ixj > i) {
                    float a = buf[i], bv = buf[ixj];
                    bool up = ((i & k) == 0);
                    if (up ? (a > bv) : (a < bv)) { buf[i] = bv; buf[ixj] = a; }
                }
            }
            __syncthreads();
        }
    }
    if (tid == 0) med[b] = buf[1024];
}

// ---------------------------------------------------------------------------
// Twiddle table for stage C MFMA:  twA[n][q], n=0..4351, q=0..511, bf16.
//   q=2*k2 -> cos(2*pi*n*k2/N),  q=2*k2+1 -> -sin(2*pi*n*k2/N); zero pads.
// ---------------------------------------------------------------------------
__global__ __launch_bounds__(256) void k_twfill(unsigned short* __restrict__ twA) {
    int n = blockIdx.x;          // 0..4351
    int k2 = threadIdx.x;        // 0..255
    unsigned pack = 0u;
    if (n <= 4096 && k2 <= 240) {
        int rr = (n * k2) % N_;
        float s, cth; sincosf(W_N * (float)rr, &s, &cth);
        pack = (unsigned)f2bf(cth) | ((unsigned)f2bf(-s) << 16);
    }
    *(unsigned*)(twA + (size_t)n * Q_ + 2 * k2) = pack;
}

// ---------------------------------------------------------------------------
// vbuild (tiled): mask + weights + inverse inner 17-point stage.
//   Z[f] = X[f]*(w + m*wh) * (f==0?1:2)/sqrt(N)
//   v[k2,m2] = sum_s Z[k2+241 s] * e^{+2pi i s m2/17}
// Output v_t[b][m2][c][q=2k2+p] bf16 (stride Q_), COALESCED via LDS staging.
// block: (b, k2-tile of 32, c-tile of 32); 256 thr = 32 c x 8 k2sub, 4 k2-iters.
// ---------------------------------------------------------------------------
__global__ __launch_bounds__(256) void k_vbuild_t(
        const unsigned short* __restrict__ X, const float* __restrict__ energy,
        const float* __restrict__ med, const float* __restrict__ thr,
        const float* __restrict__ cw, const float* __restrict__ cwh,
        unsigned short* __restrict__ vt) {
    int bid = blockIdx.x;            // 32*8*8 = 2048
    int b = bid / 64; int rem = bid % 64;
    int kt = rem >> 3, ct = rem & 7;
    int tid = threadIdx.x;
    int cl = tid & 31, ks = tid >> 5;
    int c = ct * 32 + cl;

    __shared__ unsigned stage[17 * 32 * 33];   // [m2][cl][klocal pad 33]

    float wr = cw[2 * c], wi = cw[2 * c + 1];
    float whr = cwh[2 * c], whi = cwh[2 * c + 1];
    float denom = med[b] + 1e-6f;

    float C17[17], S17[17];
#pragma unroll
    for (int r = 0; r < 17; ++r) {
        float s, cth; sincosf(W_17 * (float)r, &s, &cth);
        C17[r] = cth; S17[r] = s;
    }

    for (int kk = 0; kk < 4; ++kk) {
        int klocal = kk * 8 + ks;
        int k2 = kt * 32 + klocal;
        float vr[17], vi[17];
#pragma unroll
        for (int m = 0; m < 17; ++m) { vr[m] = 0.f; vi[m] = 0.f; }
        if (k2 <= 240) {
#pragma unroll
            for (int s = 0; s < 9; ++s) {
                int f = k2 + 241 * s;
                if (f < F_) {
                    float e = energy[b * F_ + f];
                    float m = (e / denom > thr[f]) ? 1.0f : 0.0f;
                    float wer = wr + m * whr, wei = wi + m * whi;
                    float cf = ((f == 0) ? 1.0f : 2.0f) * INV_SQRT_N;
                    const unsigned short* Xrow = X + ((size_t)(b * F_ + f) * 2) * C_;
                    float Xr = bf2f(Xrow[c]), Xi = bf2f(Xrow[C_ + c]);
                    float Zr = (Xr * wer - Xi * wei) * cf;
                    float Zi = (Xr * wei + Xi * wer) * cf;
#pragma unroll
                    for (int m2 = 0; m2 < 17; ++m2) {
                        int r = (s * m2) % 17;
                        vr[m2] += Zr * C17[r] - Zi * S17[r];
                        vi[m2] += Zr * S17[r] + Zi * C17[r];
                    }
                }
            }
        }
#pragma unroll
        for (int m2 = 0; m2 < 17; ++m2)
            stage[(m2 * 32 + cl) * 33 + klocal] =
                (unsigned)f2bf(vr[m2]) | ((unsigned)f2bf(vi[m2]) << 16);
    }
    __syncthreads();
    unsigned* vt32 = (unsigned*)vt;
    for (int r = tid; r < 544; r += 256) {
        int m2 = r >> 5, c2 = r & 31;
        size_t ubase = ((size_t)((b * 17 + m2) * 256 + ct * 32 + c2)) * 256 + kt * 32;
        const unsigned* srow = &stage[(m2 * 32 + c2) * 33];
#pragma unroll
        for (int g = 0; g < 8; ++g) {
            uint4 w;
            w.x = srow[g * 4]; w.y = srow[g * 4 + 1];
            w.z = srow[g * 4 + 2]; w.w = srow[g * 4 + 3];
            *(uint4*)(vt32 + ubase + g * 4) = w;
        }
    }
}

// ---------------------------------------------------------------------------
// Stage C via MFMA:  per (b,m2): OUT[m1][c] = sum_q twA[17*m1+m2][q]*v_t[c][q]
// Block = 4 waves (2x2), each wave 64x64 via 4x4 mfma 16x16x32 tiles.
// grid 2176 = B*17*2*2, chunk-swizzled.
// ---------------------------------------------------------------------------
__global__ __launch_bounds__(256) void k_stageC_mfma(const short* __restrict__ vt,
                                                     const short* __restrict__ twA,
                                                     float* __restrict__ out) {
    int bid = (blockIdx.x & 7) * 272 + (blockIdx.x >> 3);
    int ct = bid & 1;
    int m1t = (bid >> 1) & 1;
    int bm = bid >> 2;
    int b = bm / 17, m2 = bm % 17;

    int tid = threadIdx.x;
    int lane = tid & 63;
    int wid = tid >> 6;
    int wr = wid >> 1, wc = wid & 1;
    int l15 = lane & 15, lg = lane >> 4;

    int m1w = m1t * 128 + wr * 64;
    int cw = ct * 128 + wc * 64;

    const short* vtb = vt + ((size_t)(b * 17 + m2) * 256) * Q_;

    const short* aptr[4];
#pragma unroll
    for (int rt = 0; rt < 4; ++rt) {
        int m1 = m1w + rt * 16 + l15;
        int n = 17 * m1 + m2;
        aptr[rt] = twA + (size_t)n * Q_ + lg * 8;
    }
    const short* bptr[4];
#pragma unroll
    for (int nt = 0; nt < 4; ++nt) {
        int c = cw + nt * 16 + l15;
        bptr[nt] = vtb + (size_t)c * Q_ + lg * 8;
    }

    f32x4 acc[4][4];
#pragma unroll
    for (int rt = 0; rt < 4; ++rt)
#pragma unroll
        for (int nt = 0; nt < 4; ++nt) acc[rt][nt] = (f32x4){0.f, 0.f, 0.f, 0.f};

    for (int q0 = 0; q0 < Q_; q0 += 32) {
        short8v a[4], bb[4];
#pragma unroll
        for (int rt = 0; rt < 4; ++rt) a[rt] = *(const short8v*)(aptr[rt] + q0);
#pragma unroll
        for (int nt = 0; nt < 4; ++nt) bb[nt] = *(const short8v*)(bptr[nt] + q0);
#pragma unroll
        for (int rt = 0; rt < 4; ++rt)
#pragma unroll
            for (int nt = 0; nt < 4; ++nt)
                acc[rt][nt] = __builtin_amdgcn_mfma_f32_16x16x32_bf16(
                    a[rt], bb[nt], acc[rt][nt], 0, 0, 0);
    }

#pragma unroll
    for (int rt = 0; rt < 4; ++rt) {
#pragma unroll
        for (int j = 0; j < 4; ++j) {
            int m1 = m1w + rt * 16 + lg * 4 + j;
            if (m1 < N2_) {
                int n = 17 * m1 + m2;
                float* orow = out + ((size_t)b * N_ + n) * C_ + cw;
#pragma unroll
                for (int nt = 0; nt < 4; ++nt)
                    orow[nt * 16 + l15] = acc[rt][nt][j];
            }
        }
    }
}

// ---------------------------------------------------------------------------
extern "C" void kernel_launch(void* const* d_in, const int* in_sizes, int n_in,
                              void* d_out, int out_size, void* d_ws, size_t ws_size,
                              hipStream_t stream) {
    const float* x   = (const float*)d_in[0];
    const float* cw  = (const float*)d_in[1];
    const float* cwh = (const float*)d_in[2];
    const float* thr = (const float*)d_in[3];
    float* out = (float*)d_out;

    // workspace (~231.8 MB), v_t aliases the dead y_t region:
    //   X     bf16 [B][F][2][C]          :  67,141,632
    //   SH    region (y_t_hi + y_t_lo | v_t):
    //     y_t_hi bf16 [B][9][256][512]   :  75,497,472
    //     y_t_lo bf16                    :  75,497,472
    //     v_t    bf16 [B][17][256][512]  : 142,606,336 (aliased at SH base)
    //   twA   bf16 [4352][512]           :   4,456,448
    //   twB_hi/lo bf16 [17][256][512]    :   4,456,448 each
    //   energy f32 [B][F]                :     262,272
    //   med    f32 [B]                   :         128
    char* ws = (char*)d_ws;
    unsigned short* Xb    = (unsigned short*)ws;
    char* sh = ws + 67141632ull;
    unsigned short* ythi  = (unsigned short*)sh;
    unsigned short* ytlo  = (unsigned short*)(sh + 75497472ull);
    unsigned short* vtb   = (unsigned short*)sh;                 // alias
    char* tail = sh + 150994944ull;
    unsigned short* twA   = (unsigned short*)tail;
    unsigned short* twBh  = (unsigned short*)(tail + 4456448ull);
    unsigned short* twBl  = (unsigned short*)(tail + 8912896ull);
    float* energy = (float*)(tail + 13369344ull);
    float* med    = (float*)(tail + 13369344ull + 262272ull);

    k_twfill<<<TWROWS, 256, 0, stream>>>(twA);
    k_twfillB<<<17 * 256, 256, 0, stream>>>(twBh, twBl);
    k_stageA<<<B_ * 61, 256, 0, stream>>>(x, out);
    k_ytrans<<<B_ * 9 * 32, 256, 0, stream>>>(out, ythi, ytlo);
    k_stageB_mfma<<<B_ * 68, 256, 0, stream>>>((const short*)ythi, (const short*)ytlo,
                                               (const short*)twBh, (const short*)twBl,
                                               Xb, energy);
    k_median<<<B_, 256, 0, stream>>>(energy, med);
    k_vbuild_t<<<B_ * 64, 256, 0, stream>>>(Xb, energy, med, thr, cw, cwh, vtb);
    k_stageC_mfma<<<B_ * 68, 256, 0, stream>>>((const short*)vtb, (const short*)twA, out);
}

// Round 4
// 596.801 us; speedup vs baseline: 2.4131x; 1.4144x over previous
//
#include <hip/hip_runtime.h>
#include <math.h>
#include <float.h>

#define B_ 32
#define N_ 4097
#define C_ 256
#define F_ 2049
#define N2_ 241
#define Q_ 512                        // padded K (q = 2*n2 + p, zeros q>=482)
#define TWROWS 4352                   // stageC twiddle rows (m1-tail padded)
#define INV_SQRT_N 0.0156230927f      // 1/sqrt(4097)
#define W_N 0.0015336063f             // 2*pi/4097
#define W_17 0.36959913571644626f     // 2*pi/17

typedef __attribute__((ext_vector_type(8))) short short8v;
typedef __attribute__((ext_vector_type(4))) float f32x4;

__device__ __forceinline__ float bf2f(unsigned short u) {
    return __uint_as_float(((unsigned)u) << 16);
}
__device__ __forceinline__ unsigned short f2bf(float v) {
    unsigned u = __float_as_uint(v);
    u += 0x7FFFu + ((u >> 16) & 1u);
    return (unsigned short)(u >> 16);
}
__device__ __forceinline__ void gload16(const void* gptr, void* ldsptr) {
    __builtin_amdgcn_global_load_lds(
        (const __attribute__((address_space(1))) void*)gptr,
        (__attribute__((address_space(3))) void*)ldsptr,
        16, 0, 0);
}

// ---------------------------------------------------------------------------
// Stage A: 17-point real DFTs.  x[B][N][C] f32 -> y planes [B][17][241][C] f32
// planes 0..8 = Re y[k1], planes 9..16 = Im y[k1] (k1=1..8).  1/sqrt(N) folded.
// y lives in d_out (17*241 == 4097).
// ---------------------------------------------------------------------------
__global__ __launch_bounds__(256) void k_stageA(const float* __restrict__ x,
                                                float* __restrict__ y) {
    int bid = blockIdx.x;                 // B*61
    int b = bid / 61, n2q = bid % 61;
    int tid = threadIdx.x;
    int cq = tid & 63, sub = tid >> 6;
    int n2 = n2q * 4 + sub;
    if (n2 >= N2_) return;
    int c = cq * 4;

    float C17[17], S17[17];
#pragma unroll
    for (int r = 0; r < 17; ++r) {
        float s, cth; sincosf(W_17 * (float)r, &s, &cth);
        C17[r] = cth; S17[r] = s;
    }

    float4 accr[9], acci[9];
#pragma unroll
    for (int k = 0; k < 9; ++k) {
        accr[k] = make_float4(0.f, 0.f, 0.f, 0.f);
        acci[k] = make_float4(0.f, 0.f, 0.f, 0.f);
    }

    const float* xb = x + (size_t)b * N_ * C_ + c;
#pragma unroll
    for (int n1 = 0; n1 < 17; ++n1) {
        float4 xv = *(const float4*)(xb + (size_t)(n1 * N2_ + n2) * C_);
#pragma unroll
        for (int k1 = 0; k1 < 9; ++k1) {
            int r = (k1 * n1) % 17;       // compile-time after unroll
            float cc = C17[r], ss = S17[r];
            accr[k1].x += xv.x * cc; accr[k1].y += xv.y * cc;
            accr[k1].z += xv.z * cc; accr[k1].w += xv.w * cc;
            if (k1 > 0) {
                acci[k1].x += xv.x * ss; acci[k1].y += xv.y * ss;
                acci[k1].z += xv.z * ss; acci[k1].w += xv.w * ss;
            }
        }
    }

    float* yb = y + ((size_t)(b * 17) * N2_ + n2) * C_ + c;
#pragma unroll
    for (int k1 = 0; k1 < 9; ++k1) {
        float4 o;
        o.x = accr[k1].x * INV_SQRT_N; o.y = accr[k1].y * INV_SQRT_N;
        o.z = accr[k1].z * INV_SQRT_N; o.w = accr[k1].w * INV_SQRT_N;
        *(float4*)(yb + (size_t)k1 * N2_ * C_) = o;
    }
#pragma unroll
    for (int k1 = 1; k1 < 9; ++k1) {
        float4 o;
        o.x = -acci[k1].x * INV_SQRT_N; o.y = -acci[k1].y * INV_SQRT_N;
        o.z = -acci[k1].z * INV_SQRT_N; o.w = -acci[k1].w * INV_SQRT_N;
        *(float4*)(yb + (size_t)(8 + k1) * N2_ * C_) = o;
    }
}

// ---------------------------------------------------------------------------
// ytrans: y f32 planes -> y_t hi/lo bf16 [b][j 0..8][c][q], q=2n2+p, zero pad.
// ---------------------------------------------------------------------------
__global__ __launch_bounds__(256) void k_ytrans(const float* __restrict__ y,
                                                unsigned short* __restrict__ yhi,
                                                unsigned short* __restrict__ ylo) {
    int bid = blockIdx.x;
    int b = bid / 288; int rem = bid % 288;
    int j = rem / 32; int rem2 = rem % 32;
    int kt = rem2 >> 2, ct = rem2 & 3;
    int tid = threadIdx.x;
    __shared__ float lre[32 * 65], lim[32 * 65];
    int cl = tid & 63, rs = tid >> 6;
#pragma unroll
    for (int it = 0; it < 8; ++it) {
        int rowl = it * 4 + rs;           // 0..31
        int n2 = kt * 32 + rowl;
        int cg = ct * 64 + cl;
        float re = 0.f, im = 0.f;
        if (n2 <= 240) {
            re = y[((size_t)((b * 17 + j) * N2_ + n2)) * C_ + cg];
            if (j > 0) im = y[((size_t)((b * 17 + 8 + j) * N2_ + n2)) * C_ + cg];
        }
        lre[rowl * 65 + cl] = re; lim[rowl * 65 + cl] = im;
    }
    __syncthreads();
    int c = tid >> 2, qg = tid & 3;
    unsigned wh[8], wl[8];
#pragma unroll
    for (int i = 0; i < 8; ++i) {
        int rowl = qg * 8 + i;
        float re = lre[rowl * 65 + c], im = lim[rowl * 65 + c];
        unsigned short rh = f2bf(re); float rl = re - bf2f(rh);
        unsigned short ih = f2bf(im); float il = im - bf2f(ih);
        wh[i] = (unsigned)rh | ((unsigned)ih << 16);
        wl[i] = (unsigned)f2bf(rl) | ((unsigned)f2bf(il) << 16);
    }
    size_t ubase = ((size_t)((b * 9 + j) * 256 + ct * 64 + c)) * 256 + kt * 32 + qg * 8;
    uint4 v0; v0.x = wh[0]; v0.y = wh[1]; v0.z = wh[2]; v0.w = wh[3];
    uint4 v1; v1.x = wh[4]; v1.y = wh[5]; v1.z = wh[6]; v1.w = wh[7];
    *(uint4*)((unsigned*)yhi + ubase) = v0;
    *(uint4*)((unsigned*)yhi + ubase + 4) = v1;
    uint4 u0; u0.x = wl[0]; u0.y = wl[1]; u0.z = wl[2]; u0.w = wl[3];
    uint4 u1; u1.x = wl[4]; u1.y = wl[5]; u1.z = wl[6]; u1.w = wl[7];
    *(uint4*)((unsigned*)ylo + ubase) = u0;
    *(uint4*)((unsigned*)ylo + ubase + 4) = u1;
}

// ---------------------------------------------------------------------------
// twB: stageB twiddle A-operand, [k1][m=2t+r][q], bf16 hi/lo.
// ---------------------------------------------------------------------------
__global__ __launch_bounds__(256) void k_twfillB(unsigned short* __restrict__ hi,
                                                 unsigned short* __restrict__ lo) {
    int m = blockIdx.x & 255; int k1 = blockIdx.x >> 8;   // grid 17*256
    int n2 = threadIdx.x;
    int t = m >> 1, r = m & 1;
    int f = k1 + 17 * t;
    unsigned ph = 0u, pl = 0u;
    if (t <= 120 && f < F_ && n2 <= 240) {
        float s_ = (k1 <= 8) ? 1.f : -1.f;
        int rr = (f * n2) % N_;
        float sn, cs; sincosf(W_N * (float)rr, &sn, &cs);
        float a0 = (r == 0) ? cs : -sn;
        float a1 = (r == 0) ? s_ * sn : s_ * cs;
        unsigned short h0 = f2bf(a0); float l0 = a0 - bf2f(h0);
        unsigned short h1 = f2bf(a1); float l1 = a1 - bf2f(h1);
        ph = (unsigned)h0 | ((unsigned)h1 << 16);
        pl = (unsigned)f2bf(l0) | ((unsigned)f2bf(l1) << 16);
    }
    size_t ub = ((size_t)(k1 * 256 + m)) * 256 + n2;
    *((unsigned*)hi + ub) = ph;
    *((unsigned*)lo + ub) = pl;
}

// ---------------------------------------------------------------------------
// Stage B v2: LDS-staged split-bf16 MFMA GEMM (m97 structure).
// Per (b,j): OUT[m][c] = sum_q twB[k1(m)][m][q] * y_t[b][j][c][q],
// acc += Ah*Bh + Al*Bh + Ah*Bl.  Tile 128(m) x 128(c), BK=32, 4 waves 2x2.
// Staging via global_load_lds w16 with source-side XOR swizzle
// (chunk ^= (row>>1)&3) -> conflict-free ds_read_b128.
// Energy: block-partial (128 c) reduce + atomicAdd (2 contributions/(b,f)).
// grid 2176 = B*68, chunk-swizzled.
// ---------------------------------------------------------------------------
__global__ __launch_bounds__(256) void k_stageB_v2(
        const short* __restrict__ yt_hi, const short* __restrict__ yt_lo,
        const short* __restrict__ twb_hi, const short* __restrict__ twb_lo,
        unsigned short* __restrict__ X, float* __restrict__ energy) {
    int bid = (blockIdx.x & 7) * 272 + (blockIdx.x >> 3);   // 2176 = 8*272
    int b = bid / 68, rem = bid % 68;
    int j, mt, ct;
    if (rem < 4) { j = 0; mt = rem >> 1; ct = rem & 1; }
    else { int r2 = rem - 4; j = 1 + (r2 >> 3); int sub = r2 & 7; mt = sub >> 1; ct = sub & 1; }
    int k1 = (mt < 2) ? j : 17 - j;
    const short* pAh = twb_hi + (size_t)(k1 * 256 + (mt & 1) * 128) * Q_;
    const short* pAl = twb_lo + (size_t)(k1 * 256 + (mt & 1) * 128) * Q_;
    const short* pBh = yt_hi + (size_t)((b * 9 + j) * 256 + ct * 128) * Q_;
    const short* pBl = yt_lo + (size_t)((b * 9 + j) * 256 + ct * 128) * Q_;

    int tid = threadIdx.x, lane = tid & 63, wid = tid >> 6;
    int wr = wid >> 1, wc = wid & 1;
    int l15 = lane & 15, lg = lane >> 4;
    int srow = lane >> 2, sch = lane & 3;     // staging row-in-16 / chunk

    __shared__ __align__(16) short lds[16384];   // Ah|Al|Bh|Bl, each [128][32]
    __shared__ float eL[2][2][4][4][2];

    f32x4 acc[4][4];
#pragma unroll
    for (int rt = 0; rt < 4; ++rt)
#pragma unroll
        for (int nt = 0; nt < 4; ++nt) acc[rt][nt] = (f32x4){0.f, 0.f, 0.f, 0.f};

    for (int ks = 0; ks < 16; ++ks) {
        int q0 = ks * 32;
        // ---- stage 32 KB: 8 wave-rounds, tile = r>>1 ----
#pragma unroll
        for (int r = 0; r < 8; ++r) {
            const short* gp = (r < 2) ? pAh : (r < 4) ? pAl : (r < 6) ? pBh : pBl;
            int row = (r & 1) * 64 + wid * 16 + srow;          // 0..127
            int ch = sch ^ ((row >> 1) & 3);
            gload16(gp + (size_t)row * Q_ + q0 + ch * 8,
                    &lds[(r * 4 + wid) * 512]);
        }
        __syncthreads();
        // ---- fragments + MFMA ----
        short8v Ah[4], Al[4], Bh[4], Bl[4];
#pragma unroll
        for (int rt = 0; rt < 4; ++rt) {
            int row = wr * 64 + rt * 16 + l15;
            int u = row * 4 + (lg ^ ((row >> 1) & 3));
            Ah[rt] = *(const short8v*)&lds[u * 8];
            Al[rt] = *(const short8v*)&lds[4096 + u * 8];
        }
#pragma unroll
        for (int nt = 0; nt < 4; ++nt) {
            int row = wc * 64 + nt * 16 + l15;
            int u = row * 4 + (lg ^ ((row >> 1) & 3));
            Bh[nt] = *(const short8v*)&lds[8192 + u * 8];
            Bl[nt] = *(const short8v*)&lds[12288 + u * 8];
        }
#pragma unroll
        for (int rt = 0; rt < 4; ++rt)
#pragma unroll
            for (int nt = 0; nt < 4; ++nt) {
                acc[rt][nt] = __builtin_amdgcn_mfma_f32_16x16x32_bf16(
                    Ah[rt], Bh[nt], acc[rt][nt], 0, 0, 0);
                acc[rt][nt] = __builtin_amdgcn_mfma_f32_16x16x32_bf16(
                    Al[rt], Bh[nt], acc[rt][nt], 0, 0, 0);
                acc[rt][nt] = __builtin_amdgcn_mfma_f32_16x16x32_bf16(
                    Ah[rt], Bl[nt], acc[rt][nt], 0, 0, 0);
            }
        __syncthreads();
    }

    // ---- energy: partial sum over this block's 128 c, atomicAdd ----
#pragma unroll
    for (int rt = 0; rt < 4; ++rt) {
        float e0 = 0.f, e1 = 0.f;
#pragma unroll
        for (int nt = 0; nt < 4; ++nt) {
            e0 += acc[rt][nt][0] * acc[rt][nt][0] + acc[rt][nt][1] * acc[rt][nt][1];
            e1 += acc[rt][nt][2] * acc[rt][nt][2] + acc[rt][nt][3] * acc[rt][nt][3];
        }
#pragma unroll
        for (int off = 1; off < 16; off <<= 1) {
            e0 += __shfl_xor(e0, off, 64);
            e1 += __shfl_xor(e1, off, 64);
        }
        if (l15 == 0) { eL[wr][wc][rt][lg][0] = e0; eL[wr][wc][rt][lg][1] = e1; }
    }
    __syncthreads();
    if (tid < 64) {
        int wr2 = tid >> 5, rt2 = (tid >> 3) & 3, lg2 = (tid >> 1) & 3, pr = tid & 1;
        int mrow = (mt & 1) * 128 + wr2 * 64 + rt2 * 16 + lg2 * 4 + pr * 2;
        int f = k1 + 17 * (mrow >> 1);
        if (f < F_) {
            float e = eL[wr2][0][rt2][lg2][pr] + eL[wr2][1][rt2][lg2][pr];
            atomicAdd(&energy[b * F_ + f], e);
        }
    }

    // ---- X store (bf16) ----
#pragma unroll
    for (int rt = 0; rt < 4; ++rt) {
#pragma unroll
        for (int jj = 0; jj < 4; ++jj) {
            int mrow = (mt & 1) * 128 + wr * 64 + rt * 16 + lg * 4 + jj;
            int t = mrow >> 1, p = mrow & 1;
            int f = k1 + 17 * t;
            if (f < F_) {
                size_t base = ((size_t)((b * F_ + f) * 2 + p)) * C_ + ct * 128 + wc * 64 + l15;
#pragma unroll
                for (int nt = 0; nt < 4; ++nt)
                    X[base + nt * 16] = f2bf(acc[rt][nt][jj]);
            }
        }
    }
}

// ---------------------------------------------------------------------------
// Median per batch: bitonic sort 2049 energies (padded to 4096), take [1024].
// ---------------------------------------------------------------------------
__global__ __launch_bounds__(256) void k_median(const float* __restrict__ energy,
                                                float* __restrict__ med) {
    __shared__ float buf[4096];
    int b = blockIdx.x;
    int tid = threadIdx.x;
    for (int i = tid; i < 4096; i += 256)
        buf[i] = (i < F_) ? energy[b * F_ + i] : FLT_MAX;
    __syncthreads();
    for (int k = 2; k <= 4096; k <<= 1) {
        for (int jj = k >> 1; jj > 0; jj >>= 1) {
            for (int i = tid; i < 4096; i += 256) {
                int ixj = i ^ jj;
                if (ixj > i) {
                    float a = buf[i], bv = buf[ixj];
                    bool up = ((i & k) == 0);
                    if (up ? (a > bv) : (a < bv)) { buf[i] = bv; buf[ixj] = a; }
                }
            }
            __syncthreads();
        }
    }
    if (tid == 0) med[b] = buf[1024];
}

// ---------------------------------------------------------------------------
// Twiddle table for stage C MFMA:  twA[n][q], n=0..4351, q=0..511, bf16.
// ---------------------------------------------------------------------------
__global__ __launch_bounds__(256) void k_twfill(unsigned short* __restrict__ twA) {
    int n = blockIdx.x;          // 0..4351
    int k2 = threadIdx.x;        // 0..255
    unsigned pack = 0u;
    if (n <= 4096 && k2 <= 240) {
        int rr = (n * k2) % N_;
        float s, cth; sincosf(W_N * (float)rr, &s, &cth);
        pack = (unsigned)f2bf(cth) | ((unsigned)f2bf(-s) << 16);
    }
    *(unsigned*)(twA + (size_t)n * Q_ + 2 * k2) = pack;
}

// ---------------------------------------------------------------------------
// vbuild (tiled): mask + weights + inverse inner 17-point stage.
// Output v_t[b][m2][c][q=2k2+p] bf16 (stride Q_), coalesced via LDS staging.
// ---------------------------------------------------------------------------
__global__ __launch_bounds__(256) void k_vbuild_t(
        const unsigned short* __restrict__ X, const float* __restrict__ energy,
        const float* __restrict__ med, const float* __restrict__ thr,
        const float* __restrict__ cw, const float* __restrict__ cwh,
        unsigned short* __restrict__ vt) {
    int bid = blockIdx.x;            // 32*8*8 = 2048
    int b = bid / 64; int rem = bid % 64;
    int kt = rem >> 3, ct = rem & 7;
    int tid = threadIdx.x;
    int cl = tid & 31, ks = tid >> 5;
    int c = ct * 32 + cl;

    __shared__ unsigned stage[17 * 32 * 33];   // [m2][cl][klocal pad 33]

    float wr = cw[2 * c], wi = cw[2 * c + 1];
    float whr = cwh[2 * c], whi = cwh[2 * c + 1];
    float denom = med[b] + 1e-6f;

    float C17[17], S17[17];
#pragma unroll
    for (int r = 0; r < 17; ++r) {
        float s, cth; sincosf(W_17 * (float)r, &s, &cth);
        C17[r] = cth; S17[r] = s;
    }

    for (int kk = 0; kk < 4; ++kk) {
        int klocal = kk * 8 + ks;
        int k2 = kt * 32 + klocal;
        float vr[17], vi[17];
#pragma unroll
        for (int m = 0; m < 17; ++m) { vr[m] = 0.f; vi[m] = 0.f; }
        if (k2 <= 240) {
#pragma unroll
            for (int s = 0; s < 9; ++s) {
                int f = k2 + 241 * s;
                if (f < F_) {
                    float e = energy[b * F_ + f];
                    float m = (e / denom > thr[f]) ? 1.0f : 0.0f;
                    float wer = wr + m * whr, wei = wi + m * whi;
                    float cf = ((f == 0) ? 1.0f : 2.0f) * INV_SQRT_N;
                    const unsigned short* Xrow = X + ((size_t)(b * F_ + f) * 2) * C_;
                    float Xr = bf2f(Xrow[c]), Xi = bf2f(Xrow[C_ + c]);
                    float Zr = (Xr * wer - Xi * wei) * cf;
                    float Zi = (Xr * wei + Xi * wer) * cf;
#pragma unroll
                    for (int m2 = 0; m2 < 17; ++m2) {
                        int r = (s * m2) % 17;
                        vr[m2] += Zr * C17[r] - Zi * S17[r];
                        vi[m2] += Zr * S17[r] + Zi * C17[r];
                    }
                }
            }
        }
#pragma unroll
        for (int m2 = 0; m2 < 17; ++m2)
            stage[(m2 * 32 + cl) * 33 + klocal] =
                (unsigned)f2bf(vr[m2]) | ((unsigned)f2bf(vi[m2]) << 16);
    }
    __syncthreads();
    unsigned* vt32 = (unsigned*)vt;
    for (int r = tid; r < 544; r += 256) {
        int m2 = r >> 5, c2 = r & 31;
        size_t ubase = ((size_t)((b * 17 + m2) * 256 + ct * 32 + c2)) * 256 + kt * 32;
        const unsigned* srow = &stage[(m2 * 32 + c2) * 33];
#pragma unroll
        for (int g = 0; g < 8; ++g) {
            uint4 w;
            w.x = srow[g * 4]; w.y = srow[g * 4 + 1];
            w.z = srow[g * 4 + 2]; w.w = srow[g * 4 + 3];
            *(uint4*)(vt32 + ubase + g * 4) = w;
        }
    }
}

// ---------------------------------------------------------------------------
// Stage C v2: LDS-staged MFMA GEMM (m97 structure, BK=64).
// Per (b,m2): OUT[m1][c] = sum_q twA[17*m1+m2][q] * v_t[b][m2][c][q].
// Tile 128(m1) x 128(c), 4 waves 2x2, BK=64 (2 k-slices per frag row).
// Source-side XOR swizzle chunk ^= (row>>1)&7 (8 chunks of 16B per row).
// grid 2176 = B*68, chunk-swizzled.
// ---------------------------------------------------------------------------
__global__ __launch_bounds__(256) void k_stageC_v2(const short* __restrict__ vt,
                                                   const short* __restrict__ twA,
                                                   float* __restrict__ out) {
    int bid = (blockIdx.x & 7) * 272 + (blockIdx.x >> 3);
    int b = bid / 68, rem = bid % 68;
    int m2 = rem >> 2, mt = (rem >> 1) & 1, ct = rem & 1;

    int tid = threadIdx.x, lane = tid & 63, wid = tid >> 6;
    int wr = wid >> 1, wc = wid & 1;
    int l15 = lane & 15, lg = lane >> 4;
    int srow = lane >> 3, sch = lane & 7;      // staging: 8 rows x 8 chunks

    const short* vtb = vt + (size_t)((b * 17 + m2) * 256 + ct * 128) * Q_;

    __shared__ __align__(16) short lds[16384];   // A [128][64] | B [128][64]

    f32x4 acc[4][4];
#pragma unroll
    for (int rt = 0; rt < 4; ++rt)
#pragma unroll
        for (int nt = 0; nt < 4; ++nt) acc[rt][nt] = (f32x4){0.f, 0.f, 0.f, 0.f};

    for (int ks = 0; ks < 8; ++ks) {
        int q0 = ks * 64;
        // ---- stage 32 KB: 8 wave-rounds (r<4 -> A, else B) ----
#pragma unroll
        for (int r = 0; r < 8; ++r) {
            int row = (r & 3) * 32 + wid * 8 + srow;           // 0..127
            int ch = sch ^ ((row >> 1) & 7);
            const short* g;
            if (r < 4) {
                int n = 17 * (mt * 128 + row) + m2;
                g = twA + (size_t)n * Q_ + q0 + ch * 8;
            } else {
                g = vtb + (size_t)row * Q_ + q0 + ch * 8;
            }
            gload16(g, &lds[(r * 4 + wid) * 512]);
        }
        __syncthreads();
        // ---- fragments + MFMA (2 k-slices) ----
        short8v a[2][4], bb[2][4];
#pragma unroll
        for (int rt = 0; rt < 4; ++rt) {
            int row = wr * 64 + rt * 16 + l15;
            int s = (row >> 1) & 7;
            a[0][rt] = *(const short8v*)&lds[(row * 8 + (lg ^ s)) * 8];
            a[1][rt] = *(const short8v*)&lds[(row * 8 + ((4 + lg) ^ s)) * 8];
        }
#pragma unroll
        for (int nt = 0; nt < 4; ++nt) {
            int row = wc * 64 + nt * 16 + l15;
            int s = (row >> 1) & 7;
            bb[0][nt] = *(const short8v*)&lds[8192 + (row * 8 + (lg ^ s)) * 8];
            bb[1][nt] = *(const short8v*)&lds[8192 + (row * 8 + ((4 + lg) ^ s)) * 8];
        }
#pragma unroll
        for (int kh = 0; kh < 2; ++kh)
#pragma unroll
            for (int rt = 0; rt < 4; ++rt)
#pragma unroll
                for (int nt = 0; nt < 4; ++nt)
                    acc[rt][nt] = __builtin_amdgcn_mfma_f32_16x16x32_bf16(
                        a[kh][rt], bb[kh][nt], acc[rt][nt], 0, 0, 0);
        __syncthreads();
    }

#pragma unroll
    for (int rt = 0; rt < 4; ++rt) {
#pragma unroll
        for (int jj = 0; jj < 4; ++jj) {
            int m1 = mt * 128 + wr * 64 + rt * 16 + lg * 4 + jj;
            if (m1 < N2_) {
                int n = 17 * m1 + m2;
                float* orow = out + ((size_t)b * N_ + n) * C_ + ct * 128 + wc * 64;
#pragma unroll
                for (int nt = 0; nt < 4; ++nt)
                    orow[nt * 16 + l15] = acc[rt][nt][jj];
            }
        }
    }
}

// ---------------------------------------------------------------------------
extern "C" void kernel_launch(void* const* d_in, const int* in_sizes, int n_in,
                              void* d_out, int out_size, void* d_ws, size_t ws_size,
                              hipStream_t stream) {
    const float* x   = (const float*)d_in[0];
    const float* cw  = (const float*)d_in[1];
    const float* cwh = (const float*)d_in[2];
    const float* thr = (const float*)d_in[3];
    float* out = (float*)d_out;

    // workspace (~231.8 MB), v_t aliases the dead y_t region:
    //   X     bf16 [B][F][2][C]          :  67,141,632
    //   SH    region (y_t_hi + y_t_lo | v_t):
    //     y_t_hi bf16 [B][9][256][512]   :  75,497,472
    //     y_t_lo bf16                    :  75,497,472
    //     v_t    bf16 [B][17][256][512]  : 142,606,336 (aliased at SH base)
    //   twA   bf16 [4352][512]           :   4,456,448
    //   twB_hi/lo bf16 [17][256][512]    :   4,456,448 each
    //   energy f32 [B][F]                :     262,272
    //   med    f32 [B]                   :         128
    char* ws = (char*)d_ws;
    unsigned short* Xb    = (unsigned short*)ws;
    char* sh = ws + 67141632ull;
    unsigned short* ythi  = (unsigned short*)sh;
    unsigned short* ytlo  = (unsigned short*)(sh + 75497472ull);
    unsigned short* vtb   = (unsigned short*)sh;                 // alias
    char* tail = sh + 150994944ull;
    unsigned short* twA   = (unsigned short*)tail;
    unsigned short* twBh  = (unsigned short*)(tail + 4456448ull);
    unsigned short* twBl  = (unsigned short*)(tail + 8912896ull);
    float* energy = (float*)(tail + 13369344ull);
    float* med    = (float*)(tail + 13369344ull + 262272ull);

    hipMemsetAsync(energy, 0, B_ * F_ * sizeof(float), stream);
    k_twfill<<<TWROWS, 256, 0, stream>>>(twA);
    k_twfillB<<<17 * 256, 256, 0, stream>>>(twBh, twBl);
    k_stageA<<<B_ * 61, 256, 0, stream>>>(x, out);
    k_ytrans<<<B_ * 9 * 32, 256, 0, stream>>>(out, ythi, ytlo);
    k_stageB_v2<<<B_ * 68, 256, 0, stream>>>((const short*)ythi, (const short*)ytlo,
                                             (const short*)twBh, (const short*)twBl,
                                             Xb, energy);
    k_median<<<B_, 256, 0, stream>>>(energy, med);
    k_vbuild_t<<<B_ * 64, 256, 0, stream>>>(Xb, energy, med, thr, cw, cwh, vtb);
    k_stageC_v2<<<B_ * 68, 256, 0, stream>>>((const short*)vtb, (const short*)twA, out);
}

// Round 5
// 445.368 us; speedup vs baseline: 3.2337x; 1.3400x over previous
//
#include <hip/hip_runtime.h>
#include <math.h>
#include <float.h>

#define B_ 32
#define N_ 4097
#define C_ 256
#define F_ 2049
#define N2_ 241
#define Q_ 512                        // padded K (q = 2*n2 + p, zeros q>=482)
#define TWROWS 4352                   // stageC twiddle rows (m1-tail padded)
#define INV_SQRT_N 0.0156230927f      // 1/sqrt(4097)
#define W_N 0.0015336063f             // 2*pi/4097
#define W_17 0.36959913571644626f     // 2*pi/17

typedef __attribute__((ext_vector_type(8))) short short8v;
typedef __attribute__((ext_vector_type(4))) float f32x4;

__device__ __forceinline__ float bf2f(unsigned short u) {
    return __uint_as_float(((unsigned)u) << 16);
}
__device__ __forceinline__ unsigned short f2bf(float v) {
    unsigned u = __float_as_uint(v);
    u += 0x7FFFu + ((u >> 16) & 1u);
    return (unsigned short)(u >> 16);
}
__device__ __forceinline__ void gload16(const void* gptr, void* ldsptr) {
    __builtin_amdgcn_global_load_lds(
        (const __attribute__((address_space(1))) void*)gptr,
        (__attribute__((address_space(3))) void*)ldsptr,
        16, 0, 0);
}

// ---------------------------------------------------------------------------
// Stage A: 17-point real DFTs.  x[B][N][C] f32 -> y planes [B][17][241][C] f32
// planes 0..8 = Re y[k1], planes 9..16 = Im y[k1] (k1=1..8).  1/sqrt(N) folded.
// y lives in d_out (17*241 == 4097).
// ---------------------------------------------------------------------------
__global__ __launch_bounds__(256) void k_stageA(const float* __restrict__ x,
                                                float* __restrict__ y) {
    int bid = blockIdx.x;                 // B*61
    int b = bid / 61, n2q = bid % 61;
    int tid = threadIdx.x;
    int cq = tid & 63, sub = tid >> 6;
    int n2 = n2q * 4 + sub;
    if (n2 >= N2_) return;
    int c = cq * 4;

    float C17[17], S17[17];
#pragma unroll
    for (int r = 0; r < 17; ++r) {
        float s, cth; sincosf(W_17 * (float)r, &s, &cth);
        C17[r] = cth; S17[r] = s;
    }

    float4 accr[9], acci[9];
#pragma unroll
    for (int k = 0; k < 9; ++k) {
        accr[k] = make_float4(0.f, 0.f, 0.f, 0.f);
        acci[k] = make_float4(0.f, 0.f, 0.f, 0.f);
    }

    const float* xb = x + (size_t)b * N_ * C_ + c;
#pragma unroll
    for (int n1 = 0; n1 < 17; ++n1) {
        float4 xv = *(const float4*)(xb + (size_t)(n1 * N2_ + n2) * C_);
#pragma unroll
        for (int k1 = 0; k1 < 9; ++k1) {
            int r = (k1 * n1) % 17;       // compile-time after unroll
            float cc = C17[r], ss = S17[r];
            accr[k1].x += xv.x * cc; accr[k1].y += xv.y * cc;
            accr[k1].z += xv.z * cc; accr[k1].w += xv.w * cc;
            if (k1 > 0) {
                acci[k1].x += xv.x * ss; acci[k1].y += xv.y * ss;
                acci[k1].z += xv.z * ss; acci[k1].w += xv.w * ss;
            }
        }
    }

    float* yb = y + ((size_t)(b * 17) * N2_ + n2) * C_ + c;
#pragma unroll
    for (int k1 = 0; k1 < 9; ++k1) {
        float4 o;
        o.x = accr[k1].x * INV_SQRT_N; o.y = accr[k1].y * INV_SQRT_N;
        o.z = accr[k1].z * INV_SQRT_N; o.w = accr[k1].w * INV_SQRT_N;
        *(float4*)(yb + (size_t)k1 * N2_ * C_) = o;
    }
#pragma unroll
    for (int k1 = 1; k1 < 9; ++k1) {
        float4 o;
        o.x = -acci[k1].x * INV_SQRT_N; o.y = -acci[k1].y * INV_SQRT_N;
        o.z = -acci[k1].z * INV_SQRT_N; o.w = -acci[k1].w * INV_SQRT_N;
        *(float4*)(yb + (size_t)(8 + k1) * N2_ * C_) = o;
    }
}

// ---------------------------------------------------------------------------
// ytrans: y f32 planes -> y_t hi/lo bf16 [b][j 0..8][c][q], q=2n2+p, zero pad.
// ---------------------------------------------------------------------------
__global__ __launch_bounds__(256) void k_ytrans(const float* __restrict__ y,
                                                unsigned short* __restrict__ yhi,
                                                unsigned short* __restrict__ ylo) {
    int bid = blockIdx.x;
    int b = bid / 288; int rem = bid % 288;
    int j = rem / 32; int rem2 = rem % 32;
    int kt = rem2 >> 2, ct = rem2 & 3;
    int tid = threadIdx.x;
    __shared__ float lre[32 * 65], lim[32 * 65];
    int cl = tid & 63, rs = tid >> 6;
#pragma unroll
    for (int it = 0; it < 8; ++it) {
        int rowl = it * 4 + rs;           // 0..31
        int n2 = kt * 32 + rowl;
        int cg = ct * 64 + cl;
        float re = 0.f, im = 0.f;
        if (n2 <= 240) {
            re = y[((size_t)((b * 17 + j) * N2_ + n2)) * C_ + cg];
            if (j > 0) im = y[((size_t)((b * 17 + 8 + j) * N2_ + n2)) * C_ + cg];
        }
        lre[rowl * 65 + cl] = re; lim[rowl * 65 + cl] = im;
    }
    __syncthreads();
    int c = tid >> 2, qg = tid & 3;
    unsigned wh[8], wl[8];
#pragma unroll
    for (int i = 0; i < 8; ++i) {
        int rowl = qg * 8 + i;
        float re = lre[rowl * 65 + c], im = lim[rowl * 65 + c];
        unsigned short rh = f2bf(re); float rl = re - bf2f(rh);
        unsigned short ih = f2bf(im); float il = im - bf2f(ih);
        wh[i] = (unsigned)rh | ((unsigned)ih << 16);
        wl[i] = (unsigned)f2bf(rl) | ((unsigned)f2bf(il) << 16);
    }
    size_t ubase = ((size_t)((b * 9 + j) * 256 + ct * 64 + c)) * 256 + kt * 32 + qg * 8;
    uint4 v0; v0.x = wh[0]; v0.y = wh[1]; v0.z = wh[2]; v0.w = wh[3];
    uint4 v1; v1.x = wh[4]; v1.y = wh[5]; v1.z = wh[6]; v1.w = wh[7];
    *(uint4*)((unsigned*)yhi + ubase) = v0;
    *(uint4*)((unsigned*)yhi + ubase + 4) = v1;
    uint4 u0; u0.x = wl[0]; u0.y = wl[1]; u0.z = wl[2]; u0.w = wl[3];
    uint4 u1; u1.x = wl[4]; u1.y = wl[5]; u1.z = wl[6]; u1.w = wl[7];
    *(uint4*)((unsigned*)ylo + ubase) = u0;
    *(uint4*)((unsigned*)ylo + ubase + 4) = u1;
}

// ---------------------------------------------------------------------------
// twB: stageB twiddle A-operand, [k1][m=2t+r][q], bf16 hi/lo.
// ---------------------------------------------------------------------------
__global__ __launch_bounds__(256) void k_twfillB(unsigned short* __restrict__ hi,
                                                 unsigned short* __restrict__ lo) {
    int m = blockIdx.x & 255; int k1 = blockIdx.x >> 8;   // grid 17*256
    int n2 = threadIdx.x;
    int t = m >> 1, r = m & 1;
    int f = k1 + 17 * t;
    unsigned ph = 0u, pl = 0u;
    if (t <= 120 && f < F_ && n2 <= 240) {
        float s_ = (k1 <= 8) ? 1.f : -1.f;
        int rr = (f * n2) % N_;
        float sn, cs; sincosf(W_N * (float)rr, &sn, &cs);
        float a0 = (r == 0) ? cs : -sn;
        float a1 = (r == 0) ? s_ * sn : s_ * cs;
        unsigned short h0 = f2bf(a0); float l0 = a0 - bf2f(h0);
        unsigned short h1 = f2bf(a1); float l1 = a1 - bf2f(h1);
        ph = (unsigned)h0 | ((unsigned)h1 << 16);
        pl = (unsigned)f2bf(l0) | ((unsigned)f2bf(l1) << 16);
    }
    size_t ub = ((size_t)(k1 * 256 + m)) * 256 + n2;
    *((unsigned*)hi + ub) = ph;
    *((unsigned*)lo + ub) = pl;
}

// ---------------------------------------------------------------------------
// Stage B v2: LDS-staged split-bf16 MFMA GEMM (m97 structure).
// ---------------------------------------------------------------------------
__global__ __launch_bounds__(256) void k_stageB_v2(
        const short* __restrict__ yt_hi, const short* __restrict__ yt_lo,
        const short* __restrict__ twb_hi, const short* __restrict__ twb_lo,
        unsigned short* __restrict__ X, float* __restrict__ energy) {
    int bid = (blockIdx.x & 7) * 272 + (blockIdx.x >> 3);   // 2176 = 8*272
    int b = bid / 68, rem = bid % 68;
    int j, mt, ct;
    if (rem < 4) { j = 0; mt = rem >> 1; ct = rem & 1; }
    else { int r2 = rem - 4; j = 1 + (r2 >> 3); int sub = r2 & 7; mt = sub >> 1; ct = sub & 1; }
    int k1 = (mt < 2) ? j : 17 - j;
    const short* pAh = twb_hi + (size_t)(k1 * 256 + (mt & 1) * 128) * Q_;
    const short* pAl = twb_lo + (size_t)(k1 * 256 + (mt & 1) * 128) * Q_;
    const short* pBh = yt_hi + (size_t)((b * 9 + j) * 256 + ct * 128) * Q_;
    const short* pBl = yt_lo + (size_t)((b * 9 + j) * 256 + ct * 128) * Q_;

    int tid = threadIdx.x, lane = tid & 63, wid = tid >> 6;
    int wr = wid >> 1, wc = wid & 1;
    int l15 = lane & 15, lg = lane >> 4;
    int srow = lane >> 2, sch = lane & 3;     // staging row-in-16 / chunk

    __shared__ __align__(16) short lds[16384];   // Ah|Al|Bh|Bl, each [128][32]
    __shared__ float eL[2][2][4][4][2];

    f32x4 acc[4][4];
#pragma unroll
    for (int rt = 0; rt < 4; ++rt)
#pragma unroll
        for (int nt = 0; nt < 4; ++nt) acc[rt][nt] = (f32x4){0.f, 0.f, 0.f, 0.f};

    for (int ks = 0; ks < 16; ++ks) {
        int q0 = ks * 32;
        // ---- stage 32 KB: 8 wave-rounds, tile = r>>1 ----
#pragma unroll
        for (int r = 0; r < 8; ++r) {
            const short* gp = (r < 2) ? pAh : (r < 4) ? pAl : (r < 6) ? pBh : pBl;
            int row = (r & 1) * 64 + wid * 16 + srow;          // 0..127
            int ch = sch ^ ((row >> 1) & 3);
            gload16(gp + (size_t)row * Q_ + q0 + ch * 8,
                    &lds[(r * 4 + wid) * 512]);
        }
        __syncthreads();
        // ---- fragments + MFMA ----
        short8v Ah[4], Al[4], Bh[4], Bl[4];
#pragma unroll
        for (int rt = 0; rt < 4; ++rt) {
            int row = wr * 64 + rt * 16 + l15;
            int u = row * 4 + (lg ^ ((row >> 1) & 3));
            Ah[rt] = *(const short8v*)&lds[u * 8];
            Al[rt] = *(const short8v*)&lds[4096 + u * 8];
        }
#pragma unroll
        for (int nt = 0; nt < 4; ++nt) {
            int row = wc * 64 + nt * 16 + l15;
            int u = row * 4 + (lg ^ ((row >> 1) & 3));
            Bh[nt] = *(const short8v*)&lds[8192 + u * 8];
            Bl[nt] = *(const short8v*)&lds[12288 + u * 8];
        }
#pragma unroll
        for (int rt = 0; rt < 4; ++rt)
#pragma unroll
            for (int nt = 0; nt < 4; ++nt) {
                acc[rt][nt] = __builtin_amdgcn_mfma_f32_16x16x32_bf16(
                    Ah[rt], Bh[nt], acc[rt][nt], 0, 0, 0);
                acc[rt][nt] = __builtin_amdgcn_mfma_f32_16x16x32_bf16(
                    Al[rt], Bh[nt], acc[rt][nt], 0, 0, 0);
                acc[rt][nt] = __builtin_amdgcn_mfma_f32_16x16x32_bf16(
                    Ah[rt], Bl[nt], acc[rt][nt], 0, 0, 0);
            }
        __syncthreads();
    }

    // ---- energy: partial sum over this block's 128 c, atomicAdd ----
#pragma unroll
    for (int rt = 0; rt < 4; ++rt) {
        float e0 = 0.f, e1 = 0.f;
#pragma unroll
        for (int nt = 0; nt < 4; ++nt) {
            e0 += acc[rt][nt][0] * acc[rt][nt][0] + acc[rt][nt][1] * acc[rt][nt][1];
            e1 += acc[rt][nt][2] * acc[rt][nt][2] + acc[rt][nt][3] * acc[rt][nt][3];
        }
#pragma unroll
        for (int off = 1; off < 16; off <<= 1) {
            e0 += __shfl_xor(e0, off, 64);
            e1 += __shfl_xor(e1, off, 64);
        }
        if (l15 == 0) { eL[wr][wc][rt][lg][0] = e0; eL[wr][wc][rt][lg][1] = e1; }
    }
    __syncthreads();
    if (tid < 64) {
        int wr2 = tid >> 5, rt2 = (tid >> 3) & 3, lg2 = (tid >> 1) & 3, pr = tid & 1;
        int mrow = (mt & 1) * 128 + wr2 * 64 + rt2 * 16 + lg2 * 4 + pr * 2;
        int f = k1 + 17 * (mrow >> 1);
        if (f < F_) {
            float e = eL[wr2][0][rt2][lg2][pr] + eL[wr2][1][rt2][lg2][pr];
            atomicAdd(&energy[b * F_ + f], e);
        }
    }

    // ---- X store (bf16) ----
#pragma unroll
    for (int rt = 0; rt < 4; ++rt) {
#pragma unroll
        for (int jj = 0; jj < 4; ++jj) {
            int mrow = (mt & 1) * 128 + wr * 64 + rt * 16 + lg * 4 + jj;
            int t = mrow >> 1, p = mrow & 1;
            int f = k1 + 17 * t;
            if (f < F_) {
                size_t base = ((size_t)((b * F_ + f) * 2 + p)) * C_ + ct * 128 + wc * 64 + l15;
#pragma unroll
                for (int nt = 0; nt < 4; ++nt)
                    X[base + nt * 16] = f2bf(acc[rt][nt][jj]);
            }
        }
    }
}

// ---------------------------------------------------------------------------
// Median per batch via exact 4-pass radix select (energies >= 0 so uint order
// == float order).  rank 1024 of 2049 == np.sort(...)[1024].  Value is
// reconstructed bit-exactly from the selected digits.
// ---------------------------------------------------------------------------
__global__ __launch_bounds__(256) void k_median(const float* __restrict__ energy,
                                                float* __restrict__ med) {
    int b = blockIdx.x, tid = threadIdx.x;
    __shared__ unsigned vals[F_];
    __shared__ unsigned hist[256];
    __shared__ unsigned scanbuf[256];
    __shared__ unsigned sh_prefix;
    __shared__ int sh_rank;
    for (int i = tid; i < F_; i += 256)
        vals[i] = __float_as_uint(energy[b * F_ + i]);
    if (tid == 0) { sh_prefix = 0u; sh_rank = 1024; }
    __syncthreads();
#pragma unroll
    for (int shift = 24; shift >= 0; shift -= 8) {
        hist[tid] = 0u;
        __syncthreads();
        unsigned prefix = sh_prefix;
        unsigned hmask = (shift == 24) ? 0u : (0xFFFFFFFFu << (shift + 8));
        for (int i = tid; i < F_; i += 256) {
            unsigned v = vals[i];
            if (((v ^ prefix) & hmask) == 0u)
                atomicAdd(&hist[(v >> shift) & 255], 1u);
        }
        __syncthreads();
        scanbuf[tid] = hist[tid];
        __syncthreads();
#pragma unroll
        for (int off = 1; off < 256; off <<= 1) {
            unsigned y = (tid >= off) ? scanbuf[tid - off] : 0u;
            __syncthreads();
            scanbuf[tid] += y;
            __syncthreads();
        }
        int rank = sh_rank;
        unsigned cumP = (tid == 0) ? 0u : scanbuf[tid - 1];
        unsigned cumI = scanbuf[tid];
        __syncthreads();
        if ((unsigned)rank >= cumP && (unsigned)rank < cumI) {
            sh_prefix = prefix | ((unsigned)tid << shift);
            sh_rank = rank - (int)cumP;
        }
        __syncthreads();
    }
    if (tid == 0) med[b] = __uint_as_float(sh_prefix);
}

// ---------------------------------------------------------------------------
// Twiddle table for stage C MFMA:  twA[n][q], n=0..4351, q=0..511, bf16.
// ---------------------------------------------------------------------------
__global__ __launch_bounds__(256) void k_twfill(unsigned short* __restrict__ twA) {
    int n = blockIdx.x;          // 0..4351
    int k2 = threadIdx.x;        // 0..255
    unsigned pack = 0u;
    if (n <= 4096 && k2 <= 240) {
        int rr = (n * k2) % N_;
        float s, cth; sincosf(W_N * (float)rr, &s, &cth);
        pack = (unsigned)f2bf(cth) | ((unsigned)f2bf(-s) << 16);
    }
    *(unsigned*)(twA + (size_t)n * Q_ + 2 * k2) = pack;
}

// ---------------------------------------------------------------------------
// vbuild (tiled): mask + weights + inverse inner 17-point stage.
// Output v_t[b][m2][c][q=2k2+p] bf16 (stride Q_), coalesced via LDS staging.
// ---------------------------------------------------------------------------
__global__ __launch_bounds__(256) void k_vbuild_t(
        const unsigned short* __restrict__ X, const float* __restrict__ energy,
        const float* __restrict__ med, const float* __restrict__ thr,
        const float* __restrict__ cw, const float* __restrict__ cwh,
        unsigned short* __restrict__ vt) {
    int bid = blockIdx.x;            // 32*8*8 = 2048
    int b = bid / 64; int rem = bid % 64;
    int kt = rem >> 3, ct = rem & 7;
    int tid = threadIdx.x;
    int cl = tid & 31, ks = tid >> 5;
    int c = ct * 32 + cl;

    __shared__ unsigned stage[17 * 32 * 33];   // [m2][cl][klocal pad 33]

    float wr = cw[2 * c], wi = cw[2 * c + 1];
    float whr = cwh[2 * c], whi = cwh[2 * c + 1];
    float denom = med[b] + 1e-6f;

    float C17[17], S17[17];
#pragma unroll
    for (int r = 0; r < 17; ++r) {
        float s, cth; sincosf(W_17 * (float)r, &s, &cth);
        C17[r] = cth; S17[r] = s;
    }

    for (int kk = 0; kk < 4; ++kk) {
        int klocal = kk * 8 + ks;
        int k2 = kt * 32 + klocal;
        float vr[17], vi[17];
#pragma unroll
        for (int m = 0; m < 17; ++m) { vr[m] = 0.f; vi[m] = 0.f; }
        if (k2 <= 240) {
#pragma unroll
            for (int s = 0; s < 9; ++s) {
                int f = k2 + 241 * s;
                if (f < F_) {
                    float e = energy[b * F_ + f];
                    float m = (e / denom > thr[f]) ? 1.0f : 0.0f;
                    float wer = wr + m * whr, wei = wi + m * whi;
                    float cf = ((f == 0) ? 1.0f : 2.0f) * INV_SQRT_N;
                    const unsigned short* Xrow = X + ((size_t)(b * F_ + f) * 2) * C_;
                    float Xr = bf2f(Xrow[c]), Xi = bf2f(Xrow[C_ + c]);
                    float Zr = (Xr * wer - Xi * wei) * cf;
                    float Zi = (Xr * wei + Xi * wer) * cf;
#pragma unroll
                    for (int m2 = 0; m2 < 17; ++m2) {
                        int r = (s * m2) % 17;
                        vr[m2] += Zr * C17[r] - Zi * S17[r];
                        vi[m2] += Zr * S17[r] + Zi * C17[r];
                    }
                }
            }
        }
#pragma unroll
        for (int m2 = 0; m2 < 17; ++m2)
            stage[(m2 * 32 + cl) * 33 + klocal] =
                (unsigned)f2bf(vr[m2]) | ((unsigned)f2bf(vi[m2]) << 16);
    }
    __syncthreads();
    unsigned* vt32 = (unsigned*)vt;
    for (int r = tid; r < 544; r += 256) {
        int m2 = r >> 5, c2 = r & 31;
        size_t ubase = ((size_t)((b * 17 + m2) * 256 + ct * 32 + c2)) * 256 + kt * 32;
        const unsigned* srow = &stage[(m2 * 32 + c2) * 33];
#pragma unroll
        for (int g = 0; g < 8; ++g) {
            uint4 w;
            w.x = srow[g * 4]; w.y = srow[g * 4 + 1];
            w.z = srow[g * 4 + 2]; w.w = srow[g * 4 + 3];
            *(uint4*)(vt32 + ubase + g * 4) = w;
        }
    }
}

// ---------------------------------------------------------------------------
// Stage C v2: LDS-staged MFMA GEMM (m97 structure, BK=64).
// ---------------------------------------------------------------------------
__global__ __launch_bounds__(256) void k_stageC_v2(const short* __restrict__ vt,
                                                   const short* __restrict__ twA,
                                                   float* __restrict__ out) {
    int bid = (blockIdx.x & 7) * 272 + (blockIdx.x >> 3);
    int b = bid / 68, rem = bid % 68;
    int m2 = rem >> 2, mt = (rem >> 1) & 1, ct = rem & 1;

    int tid = threadIdx.x, lane = tid & 63, wid = tid >> 6;
    int wr = wid >> 1, wc = wid & 1;
    int l15 = lane & 15, lg = lane >> 4;
    int srow = lane >> 3, sch = lane & 7;      // staging: 8 rows x 8 chunks

    const short* vtb = vt + (size_t)((b * 17 + m2) * 256 + ct * 128) * Q_;

    __shared__ __align__(16) short lds[16384];   // A [128][64] | B [128][64]

    f32x4 acc[4][4];
#pragma unroll
    for (int rt = 0; rt < 4; ++rt)
#pragma unroll
        for (int nt = 0; nt < 4; ++nt) acc[rt][nt] = (f32x4){0.f, 0.f, 0.f, 0.f};

    for (int ks = 0; ks < 8; ++ks) {
        int q0 = ks * 64;
        // ---- stage 32 KB: 8 wave-rounds (r<4 -> A, else B) ----
#pragma unroll
        for (int r = 0; r < 8; ++r) {
            int row = (r & 3) * 32 + wid * 8 + srow;           // 0..127
            int ch = sch ^ ((row >> 1) & 7);
            const short* g;
            if (r < 4) {
                int n = 17 * (mt * 128 + row) + m2;
                g = twA + (size_t)n * Q_ + q0 + ch * 8;
            } else {
                g = vtb + (size_t)row * Q_ + q0 + ch * 8;
            }
            gload16(g, &lds[(r * 4 + wid) * 512]);
        }
        __syncthreads();
        // ---- fragments + MFMA (2 k-slices) ----
        short8v a[2][4], bb[2][4];
#pragma unroll
        for (int rt = 0; rt < 4; ++rt) {
            int row = wr * 64 + rt * 16 + l15;
            int s = (row >> 1) & 7;
            a[0][rt] = *(const short8v*)&lds[(row * 8 + (lg ^ s)) * 8];
            a[1][rt] = *(const short8v*)&lds[(row * 8 + ((4 + lg) ^ s)) * 8];
        }
#pragma unroll
        for (int nt = 0; nt < 4; ++nt) {
            int row = wc * 64 + nt * 16 + l15;
            int s = (row >> 1) & 7;
            bb[0][nt] = *(const short8v*)&lds[8192 + (row * 8 + (lg ^ s)) * 8];
            bb[1][nt] = *(const short8v*)&lds[8192 + (row * 8 + ((4 + lg) ^ s)) * 8];
        }
#pragma unroll
        for (int kh = 0; kh < 2; ++kh)
#pragma unroll
            for (int rt = 0; rt < 4; ++rt)
#pragma unroll
                for (int nt = 0; nt < 4; ++nt)
                    acc[rt][nt] = __builtin_amdgcn_mfma_f32_16x16x32_bf16(
                        a[kh][rt], bb[kh][nt], acc[rt][nt], 0, 0, 0);
        __syncthreads();
    }

#pragma unroll
    for (int rt = 0; rt < 4; ++rt) {
#pragma unroll
        for (int jj = 0; jj < 4; ++jj) {
            int m1 = mt * 128 + wr * 64 + rt * 16 + lg * 4 + jj;
            if (m1 < N2_) {
                int n = 17 * m1 + m2;
                float* orow = out + ((size_t)b * N_ + n) * C_ + ct * 128 + wc * 64;
#pragma unroll
                for (int nt = 0; nt < 4; ++nt)
                    orow[nt * 16 + l15] = acc[rt][nt][jj];
            }
        }
    }
}

// ---------------------------------------------------------------------------
extern "C" void kernel_launch(void* const* d_in, const int* in_sizes, int n_in,
                              void* d_out, int out_size, void* d_ws, size_t ws_size,
                              hipStream_t stream) {
    const float* x   = (const float*)d_in[0];
    const float* cw  = (const float*)d_in[1];
    const float* cwh = (const float*)d_in[2];
    const float* thr = (const float*)d_in[3];
    float* out = (float*)d_out;

    // workspace (~231.8 MB), v_t aliases the dead y_t region:
    //   X     bf16 [B][F][2][C]          :  67,141,632
    //   SH    region (y_t_hi + y_t_lo | v_t):
    //     y_t_hi bf16 [B][9][256][512]   :  75,497,472
    //     y_t_lo bf16                    :  75,497,472
    //     v_t    bf16 [B][17][256][512]  : 142,606,336 (aliased at SH base)
    //   twA   bf16 [4352][512]           :   4,456,448
    //   twB_hi/lo bf16 [17][256][512]    :   4,456,448 each
    //   energy f32 [B][F]                :     262,272
    //   med    f32 [B]                   :         128
    char* ws = (char*)d_ws;
    unsigned short* Xb    = (unsigned short*)ws;
    char* sh = ws + 67141632ull;
    unsigned short* ythi  = (unsigned short*)sh;
    unsigned short* ytlo  = (unsigned short*)(sh + 75497472ull);
    unsigned short* vtb   = (unsigned short*)sh;                 // alias
    char* tail = sh + 150994944ull;
    unsigned short* twA   = (unsigned short*)tail;
    unsigned short* twBh  = (unsigned short*)(tail + 4456448ull);
    unsigned short* twBl  = (unsigned short*)(tail + 8912896ull);
    float* energy = (float*)(tail + 13369344ull);
    float* med    = (float*)(tail + 13369344ull + 262272ull);

    hipMemsetAsync(energy, 0, B_ * F_ * sizeof(float), stream);
    k_twfill<<<TWROWS, 256, 0, stream>>>(twA);
    k_twfillB<<<17 * 256, 256, 0, stream>>>(twBh, twBl);
    k_stageA<<<B_ * 61, 256, 0, stream>>>(x, out);
    k_ytrans<<<B_ * 9 * 32, 256, 0, stream>>>(out, ythi, ytlo);
    k_stageB_v2<<<B_ * 68, 256, 0, stream>>>((const short*)ythi, (const short*)ytlo,
                                             (const short*)twBh, (const short*)twBl,
                                             Xb, energy);
    k_median<<<B_, 256, 0, stream>>>(energy, med);
    k_vbuild_t<<<B_ * 64, 256, 0, stream>>>(Xb, energy, med, thr, cw, cwh, vtb);
    k_stageC_v2<<<B_ * 68, 256, 0, stream>>>((const short*)vtb, (const short*)twA, out);
}

// Round 6
// 401.421 us; speedup vs baseline: 3.5877x; 1.1095x over previous
//
#include <hip/hip_runtime.h>
#include <math.h>
#include <float.h>

#define B_ 32
#define N_ 4097
#define C_ 256
#define F_ 2049
#define N2_ 241
#define Q_ 512                        // padded K (q = 2*n2 + p, zeros q>=482)
#define TWROWS 4352                   // stageC twiddle rows (m1-tail padded)
#define INV_SQRT_N 0.0156230927f      // 1/sqrt(4097)
#define W_N 0.0015336063f             // 2*pi/4097
#define W_17 0.36959913571644626f     // 2*pi/17

typedef __attribute__((ext_vector_type(8))) short short8v;
typedef __attribute__((ext_vector_type(4))) float f32x4;

__device__ __forceinline__ float bf2f(unsigned short u) {
    return __uint_as_float(((unsigned)u) << 16);
}
__device__ __forceinline__ unsigned short f2bf(float v) {
    unsigned u = __float_as_uint(v);
    u += 0x7FFFu + ((u >> 16) & 1u);
    return (unsigned short)(u >> 16);
}
__device__ __forceinline__ void gload16(const void* gptr, void* ldsptr) {
    __builtin_amdgcn_global_load_lds(
        (const __attribute__((address_space(1))) void*)gptr,
        (__attribute__((address_space(3))) void*)ldsptr,
        16, 0, 0);
}

// ---------------------------------------------------------------------------
// Fused Stage A + transpose: x[B][N][C] f32 -> y_t hi/lo bf16 [b][j][c][q].
// 17-point real DFT accumulated in registers (no f32 y round-trip to HBM);
// per-j LDS transpose, packed (re,im) u32 writes, zero pad rows n2>240.
// grid 1024 = B*8(n2t)*4(ct); block 256 = 64 c x 4 row-groups of 8.
// ---------------------------------------------------------------------------
__global__ __launch_bounds__(256) void k_stageA_t(const float* __restrict__ x,
                                                  unsigned short* __restrict__ yhi,
                                                  unsigned short* __restrict__ ylo) {
    int bid = blockIdx.x;
    int b = bid >> 5; int rem = bid & 31;
    int n2t = rem >> 2, ct = rem & 3;
    int tid = threadIdx.x;
    int cl = tid & 63, sub = tid >> 6;
    int c = ct * 64 + cl;

    float C17[17], S17[17];
#pragma unroll
    for (int r = 0; r < 17; ++r) {
        float s, cth; sincosf(W_17 * (float)r, &s, &cth);
        C17[r] = cth; S17[r] = s;
    }

    float ar[9][8], ai[8][8];
#pragma unroll
    for (int k = 0; k < 9; ++k)
#pragma unroll
        for (int i = 0; i < 8; ++i) ar[k][i] = 0.f;
#pragma unroll
    for (int k = 0; k < 8; ++k)
#pragma unroll
        for (int i = 0; i < 8; ++i) ai[k][i] = 0.f;

    const float* xb = x + (size_t)b * N_ * C_ + c;
#pragma unroll
    for (int n1 = 0; n1 < 17; ++n1) {
        float xv[8];
#pragma unroll
        for (int i = 0; i < 8; ++i) {
            int n2 = n2t * 32 + sub * 8 + i;
            xv[i] = (n2 <= 240) ? xb[(size_t)(n1 * N2_ + n2) * C_] : 0.f;
        }
#pragma unroll
        for (int k1 = 0; k1 < 9; ++k1) {
            int r = (k1 * n1) % 17;       // compile-time after unroll
            float cc = C17[r], ss = S17[r];
#pragma unroll
            for (int i = 0; i < 8; ++i) {
                ar[k1][i] += xv[i] * cc;
                if (k1 > 0) ai[k1 - 1][i] += xv[i] * ss;
            }
        }
    }

    __shared__ float lre[32 * 65], lim[32 * 65];
    int c2 = tid >> 2, qg = tid & 3;
#pragma unroll
    for (int j = 0; j < 9; ++j) {
        __syncthreads();                  // protect previous j's reads
#pragma unroll
        for (int i = 0; i < 8; ++i) {
            int row = sub * 8 + i;
            lre[row * 65 + cl] = ar[j][i] * INV_SQRT_N;
            lim[row * 65 + cl] = (j > 0) ? (-ai[j - 1][i] * INV_SQRT_N) : 0.f;
        }
        __syncthreads();
        unsigned wh[8], wl[8];
#pragma unroll
        for (int i = 0; i < 8; ++i) {
            int row = qg * 8 + i;
            float re = lre[row * 65 + c2], im = lim[row * 65 + c2];
            unsigned short rh = f2bf(re); float rl = re - bf2f(rh);
            unsigned short ih = f2bf(im); float il = im - bf2f(ih);
            wh[i] = (unsigned)rh | ((unsigned)ih << 16);
            wl[i] = (unsigned)f2bf(rl) | ((unsigned)f2bf(il) << 16);
        }
        size_t ubase = ((size_t)((b * 9 + j) * 256 + ct * 64 + c2)) * 256 + n2t * 32 + qg * 8;
        uint4 v0; v0.x = wh[0]; v0.y = wh[1]; v0.z = wh[2]; v0.w = wh[3];
        uint4 v1; v1.x = wh[4]; v1.y = wh[5]; v1.z = wh[6]; v1.w = wh[7];
        *(uint4*)((unsigned*)yhi + ubase) = v0;
        *(uint4*)((unsigned*)yhi + ubase + 4) = v1;
        uint4 u0; u0.x = wl[0]; u0.y = wl[1]; u0.z = wl[2]; u0.w = wl[3];
        uint4 u1; u1.x = wl[4]; u1.y = wl[5]; u1.z = wl[6]; u1.w = wl[7];
        *(uint4*)((unsigned*)ylo + ubase) = u0;
        *(uint4*)((unsigned*)ylo + ubase + 4) = u1;
    }
}

// ---------------------------------------------------------------------------
// twB: stageB twiddle A-operand, [k1][m=2t+r][q], bf16 hi/lo.
// ---------------------------------------------------------------------------
__global__ __launch_bounds__(256) void k_twfillB(unsigned short* __restrict__ hi,
                                                 unsigned short* __restrict__ lo) {
    int m = blockIdx.x & 255; int k1 = blockIdx.x >> 8;   // grid 17*256
    int n2 = threadIdx.x;
    int t = m >> 1, r = m & 1;
    int f = k1 + 17 * t;
    unsigned ph = 0u, pl = 0u;
    if (t <= 120 && f < F_ && n2 <= 240) {
        float s_ = (k1 <= 8) ? 1.f : -1.f;
        int rr = (f * n2) % N_;
        float sn, cs; sincosf(W_N * (float)rr, &sn, &cs);
        float a0 = (r == 0) ? cs : -sn;
        float a1 = (r == 0) ? s_ * sn : s_ * cs;
        unsigned short h0 = f2bf(a0); float l0 = a0 - bf2f(h0);
        unsigned short h1 = f2bf(a1); float l1 = a1 - bf2f(h1);
        ph = (unsigned)h0 | ((unsigned)h1 << 16);
        pl = (unsigned)f2bf(l0) | ((unsigned)f2bf(l1) << 16);
    }
    size_t ub = ((size_t)(k1 * 256 + m)) * 256 + n2;
    *((unsigned*)hi + ub) = ph;
    *((unsigned*)lo + ub) = pl;
}

// ---------------------------------------------------------------------------
// Stage B v3: LDS-staged split-bf16 MFMA GEMM, BN=256 (8 waves 2Mx4N).
// Per (b,j,k1,mh): OUT[m][c] = sum_q twB[k1][mh*128+m][q] * y_t[b][j][c][q],
// acc += Ah*Bh + Al*Bh + Ah*Bl.  Tile 128(m) x 256(c), BK=32.
// A staged once per block (vs twice in v2); energy block-local -> direct store.
// grid 1088 = B*34, chunk-swizzled; 512 threads.
// ---------------------------------------------------------------------------
__global__ __launch_bounds__(512) void k_stageB_v3(
        const short* __restrict__ yt_hi, const short* __restrict__ yt_lo,
        const short* __restrict__ twb_hi, const short* __restrict__ twb_lo,
        unsigned short* __restrict__ X, float* __restrict__ energy) {
    int bid = (blockIdx.x & 7) * 136 + (blockIdx.x >> 3);   // 1088 = 8*136
    int b = bid / 34, rem = bid % 34;
    int j, k1, mh;
    if (rem < 2) { j = 0; k1 = 0; mh = rem; }
    else { int r2 = rem - 2; j = 1 + (r2 >> 2); int sub = r2 & 3;
           k1 = (sub < 2) ? j : 17 - j; mh = sub & 1; }
    const short* pAh = twb_hi + (size_t)(k1 * 256 + mh * 128) * Q_;
    const short* pAl = twb_lo + (size_t)(k1 * 256 + mh * 128) * Q_;
    const short* pBh = yt_hi + (size_t)((b * 9 + j) * 256) * Q_;
    const short* pBl = yt_lo + (size_t)((b * 9 + j) * 256) * Q_;

    int tid = threadIdx.x, lane = tid & 63, wid = tid >> 6;   // 8 waves
    int wr = wid >> 2, wc = wid & 3;
    int l15 = lane & 15, lg = lane >> 4;
    int srow = lane >> 2, sch = lane & 3;

    __shared__ __align__(16) short lds[24576];   // Ah(4K) Al(4K) Bh(8K) Bl(8K) shorts
    __shared__ float eL[2][4][4][4][2];

    f32x4 acc[4][4];
#pragma unroll
    for (int rt = 0; rt < 4; ++rt)
#pragma unroll
        for (int nt = 0; nt < 4; ++nt) acc[rt][nt] = (f32x4){0.f, 0.f, 0.f, 0.f};

    for (int ks = 0; ks < 16; ++ks) {
        int q0 = ks * 32;
        // 6 staging rounds: r0 Ah, r1 Al, r2-3 Bh, r4-5 Bl; wave stages 16 rows.
#pragma unroll
        for (int r = 0; r < 6; ++r) {
            const short* gp; int row; int ldsbase;
            if (r == 0)      { gp = pAh; row = wid * 16 + srow; ldsbase = 0; }
            else if (r == 1) { gp = pAl; row = wid * 16 + srow; ldsbase = 4096; }
            else if (r < 4)  { gp = pBh; row = (r - 2) * 128 + wid * 16 + srow;
                               ldsbase = 8192 + (r - 2) * 4096; }
            else             { gp = pBl; row = (r - 4) * 128 + wid * 16 + srow;
                               ldsbase = 16384 + (r - 4) * 4096; }
            int ch = sch ^ ((row >> 1) & 3);
            gload16(gp + (size_t)row * Q_ + q0 + ch * 8, &lds[ldsbase + wid * 512]);
        }
        __syncthreads();
        short8v Ah[4], Al[4], Bh[4], Bl[4];
#pragma unroll
        for (int rt = 0; rt < 4; ++rt) {
            int row = wr * 64 + rt * 16 + l15;
            int u = row * 4 + (lg ^ ((row >> 1) & 3));
            Ah[rt] = *(const short8v*)&lds[u * 8];
            Al[rt] = *(const short8v*)&lds[4096 + u * 8];
        }
#pragma unroll
        for (int nt = 0; nt < 4; ++nt) {
            int row = wc * 64 + nt * 16 + l15;
            int u = row * 4 + (lg ^ ((row >> 1) & 3));
            Bh[nt] = *(const short8v*)&lds[8192 + u * 8];
            Bl[nt] = *(const short8v*)&lds[16384 + u * 8];
        }
#pragma unroll
        for (int rt = 0; rt < 4; ++rt)
#pragma unroll
            for (int nt = 0; nt < 4; ++nt) {
                acc[rt][nt] = __builtin_amdgcn_mfma_f32_16x16x32_bf16(
                    Ah[rt], Bh[nt], acc[rt][nt], 0, 0, 0);
                acc[rt][nt] = __builtin_amdgcn_mfma_f32_16x16x32_bf16(
                    Al[rt], Bh[nt], acc[rt][nt], 0, 0, 0);
                acc[rt][nt] = __builtin_amdgcn_mfma_f32_16x16x32_bf16(
                    Ah[rt], Bl[nt], acc[rt][nt], 0, 0, 0);
            }
        __syncthreads();
    }

    // ---- energy: full-c reduction in-block, direct store ----
#pragma unroll
    for (int rt = 0; rt < 4; ++rt) {
        float e0 = 0.f, e1 = 0.f;
#pragma unroll
        for (int nt = 0; nt < 4; ++nt) {
            e0 += acc[rt][nt][0] * acc[rt][nt][0] + acc[rt][nt][1] * acc[rt][nt][1];
            e1 += acc[rt][nt][2] * acc[rt][nt][2] + acc[rt][nt][3] * acc[rt][nt][3];
        }
#pragma unroll
        for (int off = 1; off < 16; off <<= 1) {
            e0 += __shfl_xor(e0, off, 64);
            e1 += __shfl_xor(e1, off, 64);
        }
        if (l15 == 0) { eL[wr][wc][rt][lg][0] = e0; eL[wr][wc][rt][lg][1] = e1; }
    }
    __syncthreads();
    if (tid < 64) {
        int wr2 = tid >> 5, rt2 = (tid >> 3) & 3, lg2 = (tid >> 1) & 3, pr = tid & 1;
        int mrow = mh * 128 + wr2 * 64 + rt2 * 16 + lg2 * 4 + pr * 2;
        int f = k1 + 17 * (mrow >> 1);
        if (f < F_) {
            float e = eL[wr2][0][rt2][lg2][pr] + eL[wr2][1][rt2][lg2][pr] +
                      eL[wr2][2][rt2][lg2][pr] + eL[wr2][3][rt2][lg2][pr];
            energy[b * F_ + f] = e;
        }
    }

    // ---- X store (bf16) ----
#pragma unroll
    for (int rt = 0; rt < 4; ++rt) {
#pragma unroll
        for (int jj = 0; jj < 4; ++jj) {
            int mrow = mh * 128 + wr * 64 + rt * 16 + lg * 4 + jj;
            int t = mrow >> 1, p = mrow & 1;
            int f = k1 + 17 * t;
            if (f < F_) {
                size_t base = ((size_t)((b * F_ + f) * 2 + p)) * C_ + wc * 64 + l15;
#pragma unroll
                for (int nt = 0; nt < 4; ++nt)
                    X[base + nt * 16] = f2bf(acc[rt][nt][jj]);
            }
        }
    }
}

// ---------------------------------------------------------------------------
// Median per batch via exact 4-pass radix select (energies >= 0 so uint order
// == float order).  rank 1024 of 2049 == np.sort(...)[1024], bit-exact.
// ---------------------------------------------------------------------------
__global__ __launch_bounds__(256) void k_median(const float* __restrict__ energy,
                                                float* __restrict__ med) {
    int b = blockIdx.x, tid = threadIdx.x;
    __shared__ unsigned vals[F_];
    __shared__ unsigned hist[256];
    __shared__ unsigned scanbuf[256];
    __shared__ unsigned sh_prefix;
    __shared__ int sh_rank;
    for (int i = tid; i < F_; i += 256)
        vals[i] = __float_as_uint(energy[b * F_ + i]);
    if (tid == 0) { sh_prefix = 0u; sh_rank = 1024; }
    __syncthreads();
#pragma unroll
    for (int shift = 24; shift >= 0; shift -= 8) {
        hist[tid] = 0u;
        __syncthreads();
        unsigned prefix = sh_prefix;
        unsigned hmask = (shift == 24) ? 0u : (0xFFFFFFFFu << (shift + 8));
        for (int i = tid; i < F_; i += 256) {
            unsigned v = vals[i];
            if (((v ^ prefix) & hmask) == 0u)
                atomicAdd(&hist[(v >> shift) & 255], 1u);
        }
        __syncthreads();
        scanbuf[tid] = hist[tid];
        __syncthreads();
#pragma unroll
        for (int off = 1; off < 256; off <<= 1) {
            unsigned y = (tid >= off) ? scanbuf[tid - off] : 0u;
            __syncthreads();
            scanbuf[tid] += y;
            __syncthreads();
        }
        int rank = sh_rank;
        unsigned cumP = (tid == 0) ? 0u : scanbuf[tid - 1];
        unsigned cumI = scanbuf[tid];
        __syncthreads();
        if ((unsigned)rank >= cumP && (unsigned)rank < cumI) {
            sh_prefix = prefix | ((unsigned)tid << shift);
            sh_rank = rank - (int)cumP;
        }
        __syncthreads();
    }
    if (tid == 0) med[b] = __uint_as_float(sh_prefix);
}

// ---------------------------------------------------------------------------
// Twiddle table for stage C MFMA:  twA[n][q], n=0..4351, q=0..511, bf16.
// ---------------------------------------------------------------------------
__global__ __launch_bounds__(256) void k_twfill(unsigned short* __restrict__ twA) {
    int n = blockIdx.x;          // 0..4351
    int k2 = threadIdx.x;        // 0..255
    unsigned pack = 0u;
    if (n <= 4096 && k2 <= 240) {
        int rr = (n * k2) % N_;
        float s, cth; sincosf(W_N * (float)rr, &s, &cth);
        pack = (unsigned)f2bf(cth) | ((unsigned)f2bf(-s) << 16);
    }
    *(unsigned*)(twA + (size_t)n * Q_ + 2 * k2) = pack;
}

// ---------------------------------------------------------------------------
// vbuild (tiled): mask + weights + inverse inner 17-point stage.
// Output v_t[b][m2][c][q=2k2+p] bf16 (stride Q_), coalesced via LDS staging.
// ---------------------------------------------------------------------------
__global__ __launch_bounds__(256) void k_vbuild_t(
        const unsigned short* __restrict__ X, const float* __restrict__ energy,
        const float* __restrict__ med, const float* __restrict__ thr,
        const float* __restrict__ cw, const float* __restrict__ cwh,
        unsigned short* __restrict__ vt) {
    int bid = blockIdx.x;            // 32*8*8 = 2048
    int b = bid / 64; int rem = bid % 64;
    int kt = rem >> 3, ct = rem & 7;
    int tid = threadIdx.x;
    int cl = tid & 31, ks = tid >> 5;
    int c = ct * 32 + cl;

    __shared__ unsigned stage[17 * 32 * 33];   // [m2][cl][klocal pad 33]

    float wr = cw[2 * c], wi = cw[2 * c + 1];
    float whr = cwh[2 * c], whi = cwh[2 * c + 1];
    float denom = med[b] + 1e-6f;

    float C17[17], S17[17];
#pragma unroll
    for (int r = 0; r < 17; ++r) {
        float s, cth; sincosf(W_17 * (float)r, &s, &cth);
        C17[r] = cth; S17[r] = s;
    }

    for (int kk = 0; kk < 4; ++kk) {
        int klocal = kk * 8 + ks;
        int k2 = kt * 32 + klocal;
        float vr[17], vi[17];
#pragma unroll
        for (int m = 0; m < 17; ++m) { vr[m] = 0.f; vi[m] = 0.f; }
        if (k2 <= 240) {
#pragma unroll
            for (int s = 0; s < 9; ++s) {
                int f = k2 + 241 * s;
                if (f < F_) {
                    float e = energy[b * F_ + f];
                    float m = (e / denom > thr[f]) ? 1.0f : 0.0f;
                    float wer = wr + m * whr, wei = wi + m * whi;
                    float cf = ((f == 0) ? 1.0f : 2.0f) * INV_SQRT_N;
                    const unsigned short* Xrow = X + ((size_t)(b * F_ + f) * 2) * C_;
                    float Xr = bf2f(Xrow[c]), Xi = bf2f(Xrow[C_ + c]);
                    float Zr = (Xr * wer - Xi * wei) * cf;
                    float Zi = (Xr * wei + Xi * wer) * cf;
#pragma unroll
                    for (int m2 = 0; m2 < 17; ++m2) {
                        int r = (s * m2) % 17;
                        vr[m2] += Zr * C17[r] - Zi * S17[r];
                        vi[m2] += Zr * S17[r] + Zi * C17[r];
                    }
                }
            }
        }
#pragma unroll
        for (int m2 = 0; m2 < 17; ++m2)
            stage[(m2 * 32 + cl) * 33 + klocal] =
                (unsigned)f2bf(vr[m2]) | ((unsigned)f2bf(vi[m2]) << 16);
    }
    __syncthreads();
    unsigned* vt32 = (unsigned*)vt;
    for (int r = tid; r < 544; r += 256) {
        int m2 = r >> 5, c2 = r & 31;
        size_t ubase = ((size_t)((b * 17 + m2) * 256 + ct * 32 + c2)) * 256 + kt * 32;
        const unsigned* srow = &stage[(m2 * 32 + c2) * 33];
#pragma unroll
        for (int g = 0; g < 8; ++g) {
            uint4 w;
            w.x = srow[g * 4]; w.y = srow[g * 4 + 1];
            w.z = srow[g * 4 + 2]; w.w = srow[g * 4 + 3];
            *(uint4*)(vt32 + ubase + g * 4) = w;
        }
    }
}

// ---------------------------------------------------------------------------
// Stage C v2: LDS-staged MFMA GEMM (m97 structure, BK=64).
// ---------------------------------------------------------------------------
__global__ __launch_bounds__(256) void k_stageC_v2(const short* __restrict__ vt,
                                                   const short* __restrict__ twA,
                                                   float* __restrict__ out) {
    int bid = (blockIdx.x & 7) * 272 + (blockIdx.x >> 3);
    int b = bid / 68, rem = bid % 68;
    int m2 = rem >> 2, mt = (rem >> 1) & 1, ct = rem & 1;

    int tid = threadIdx.x, lane = tid & 63, wid = tid >> 6;
    int wr = wid >> 1, wc = wid & 1;
    int l15 = lane & 15, lg = lane >> 4;
    int srow = lane >> 3, sch = lane & 7;      // staging: 8 rows x 8 chunks

    const short* vtb = vt + (size_t)((b * 17 + m2) * 256 + ct * 128) * Q_;

    __shared__ __align__(16) short lds[16384];   // A [128][64] | B [128][64]

    f32x4 acc[4][4];
#pragma unroll
    for (int rt = 0; rt < 4; ++rt)
#pragma unroll
        for (int nt = 0; nt < 4; ++nt) acc[rt][nt] = (f32x4){0.f, 0.f, 0.f, 0.f};

    for (int ks = 0; ks < 8; ++ks) {
        int q0 = ks * 64;
#pragma unroll
        for (int r = 0; r < 8; ++r) {
            int row = (r & 3) * 32 + wid * 8 + srow;           // 0..127
            int ch = sch ^ ((row >> 1) & 7);
            const short* g;
            if (r < 4) {
                int n = 17 * (mt * 128 + row) + m2;
                g = twA + (size_t)n * Q_ + q0 + ch * 8;
            } else {
                g = vtb + (size_t)row * Q_ + q0 + ch * 8;
            }
            gload16(g, &lds[(r * 4 + wid) * 512]);
        }
        __syncthreads();
        short8v a[2][4], bb[2][4];
#pragma unroll
        for (int rt = 0; rt < 4; ++rt) {
            int row = wr * 64 + rt * 16 + l15;
            int s = (row >> 1) & 7;
            a[0][rt] = *(const short8v*)&lds[(row * 8 + (lg ^ s)) * 8];
            a[1][rt] = *(const short8v*)&lds[(row * 8 + ((4 + lg) ^ s)) * 8];
        }
#pragma unroll
        for (int nt = 0; nt < 4; ++nt) {
            int row = wc * 64 + nt * 16 + l15;
            int s = (row >> 1) & 7;
            bb[0][nt] = *(const short8v*)&lds[8192 + (row * 8 + (lg ^ s)) * 8];
            bb[1][nt] = *(const short8v*)&lds[8192 + (row * 8 + ((4 + lg) ^ s)) * 8];
        }
#pragma unroll
        for (int kh = 0; kh < 2; ++kh)
#pragma unroll
            for (int rt = 0; rt < 4; ++rt)
#pragma unroll
                for (int nt = 0; nt < 4; ++nt)
                    acc[rt][nt] = __builtin_amdgcn_mfma_f32_16x16x32_bf16(
                        a[kh][rt], bb[kh][nt], acc[rt][nt], 0, 0, 0);
        __syncthreads();
    }

#pragma unroll
    for (int rt = 0; rt < 4; ++rt) {
#pragma unroll
        for (int jj = 0; jj < 4; ++jj) {
            int m1 = mt * 128 + wr * 64 + rt * 16 + lg * 4 + jj;
            if (m1 < N2_) {
                int n = 17 * m1 + m2;
                float* orow = out + ((size_t)b * N_ + n) * C_ + ct * 128 + wc * 64;
#pragma unroll
                for (int nt = 0; nt < 4; ++nt)
                    orow[nt * 16 + l15] = acc[rt][nt][jj];
            }
        }
    }
}

// ---------------------------------------------------------------------------
extern "C" void kernel_launch(void* const* d_in, const int* in_sizes, int n_in,
                              void* d_out, int out_size, void* d_ws, size_t ws_size,
                              hipStream_t stream) {
    const float* x   = (const float*)d_in[0];
    const float* cw  = (const float*)d_in[1];
    const float* cwh = (const float*)d_in[2];
    const float* thr = (const float*)d_in[3];
    float* out = (float*)d_out;

    // workspace (~231.8 MB), v_t aliases the dead y_t region:
    //   X     bf16 [B][F][2][C]          :  67,141,632
    //   SH    region (y_t_hi + y_t_lo | v_t):
    //     y_t_hi bf16 [B][9][256][512]   :  75,497,472
    //     y_t_lo bf16                    :  75,497,472
    //     v_t    bf16 [B][17][256][512]  : 142,606,336 (aliased at SH base)
    //   twA   bf16 [4352][512]           :   4,456,448
    //   twB_hi/lo bf16 [17][256][512]    :   4,456,448 each
    //   energy f32 [B][F]                :     262,272
    //   med    f32 [B]                   :         128
    char* ws = (char*)d_ws;
    unsigned short* Xb    = (unsigned short*)ws;
    char* sh = ws + 67141632ull;
    unsigned short* ythi  = (unsigned short*)sh;
    unsigned short* ytlo  = (unsigned short*)(sh + 75497472ull);
    unsigned short* vtb   = (unsigned short*)sh;                 // alias
    char* tail = sh + 150994944ull;
    unsigned short* twA   = (unsigned short*)tail;
    unsigned short* twBh  = (unsigned short*)(tail + 4456448ull);
    unsigned short* twBl  = (unsigned short*)(tail + 8912896ull);
    float* energy = (float*)(tail + 13369344ull);
    float* med    = (float*)(tail + 13369344ull + 262272ull);

    k_twfill<<<TWROWS, 256, 0, stream>>>(twA);
    k_twfillB<<<17 * 256, 256, 0, stream>>>(twBh, twBl);
    k_stageA_t<<<B_ * 32, 256, 0, stream>>>(x, ythi, ytlo);
    k_stageB_v3<<<B_ * 34, 512, 0, stream>>>((const short*)ythi, (const short*)ytlo,
                                             (const short*)twBh, (const short*)twBl,
                                             Xb, energy);
    k_median<<<B_, 256, 0, stream>>>(energy, med);
    k_vbuild_t<<<B_ * 64, 256, 0, stream>>>(Xb, energy, med, thr, cw, cwh, vtb);
    k_stageC_v2<<<B_ * 68, 256, 0, stream>>>((const short*)vtb, (const short*)twA, out);
}

// Round 7
// 326.511 us; speedup vs baseline: 4.4108x; 1.2294x over previous
//
#include <hip/hip_runtime.h>
#include <math.h>
#include <float.h>

#define B_ 32
#define N_ 4097
#define C_ 256
#define F_ 2049
#define N2_ 241
#define Q_ 512                        // padded K (q = 2*n2 + p, zeros q>=482)
#define TWROWS 4352                   // stageC twiddle rows (m1-tail padded)
#define INV_SQRT_N 0.0156230927f      // 1/sqrt(4097)
#define W_N 0.0015336063f             // 2*pi/4097
#define W_17 0.36959913571644626f     // 2*pi/17

typedef __attribute__((ext_vector_type(8))) short short8v;
typedef _Float16 f16x8 __attribute__((ext_vector_type(8)));
typedef __attribute__((ext_vector_type(4))) float f32x4;

__device__ __forceinline__ float bf2f(unsigned short u) {
    return __uint_as_float(((unsigned)u) << 16);
}
__device__ __forceinline__ unsigned short f2bf(float v) {
    unsigned u = __float_as_uint(v);
    u += 0x7FFFu + ((u >> 16) & 1u);
    return (unsigned short)(u >> 16);
}
__device__ __forceinline__ unsigned short f2h(float v) {
    union { _Float16 h; unsigned short u; } cv;
    cv.h = (_Float16)v;               // v_cvt_f16_f32, RTN
    return cv.u;
}
__device__ __forceinline__ void gload16(const void* gptr, void* ldsptr) {
    __builtin_amdgcn_global_load_lds(
        (const __attribute__((address_space(1))) void*)gptr,
        (__attribute__((address_space(3))) void*)ldsptr,
        16, 0, 0);
}

// ---------------------------------------------------------------------------
// Fused Stage A + transpose: x[B][N][C] f32 -> y_t fp16 [b][j][c][q].
// 17-point real DFT accumulated in registers; per-j LDS transpose,
// packed (re,im) u32 writes, zero pad rows n2>240.
// grid 1024 = B*8(n2t)*4(ct); block 256 = 64 c x 4 row-groups of 8.
// ---------------------------------------------------------------------------
__global__ __launch_bounds__(256) void k_stageA_t(const float* __restrict__ x,
                                                  unsigned short* __restrict__ yt) {
    int bid = blockIdx.x;
    int b = bid >> 5; int rem = bid & 31;
    int n2t = rem >> 2, ct = rem & 3;
    int tid = threadIdx.x;
    int cl = tid & 63, sub = tid >> 6;
    int c = ct * 64 + cl;

    float C17[17], S17[17];
#pragma unroll
    for (int r = 0; r < 17; ++r) {
        float s, cth; sincosf(W_17 * (float)r, &s, &cth);
        C17[r] = cth; S17[r] = s;
    }

    float ar[9][8], ai[8][8];
#pragma unroll
    for (int k = 0; k < 9; ++k)
#pragma unroll
        for (int i = 0; i < 8; ++i) ar[k][i] = 0.f;
#pragma unroll
    for (int k = 0; k < 8; ++k)
#pragma unroll
        for (int i = 0; i < 8; ++i) ai[k][i] = 0.f;

    const float* xb = x + (size_t)b * N_ * C_ + c;
#pragma unroll
    for (int n1 = 0; n1 < 17; ++n1) {
        float xv[8];
#pragma unroll
        for (int i = 0; i < 8; ++i) {
            int n2 = n2t * 32 + sub * 8 + i;
            xv[i] = (n2 <= 240) ? xb[(size_t)(n1 * N2_ + n2) * C_] : 0.f;
        }
#pragma unroll
        for (int k1 = 0; k1 < 9; ++k1) {
            int r = (k1 * n1) % 17;       // compile-time after unroll
            float cc = C17[r], ss = S17[r];
#pragma unroll
            for (int i = 0; i < 8; ++i) {
                ar[k1][i] += xv[i] * cc;
                if (k1 > 0) ai[k1 - 1][i] += xv[i] * ss;
            }
        }
    }

    __shared__ float lre[32 * 65], lim[32 * 65];
    int c2 = tid >> 2, qg = tid & 3;
#pragma unroll
    for (int j = 0; j < 9; ++j) {
        __syncthreads();                  // protect previous j's reads
#pragma unroll
        for (int i = 0; i < 8; ++i) {
            int row = sub * 8 + i;
            lre[row * 65 + cl] = ar[j][i] * INV_SQRT_N;
            lim[row * 65 + cl] = (j > 0) ? (-ai[j - 1][i] * INV_SQRT_N) : 0.f;
        }
        __syncthreads();
        unsigned wh[8];
#pragma unroll
        for (int i = 0; i < 8; ++i) {
            int row = qg * 8 + i;
            float re = lre[row * 65 + c2], im = lim[row * 65 + c2];
            wh[i] = (unsigned)f2h(re) | ((unsigned)f2h(im) << 16);
        }
        size_t ubase = ((size_t)((b * 9 + j) * 256 + ct * 64 + c2)) * 256 + n2t * 32 + qg * 8;
        uint4 v0; v0.x = wh[0]; v0.y = wh[1]; v0.z = wh[2]; v0.w = wh[3];
        uint4 v1; v1.x = wh[4]; v1.y = wh[5]; v1.z = wh[6]; v1.w = wh[7];
        *(uint4*)((unsigned*)yt + ubase) = v0;
        *(uint4*)((unsigned*)yt + ubase + 4) = v1;
    }
}

// ---------------------------------------------------------------------------
// twB: stageB twiddle A-operand, [k1][m=2t+r][q], fp16.
//   r=0 (Xr): q=2n2 -> cos, q=2n2+1 -> s*sin
//   r=1 (Xi): q=2n2 -> -sin, q=2n2+1 -> s*cos   (s = +1 k1<=8, -1 else)
// ---------------------------------------------------------------------------
__global__ __launch_bounds__(256) void k_twfillB(unsigned short* __restrict__ tw) {
    int m = blockIdx.x & 255; int k1 = blockIdx.x >> 8;   // grid 17*256
    int n2 = threadIdx.x;
    int t = m >> 1, r = m & 1;
    int f = k1 + 17 * t;
    unsigned ph = 0u;
    if (t <= 120 && f < F_ && n2 <= 240) {
        float s_ = (k1 <= 8) ? 1.f : -1.f;
        int rr = (f * n2) % N_;
        float sn, cs; sincosf(W_N * (float)rr, &sn, &cs);
        float a0 = (r == 0) ? cs : -sn;
        float a1 = (r == 0) ? s_ * sn : s_ * cs;
        ph = (unsigned)f2h(a0) | ((unsigned)f2h(a1) << 16);
    }
    size_t ub = ((size_t)(k1 * 256 + m)) * 256 + n2;
    *((unsigned*)tw + ub) = ph;
}

// ---------------------------------------------------------------------------
// Stage B v4: LDS-staged single-pass fp16 MFMA GEMM.
// Per (b,j,k1,mh,ct): OUT[m][c] = sum_q twB[k1][mh*128+m][q] * y_t[b][j][c][q].
// Tile 128(m) x 128(c), BK=64, 4 waves 2x2.  Staging via global_load_lds w16,
// source-side XOR swizzle chunk ^= (row>>1)&7 (pattern validated in stageC_v2).
// Energy: block-partial (128 c) reduce + atomicAdd (2 deterministic terms).
// grid 2176 = B*68, chunk-swizzled.
// ---------------------------------------------------------------------------
__global__ __launch_bounds__(256) void k_stageB_v4(
        const unsigned short* __restrict__ yt, const unsigned short* __restrict__ twb,
        unsigned short* __restrict__ X, float* __restrict__ energy) {
    int bid = (blockIdx.x & 7) * 272 + (blockIdx.x >> 3);   // 2176 = 8*272
    int b = bid / 68, rem = bid % 68;
    int j, mt, ct;
    if (rem < 4) { j = 0; mt = rem >> 1; ct = rem & 1; }
    else { int r2 = rem - 4; j = 1 + (r2 >> 3); int sub = r2 & 7; mt = sub >> 1; ct = sub & 1; }
    int k1 = (mt < 2) ? j : 17 - j;
    int mh = mt & 1;
    const unsigned short* pA = twb + (size_t)(k1 * 256 + mh * 128) * Q_;
    const unsigned short* pB = yt + (size_t)((b * 9 + j) * 256 + ct * 128) * Q_;

    int tid = threadIdx.x, lane = tid & 63, wid = tid >> 6;
    int wr = wid >> 1, wc = wid & 1;
    int l15 = lane & 15, lg = lane >> 4;
    int srow = lane >> 3, sch = lane & 7;      // staging: 8 rows x 8 chunks of 16B

    __shared__ __align__(16) unsigned short lds[16384];  // A [128][64] | B [128][64]
    __shared__ float eL[2][2][4][4][2];

    f32x4 acc[4][4];
#pragma unroll
    for (int rt = 0; rt < 4; ++rt)
#pragma unroll
        for (int nt = 0; nt < 4; ++nt) acc[rt][nt] = (f32x4){0.f, 0.f, 0.f, 0.f};

    for (int ks = 0; ks < 8; ++ks) {
        int q0 = ks * 64;
        // ---- stage 32 KB: 8 wave-rounds (r<4 -> A, else B) ----
#pragma unroll
        for (int r = 0; r < 8; ++r) {
            int row = (r & 3) * 32 + wid * 8 + srow;           // 0..127
            int ch = sch ^ ((row >> 1) & 7);
            const unsigned short* g = (r < 4) ? (pA + (size_t)row * Q_ + q0 + ch * 8)
                                              : (pB + (size_t)row * Q_ + q0 + ch * 8);
            gload16(g, &lds[(r * 4 + wid) * 512]);
        }
        __syncthreads();
        // ---- fragments + MFMA (2 k-slices) ----
        f16x8 a[2][4], bb[2][4];
#pragma unroll
        for (int rt = 0; rt < 4; ++rt) {
            int row = wr * 64 + rt * 16 + l15;
            int s = (row >> 1) & 7;
            a[0][rt] = *(const f16x8*)&lds[(row * 8 + (lg ^ s)) * 8];
            a[1][rt] = *(const f16x8*)&lds[(row * 8 + ((4 + lg) ^ s)) * 8];
        }
#pragma unroll
        for (int nt = 0; nt < 4; ++nt) {
            int row = wc * 64 + nt * 16 + l15;
            int s = (row >> 1) & 7;
            bb[0][nt] = *(const f16x8*)&lds[8192 + (row * 8 + (lg ^ s)) * 8];
            bb[1][nt] = *(const f16x8*)&lds[8192 + (row * 8 + ((4 + lg) ^ s)) * 8];
        }
#pragma unroll
        for (int kh = 0; kh < 2; ++kh)
#pragma unroll
            for (int rt = 0; rt < 4; ++rt)
#pragma unroll
                for (int nt = 0; nt < 4; ++nt)
                    acc[rt][nt] = __builtin_amdgcn_mfma_f32_16x16x32_f16(
                        a[kh][rt], bb[kh][nt], acc[rt][nt], 0, 0, 0);
        __syncthreads();
    }

    // ---- energy: partial sum over this block's 128 c, atomicAdd ----
#pragma unroll
    for (int rt = 0; rt < 4; ++rt) {
        float e0 = 0.f, e1 = 0.f;
#pragma unroll
        for (int nt = 0; nt < 4; ++nt) {
            e0 += acc[rt][nt][0] * acc[rt][nt][0] + acc[rt][nt][1] * acc[rt][nt][1];
            e1 += acc[rt][nt][2] * acc[rt][nt][2] + acc[rt][nt][3] * acc[rt][nt][3];
        }
#pragma unroll
        for (int off = 1; off < 16; off <<= 1) {
            e0 += __shfl_xor(e0, off, 64);
            e1 += __shfl_xor(e1, off, 64);
        }
        if (l15 == 0) { eL[wr][wc][rt][lg][0] = e0; eL[wr][wc][rt][lg][1] = e1; }
    }
    __syncthreads();
    if (tid < 64) {
        int wr2 = tid >> 5, rt2 = (tid >> 3) & 3, lg2 = (tid >> 1) & 3, pr = tid & 1;
        int mrow = mh * 128 + wr2 * 64 + rt2 * 16 + lg2 * 4 + pr * 2;
        int f = k1 + 17 * (mrow >> 1);
        if (f < F_) {
            float e = eL[wr2][0][rt2][lg2][pr] + eL[wr2][1][rt2][lg2][pr];
            atomicAdd(&energy[b * F_ + f], e);
        }
    }

    // ---- X store (bf16) ----
#pragma unroll
    for (int rt = 0; rt < 4; ++rt) {
#pragma unroll
        for (int jj = 0; jj < 4; ++jj) {
            int mrow = mh * 128 + wr * 64 + rt * 16 + lg * 4 + jj;
            int t = mrow >> 1, p = mrow & 1;
            int f = k1 + 17 * t;
            if (f < F_) {
                size_t base = ((size_t)((b * F_ + f) * 2 + p)) * C_ + ct * 128 + wc * 64 + l15;
#pragma unroll
                for (int nt = 0; nt < 4; ++nt)
                    X[base + nt * 16] = f2bf(acc[rt][nt][jj]);
            }
        }
    }
}

// ---------------------------------------------------------------------------
// Median per batch via exact 4-pass radix select (energies >= 0 so uint order
// == float order).  rank 1024 of 2049 == np.sort(...)[1024], bit-exact.
// ---------------------------------------------------------------------------
__global__ __launch_bounds__(256) void k_median(const float* __restrict__ energy,
                                                float* __restrict__ med) {
    int b = blockIdx.x, tid = threadIdx.x;
    __shared__ unsigned vals[F_];
    __shared__ unsigned hist[256];
    __shared__ unsigned scanbuf[256];
    __shared__ unsigned sh_prefix;
    __shared__ int sh_rank;
    for (int i = tid; i < F_; i += 256)
        vals[i] = __float_as_uint(energy[b * F_ + i]);
    if (tid == 0) { sh_prefix = 0u; sh_rank = 1024; }
    __syncthreads();
#pragma unroll
    for (int shift = 24; shift >= 0; shift -= 8) {
        hist[tid] = 0u;
        __syncthreads();
        unsigned prefix = sh_prefix;
        unsigned hmask = (shift == 24) ? 0u : (0xFFFFFFFFu << (shift + 8));
        for (int i = tid; i < F_; i += 256) {
            unsigned v = vals[i];
            if (((v ^ prefix) & hmask) == 0u)
                atomicAdd(&hist[(v >> shift) & 255], 1u);
        }
        __syncthreads();
        scanbuf[tid] = hist[tid];
        __syncthreads();
#pragma unroll
        for (int off = 1; off < 256; off <<= 1) {
            unsigned y = (tid >= off) ? scanbuf[tid - off] : 0u;
            __syncthreads();
            scanbuf[tid] += y;
            __syncthreads();
        }
        int rank = sh_rank;
        unsigned cumP = (tid == 0) ? 0u : scanbuf[tid - 1];
        unsigned cumI = scanbuf[tid];
        __syncthreads();
        if ((unsigned)rank >= cumP && (unsigned)rank < cumI) {
            sh_prefix = prefix | ((unsigned)tid << shift);
            sh_rank = rank - (int)cumP;
        }
        __syncthreads();
    }
    if (tid == 0) med[b] = __uint_as_float(sh_prefix);
}

// ---------------------------------------------------------------------------
// Twiddle table for stage C MFMA:  twA[n][q], n=0..4351, q=0..511, bf16.
// ---------------------------------------------------------------------------
__global__ __launch_bounds__(256) void k_twfill(unsigned short* __restrict__ twA) {
    int n = blockIdx.x;          // 0..4351
    int k2 = threadIdx.x;        // 0..255
    unsigned pack = 0u;
    if (n <= 4096 && k2 <= 240) {
        int rr = (n * k2) % N_;
        float s, cth; sincosf(W_N * (float)rr, &s, &cth);
        pack = (unsigned)f2bf(cth) | ((unsigned)f2bf(-s) << 16);
    }
    *(unsigned*)(twA + (size_t)n * Q_ + 2 * k2) = pack;
}

// ---------------------------------------------------------------------------
// vbuild (tiled): mask + weights + inverse inner 17-point stage.
// Output v_t[b][m2][c][q=2k2+p] bf16 (stride Q_), coalesced via LDS staging.
// ---------------------------------------------------------------------------
__global__ __launch_bounds__(256) void k_vbuild_t(
        const unsigned short* __restrict__ X, const float* __restrict__ energy,
        const float* __restrict__ med, const float* __restrict__ thr,
        const float* __restrict__ cw, const float* __restrict__ cwh,
        unsigned short* __restrict__ vt) {
    int bid = blockIdx.x;            // 32*8*8 = 2048
    int b = bid / 64; int rem = bid % 64;
    int kt = rem >> 3, ct = rem & 7;
    int tid = threadIdx.x;
    int cl = tid & 31, ks = tid >> 5;
    int c = ct * 32 + cl;

    __shared__ unsigned stage[17 * 32 * 33];   // [m2][cl][klocal pad 33]

    float wr = cw[2 * c], wi = cw[2 * c + 1];
    float whr = cwh[2 * c], whi = cwh[2 * c + 1];
    float denom = med[b] + 1e-6f;

    float C17[17], S17[17];
#pragma unroll
    for (int r = 0; r < 17; ++r) {
        float s, cth; sincosf(W_17 * (float)r, &s, &cth);
        C17[r] = cth; S17[r] = s;
    }

    for (int kk = 0; kk < 4; ++kk) {
        int klocal = kk * 8 + ks;
        int k2 = kt * 32 + klocal;
        float vr[17], vi[17];
#pragma unroll
        for (int m = 0; m < 17; ++m) { vr[m] = 0.f; vi[m] = 0.f; }
        if (k2 <= 240) {
#pragma unroll
            for (int s = 0; s < 9; ++s) {
                int f = k2 + 241 * s;
                if (f < F_) {
                    float e = energy[b * F_ + f];
                    float m = (e / denom > thr[f]) ? 1.0f : 0.0f;
                    float wer = wr + m * whr, wei = wi + m * whi;
                    float cf = ((f == 0) ? 1.0f : 2.0f) * INV_SQRT_N;
                    const unsigned short* Xrow = X + ((size_t)(b * F_ + f) * 2) * C_;
                    float Xr = bf2f(Xrow[c]), Xi = bf2f(Xrow[C_ + c]);
                    float Zr = (Xr * wer - Xi * wei) * cf;
                    float Zi = (Xr * wei + Xi * wer) * cf;
#pragma unroll
                    for (int m2 = 0; m2 < 17; ++m2) {
                        int r = (s * m2) % 17;
                        vr[m2] += Zr * C17[r] - Zi * S17[r];
                        vi[m2] += Zr * S17[r] + Zi * C17[r];
                    }
                }
            }
        }
#pragma unroll
        for (int m2 = 0; m2 < 17; ++m2)
            stage[(m2 * 32 + cl) * 33 + klocal] =
                (unsigned)f2bf(vr[m2]) | ((unsigned)f2bf(vi[m2]) << 16);
    }
    __syncthreads();
    unsigned* vt32 = (unsigned*)vt;
    for (int r = tid; r < 544; r += 256) {
        int m2 = r >> 5, c2 = r & 31;
        size_t ubase = ((size_t)((b * 17 + m2) * 256 + ct * 32 + c2)) * 256 + kt * 32;
        const unsigned* srow = &stage[(m2 * 32 + c2) * 33];
#pragma unroll
        for (int g = 0; g < 8; ++g) {
            uint4 w;
            w.x = srow[g * 4]; w.y = srow[g * 4 + 1];
            w.z = srow[g * 4 + 2]; w.w = srow[g * 4 + 3];
            *(uint4*)(vt32 + ubase + g * 4) = w;
        }
    }
}

// ---------------------------------------------------------------------------
// Stage C v2: LDS-staged MFMA GEMM (m97 structure, BK=64).
// ---------------------------------------------------------------------------
__global__ __launch_bounds__(256) void k_stageC_v2(const short* __restrict__ vt,
                                                   const short* __restrict__ twA,
                                                   float* __restrict__ out) {
    int bid = (blockIdx.x & 7) * 272 + (blockIdx.x >> 3);
    int b = bid / 68, rem = bid % 68;
    int m2 = rem >> 2, mt = (rem >> 1) & 1, ct = rem & 1;

    int tid = threadIdx.x, lane = tid & 63, wid = tid >> 6;
    int wr = wid >> 1, wc = wid & 1;
    int l15 = lane & 15, lg = lane >> 4;
    int srow = lane >> 3, sch = lane & 7;      // staging: 8 rows x 8 chunks

    const short* vtb = vt + (size_t)((b * 17 + m2) * 256 + ct * 128) * Q_;

    __shared__ __align__(16) short lds[16384];   // A [128][64] | B [128][64]

    f32x4 acc[4][4];
#pragma unroll
    for (int rt = 0; rt < 4; ++rt)
#pragma unroll
        for (int nt = 0; nt < 4; ++nt) acc[rt][nt] = (f32x4){0.f, 0.f, 0.f, 0.f};

    for (int ks = 0; ks < 8; ++ks) {
        int q0 = ks * 64;
#pragma unroll
        for (int r = 0; r < 8; ++r) {
            int row = (r & 3) * 32 + wid * 8 + srow;           // 0..127
            int ch = sch ^ ((row >> 1) & 7);
            const short* g;
            if (r < 4) {
                int n = 17 * (mt * 128 + row) + m2;
                g = twA + (size_t)n * Q_ + q0 + ch * 8;
            } else {
                g = vtb + (size_t)row * Q_ + q0 + ch * 8;
            }
            gload16(g, &lds[(r * 4 + wid) * 512]);
        }
        __syncthreads();
        short8v a[2][4], bb[2][4];
#pragma unroll
        for (int rt = 0; rt < 4; ++rt) {
            int row = wr * 64 + rt * 16 + l15;
            int s = (row >> 1) & 7;
            a[0][rt] = *(const short8v*)&lds[(row * 8 + (lg ^ s)) * 8];
            a[1][rt] = *(const short8v*)&lds[(row * 8 + ((4 + lg) ^ s)) * 8];
        }
#pragma unroll
        for (int nt = 0; nt < 4; ++nt) {
            int row = wc * 64 + nt * 16 + l15;
            int s = (row >> 1) & 7;
            bb[0][nt] = *(const short8v*)&lds[8192 + (row * 8 + (lg ^ s)) * 8];
            bb[1][nt] = *(const short8v*)&lds[8192 + (row * 8 + ((4 + lg) ^ s)) * 8];
        }
#pragma unroll
        for (int kh = 0; kh < 2; ++kh)
#pragma unroll
            for (int rt = 0; rt < 4; ++rt)
#pragma unroll
                for (int nt = 0; nt < 4; ++nt)
                    acc[rt][nt] = __builtin_amdgcn_mfma_f32_16x16x32_bf16(
                        a[kh][rt], bb[kh][nt], acc[rt][nt], 0, 0, 0);
        __syncthreads();
    }

#pragma unroll
    for (int rt = 0; rt < 4; ++rt) {
#pragma unroll
        for (int jj = 0; jj < 4; ++jj) {
            int m1 = mt * 128 + wr * 64 + rt * 16 + lg * 4 + jj;
            if (m1 < N2_) {
                int n = 17 * m1 + m2;
                float* orow = out + ((size_t)b * N_ + n) * C_ + ct * 128 + wc * 64;
#pragma unroll
                for (int nt = 0; nt < 4; ++nt)
                    orow[nt * 16 + l15] = acc[rt][nt][jj];
            }
        }
    }
}

// ---------------------------------------------------------------------------
extern "C" void kernel_launch(void* const* d_in, const int* in_sizes, int n_in,
                              void* d_out, int out_size, void* d_ws, size_t ws_size,
                              hipStream_t stream) {
    const float* x   = (const float*)d_in[0];
    const float* cw  = (const float*)d_in[1];
    const float* cwh = (const float*)d_in[2];
    const float* thr = (const float*)d_in[3];
    float* out = (float*)d_out;

    // workspace (~219 MB), v_t aliases the dead y_t region:
    //   X     bf16 [B][F][2][C]          :  67,141,632
    //   SH    region (y_t | v_t):
    //     y_t  fp16 [B][9][256][512]     :  75,497,472
    //     v_t  bf16 [B][17][256][512]    : 142,606,336 (aliased at SH base)
    //   twA   bf16 [4352][512]           :   4,456,448
    //   twB   fp16 [17][256][512]        :   4,456,448
    //   energy f32 [B][F]                :     262,272
    //   med    f32 [B]                   :         128
    char* ws = (char*)d_ws;
    unsigned short* Xb    = (unsigned short*)ws;
    char* sh = ws + 67141632ull;
    unsigned short* yt    = (unsigned short*)sh;
    unsigned short* vtb   = (unsigned short*)sh;                 // alias
    char* tail = sh + 142606336ull;
    unsigned short* twA   = (unsigned short*)tail;
    unsigned short* twB   = (unsigned short*)(tail + 4456448ull);
    float* energy = (float*)(tail + 8912896ull);
    float* med    = (float*)(tail + 8912896ull + 262272ull);

    hipMemsetAsync(energy, 0, B_ * F_ * sizeof(float), stream);
    k_twfill<<<TWROWS, 256, 0, stream>>>(twA);
    k_twfillB<<<17 * 256, 256, 0, stream>>>(twB);
    k_stageA_t<<<B_ * 32, 256, 0, stream>>>(x, yt);
    k_stageB_v4<<<B_ * 68, 256, 0, stream>>>(yt, twB, Xb, energy);
    k_median<<<B_, 256, 0, stream>>>(energy, med);
    k_vbuild_t<<<B_ * 64, 256, 0, stream>>>(Xb, energy, med, thr, cw, cwh, vtb);
    k_stageC_v2<<<B_ * 68, 256, 0, stream>>>((const short*)vtb, (const short*)twA, out);
}

// Round 8
// 306.968 us; speedup vs baseline: 4.6916x; 1.0637x over previous
//
#include <hip/hip_runtime.h>
#include <math.h>
#include <float.h>

#define B_ 32
#define N_ 4097
#define C_ 256
#define F_ 2049
#define N2_ 241
#define Q_ 512                        // padded K (q = 2*n2 + p, zeros q>=482)
#define TWROWS 4352                   // stageC twiddle rows (m1-tail padded)
#define INV_SQRT_N 0.0156230927f      // 1/sqrt(4097)
#define W_N 0.0015336063f             // 2*pi/4097
#define W_17 0.36959913571644626f     // 2*pi/17

typedef __attribute__((ext_vector_type(8))) short short8v;
typedef _Float16 f16x8 __attribute__((ext_vector_type(8)));
typedef __attribute__((ext_vector_type(4))) float f32x4;

__device__ __forceinline__ float bf2f(unsigned short u) {
    return __uint_as_float(((unsigned)u) << 16);
}
__device__ __forceinline__ unsigned short f2bf(float v) {
    unsigned u = __float_as_uint(v);
    u += 0x7FFFu + ((u >> 16) & 1u);
    return (unsigned short)(u >> 16);
}
__device__ __forceinline__ unsigned short f2h(float v) {
    union { _Float16 h; unsigned short u; } cv;
    cv.h = (_Float16)v;               // v_cvt_f16_f32, RTN
    return cv.u;
}
__device__ __forceinline__ void gload16(const void* gptr, void* ldsptr) {
    __builtin_amdgcn_global_load_lds(
        (const __attribute__((address_space(1))) void*)gptr,
        (__attribute__((address_space(3))) void*)ldsptr,
        16, 0, 0);
}

// ---------------------------------------------------------------------------
// Fused Stage A + transpose: x[B][N][C] f32 -> y_t fp16 [b][j][c][q].
// 17-point real DFT accumulated in registers; per-j LDS transpose,
// packed (re,im) u32 writes, zero pad rows n2>240.
// grid 1024 = B*8(n2t)*4(ct); block 256 = 64 c x 4 row-groups of 8.
// ---------------------------------------------------------------------------
__global__ __launch_bounds__(256) void k_stageA_t(const float* __restrict__ x,
                                                  unsigned short* __restrict__ yt) {
    int bid = blockIdx.x;
    int b = bid >> 5; int rem = bid & 31;
    int n2t = rem >> 2, ct = rem & 3;
    int tid = threadIdx.x;
    int cl = tid & 63, sub = tid >> 6;
    int c = ct * 64 + cl;

    float C17[17], S17[17];
#pragma unroll
    for (int r = 0; r < 17; ++r) {
        float s, cth; sincosf(W_17 * (float)r, &s, &cth);
        C17[r] = cth; S17[r] = s;
    }

    float ar[9][8], ai[8][8];
#pragma unroll
    for (int k = 0; k < 9; ++k)
#pragma unroll
        for (int i = 0; i < 8; ++i) ar[k][i] = 0.f;
#pragma unroll
    for (int k = 0; k < 8; ++k)
#pragma unroll
        for (int i = 0; i < 8; ++i) ai[k][i] = 0.f;

    const float* xb = x + (size_t)b * N_ * C_ + c;
#pragma unroll
    for (int n1 = 0; n1 < 17; ++n1) {
        float xv[8];
#pragma unroll
        for (int i = 0; i < 8; ++i) {
            int n2 = n2t * 32 + sub * 8 + i;
            xv[i] = (n2 <= 240) ? xb[(size_t)(n1 * N2_ + n2) * C_] : 0.f;
        }
#pragma unroll
        for (int k1 = 0; k1 < 9; ++k1) {
            int r = (k1 * n1) % 17;       // compile-time after unroll
            float cc = C17[r], ss = S17[r];
#pragma unroll
            for (int i = 0; i < 8; ++i) {
                ar[k1][i] += xv[i] * cc;
                if (k1 > 0) ai[k1 - 1][i] += xv[i] * ss;
            }
        }
    }

    __shared__ float lre[32 * 65], lim[32 * 65];
    int c2 = tid >> 2, qg = tid & 3;
#pragma unroll
    for (int j = 0; j < 9; ++j) {
        __syncthreads();                  // protect previous j's reads
#pragma unroll
        for (int i = 0; i < 8; ++i) {
            int row = sub * 8 + i;
            lre[row * 65 + cl] = ar[j][i] * INV_SQRT_N;
            lim[row * 65 + cl] = (j > 0) ? (-ai[j - 1][i] * INV_SQRT_N) : 0.f;
        }
        __syncthreads();
        unsigned wh[8];
#pragma unroll
        for (int i = 0; i < 8; ++i) {
            int row = qg * 8 + i;
            float re = lre[row * 65 + c2], im = lim[row * 65 + c2];
            wh[i] = (unsigned)f2h(re) | ((unsigned)f2h(im) << 16);
        }
        size_t ubase = ((size_t)((b * 9 + j) * 256 + ct * 64 + c2)) * 256 + n2t * 32 + qg * 8;
        uint4 v0; v0.x = wh[0]; v0.y = wh[1]; v0.z = wh[2]; v0.w = wh[3];
        uint4 v1; v1.x = wh[4]; v1.y = wh[5]; v1.z = wh[6]; v1.w = wh[7];
        *(uint4*)((unsigned*)yt + ubase) = v0;
        *(uint4*)((unsigned*)yt + ubase + 4) = v1;
    }
}

// ---------------------------------------------------------------------------
// Fused twiddle fill: blocks [0, TWROWS) -> twA (bf16, stageC);
// blocks [TWROWS, TWROWS+17*256) -> twB (fp16, stageB).
// ---------------------------------------------------------------------------
__global__ __launch_bounds__(256) void k_twfill_all(unsigned short* __restrict__ twA,
                                                    unsigned short* __restrict__ twB) {
    int blk = blockIdx.x;
    if (blk < TWROWS) {
        int n = blk;                 // 0..4351
        int k2 = threadIdx.x;        // 0..255
        unsigned pack = 0u;
        if (n <= 4096 && k2 <= 240) {
            int rr = (n * k2) % N_;
            float s, cth; sincosf(W_N * (float)rr, &s, &cth);
            pack = (unsigned)f2bf(cth) | ((unsigned)f2bf(-s) << 16);
        }
        *(unsigned*)(twA + (size_t)n * Q_ + 2 * k2) = pack;
    } else {
        int idx = blk - TWROWS;      // 0..4351
        int m = idx & 255; int k1 = idx >> 8;
        int n2 = threadIdx.x;
        int t = m >> 1, r = m & 1;
        int f = k1 + 17 * t;
        unsigned ph = 0u;
        if (t <= 120 && f < F_ && n2 <= 240) {
            float s_ = (k1 <= 8) ? 1.f : -1.f;
            int rr = (f * n2) % N_;
            float sn, cs; sincosf(W_N * (float)rr, &sn, &cs);
            float a0 = (r == 0) ? cs : -sn;
            float a1 = (r == 0) ? s_ * sn : s_ * cs;
            ph = (unsigned)f2h(a0) | ((unsigned)f2h(a1) << 16);
        }
        size_t ub = ((size_t)(k1 * 256 + m)) * 256 + n2;
        *((unsigned*)twB + ub) = ph;
    }
}

// ---------------------------------------------------------------------------
// Stage B v4: LDS-staged single-pass fp16 MFMA GEMM.
// Per (b,j,k1,mh,ct): OUT[m][c] = sum_q twB[k1][mh*128+m][q] * y_t[b][j][c][q].
// Tile 128(m) x 128(c), BK=64, 4 waves 2x2.  Staging via global_load_lds w16,
// source-side XOR swizzle chunk ^= (row>>1)&7.
// Energy: block-partial (128 c) reduce + atomicAdd (2 deterministic terms).
// grid 2176 = B*68, chunk-swizzled.
// ---------------------------------------------------------------------------
__global__ __launch_bounds__(256) void k_stageB_v4(
        const unsigned short* __restrict__ yt, const unsigned short* __restrict__ twb,
        unsigned short* __restrict__ X, float* __restrict__ energy) {
    int bid = (blockIdx.x & 7) * 272 + (blockIdx.x >> 3);   // 2176 = 8*272
    int b = bid / 68, rem = bid % 68;
    int j, mt, ct;
    if (rem < 4) { j = 0; mt = rem >> 1; ct = rem & 1; }
    else { int r2 = rem - 4; j = 1 + (r2 >> 3); int sub = r2 & 7; mt = sub >> 1; ct = sub & 1; }
    int k1 = (mt < 2) ? j : 17 - j;
    int mh = mt & 1;
    const unsigned short* pA = twb + (size_t)(k1 * 256 + mh * 128) * Q_;
    const unsigned short* pB = yt + (size_t)((b * 9 + j) * 256 + ct * 128) * Q_;

    int tid = threadIdx.x, lane = tid & 63, wid = tid >> 6;
    int wr = wid >> 1, wc = wid & 1;
    int l15 = lane & 15, lg = lane >> 4;
    int srow = lane >> 3, sch = lane & 7;      // staging: 8 rows x 8 chunks of 16B

    __shared__ __align__(16) unsigned short lds[16384];  // A [128][64] | B [128][64]
    __shared__ float eL[2][2][4][4][2];

    f32x4 acc[4][4];
#pragma unroll
    for (int rt = 0; rt < 4; ++rt)
#pragma unroll
        for (int nt = 0; nt < 4; ++nt) acc[rt][nt] = (f32x4){0.f, 0.f, 0.f, 0.f};

    for (int ks = 0; ks < 8; ++ks) {
        int q0 = ks * 64;
        // ---- stage 32 KB: 8 wave-rounds (r<4 -> A, else B) ----
#pragma unroll
        for (int r = 0; r < 8; ++r) {
            int row = (r & 3) * 32 + wid * 8 + srow;           // 0..127
            int ch = sch ^ ((row >> 1) & 7);
            const unsigned short* g = (r < 4) ? (pA + (size_t)row * Q_ + q0 + ch * 8)
                                              : (pB + (size_t)row * Q_ + q0 + ch * 8);
            gload16(g, &lds[(r * 4 + wid) * 512]);
        }
        __syncthreads();
        // ---- fragments + MFMA (2 k-slices) ----
        f16x8 a[2][4], bb[2][4];
#pragma unroll
        for (int rt = 0; rt < 4; ++rt) {
            int row = wr * 64 + rt * 16 + l15;
            int s = (row >> 1) & 7;
            a[0][rt] = *(const f16x8*)&lds[(row * 8 + (lg ^ s)) * 8];
            a[1][rt] = *(const f16x8*)&lds[(row * 8 + ((4 + lg) ^ s)) * 8];
        }
#pragma unroll
        for (int nt = 0; nt < 4; ++nt) {
            int row = wc * 64 + nt * 16 + l15;
            int s = (row >> 1) & 7;
            bb[0][nt] = *(const f16x8*)&lds[8192 + (row * 8 + (lg ^ s)) * 8];
            bb[1][nt] = *(const f16x8*)&lds[8192 + (row * 8 + ((4 + lg) ^ s)) * 8];
        }
#pragma unroll
        for (int kh = 0; kh < 2; ++kh)
#pragma unroll
            for (int rt = 0; rt < 4; ++rt)
#pragma unroll
                for (int nt = 0; nt < 4; ++nt)
                    acc[rt][nt] = __builtin_amdgcn_mfma_f32_16x16x32_f16(
                        a[kh][rt], bb[kh][nt], acc[rt][nt], 0, 0, 0);
        __syncthreads();
    }

    // ---- energy: partial sum over this block's 128 c, atomicAdd ----
#pragma unroll
    for (int rt = 0; rt < 4; ++rt) {
        float e0 = 0.f, e1 = 0.f;
#pragma unroll
        for (int nt = 0; nt < 4; ++nt) {
            e0 += acc[rt][nt][0] * acc[rt][nt][0] + acc[rt][nt][1] * acc[rt][nt][1];
            e1 += acc[rt][nt][2] * acc[rt][nt][2] + acc[rt][nt][3] * acc[rt][nt][3];
        }
#pragma unroll
        for (int off = 1; off < 16; off <<= 1) {
            e0 += __shfl_xor(e0, off, 64);
            e1 += __shfl_xor(e1, off, 64);
        }
        if (l15 == 0) { eL[wr][wc][rt][lg][0] = e0; eL[wr][wc][rt][lg][1] = e1; }
    }
    __syncthreads();
    if (tid < 64) {
        int wr2 = tid >> 5, rt2 = (tid >> 3) & 3, lg2 = (tid >> 1) & 3, pr = tid & 1;
        int mrow = mh * 128 + wr2 * 64 + rt2 * 16 + lg2 * 4 + pr * 2;
        int f = k1 + 17 * (mrow >> 1);
        if (f < F_) {
            float e = eL[wr2][0][rt2][lg2][pr] + eL[wr2][1][rt2][lg2][pr];
            atomicAdd(&energy[b * F_ + f], e);
        }
    }

    // ---- X store (bf16) ----
#pragma unroll
    for (int rt = 0; rt < 4; ++rt) {
#pragma unroll
        for (int jj = 0; jj < 4; ++jj) {
            int mrow = mh * 128 + wr * 64 + rt * 16 + lg * 4 + jj;
            int t = mrow >> 1, p = mrow & 1;
            int f = k1 + 17 * t;
            if (f < F_) {
                size_t base = ((size_t)((b * F_ + f) * 2 + p)) * C_ + ct * 128 + wc * 64 + l15;
#pragma unroll
                for (int nt = 0; nt < 4; ++nt)
                    X[base + nt * 16] = f2bf(acc[rt][nt][jj]);
            }
        }
    }
}

// ---------------------------------------------------------------------------
// Median per batch via exact 4-pass radix select (energies >= 0 so uint order
// == float order).  rank 1024 of 2049 == np.sort(...)[1024], bit-exact.
// ---------------------------------------------------------------------------
__global__ __launch_bounds__(256) void k_median(const float* __restrict__ energy,
                                                float* __restrict__ med) {
    int b = blockIdx.x, tid = threadIdx.x;
    __shared__ unsigned vals[F_];
    __shared__ unsigned hist[256];
    __shared__ unsigned scanbuf[256];
    __shared__ unsigned sh_prefix;
    __shared__ int sh_rank;
    for (int i = tid; i < F_; i += 256)
        vals[i] = __float_as_uint(energy[b * F_ + i]);
    if (tid == 0) { sh_prefix = 0u; sh_rank = 1024; }
    __syncthreads();
#pragma unroll
    for (int shift = 24; shift >= 0; shift -= 8) {
        hist[tid] = 0u;
        __syncthreads();
        unsigned prefix = sh_prefix;
        unsigned hmask = (shift == 24) ? 0u : (0xFFFFFFFFu << (shift + 8));
        for (int i = tid; i < F_; i += 256) {
            unsigned v = vals[i];
            if (((v ^ prefix) & hmask) == 0u)
                atomicAdd(&hist[(v >> shift) & 255], 1u);
        }
        __syncthreads();
        scanbuf[tid] = hist[tid];
        __syncthreads();
#pragma unroll
        for (int off = 1; off < 256; off <<= 1) {
            unsigned y = (tid >= off) ? scanbuf[tid - off] : 0u;
            __syncthreads();
            scanbuf[tid] += y;
            __syncthreads();
        }
        int rank = sh_rank;
        unsigned cumP = (tid == 0) ? 0u : scanbuf[tid - 1];
        unsigned cumI = scanbuf[tid];
        __syncthreads();
        if ((unsigned)rank >= cumP && (unsigned)rank < cumI) {
            sh_prefix = prefix | ((unsigned)tid << shift);
            sh_rank = rank - (int)cumP;
        }
        __syncthreads();
    }
    if (tid == 0) med[b] = __uint_as_float(sh_prefix);
}

// ---------------------------------------------------------------------------
// vbuild (tiled, 16-k2 tiles for 4 blocks/CU occupancy): mask + weights +
// inverse inner 17-point stage.
//   Z[f] = X[f]*(w + m*wh) * (f==0?1:2)/sqrt(N)
//   v[k2,m2] = sum_s Z[k2+241 s] * e^{+2pi i s m2/17}
// Output v_t[b][m2][c][q=2k2+p] bf16 (stride Q_), coalesced via LDS staging.
// grid 4096 = B*16(kt)*8(ct); block 256 = 32 c x 8 k2-groups, 2 k2-iters.
// ---------------------------------------------------------------------------
__global__ __launch_bounds__(256) void k_vbuild_t(
        const unsigned short* __restrict__ X, const float* __restrict__ energy,
        const float* __restrict__ med, const float* __restrict__ thr,
        const float* __restrict__ cw, const float* __restrict__ cwh,
        unsigned short* __restrict__ vt) {
    int bid = blockIdx.x;            // 32*16*8 = 4096
    int b = bid >> 7; int rem = bid & 127;
    int kt = rem >> 3, ct = rem & 7;
    int tid = threadIdx.x;
    int cl = tid & 31, ks = tid >> 5;
    int c = ct * 32 + cl;

    __shared__ unsigned stage[17 * 32 * 17];   // [m2][cl][klocal(16) pad->17] ~37KB

    float wr = cw[2 * c], wi = cw[2 * c + 1];
    float whr = cwh[2 * c], whi = cwh[2 * c + 1];
    float denom = med[b] + 1e-6f;

    float C17[17], S17[17];
#pragma unroll
    for (int r = 0; r < 17; ++r) {
        float s, cth; sincosf(W_17 * (float)r, &s, &cth);
        C17[r] = cth; S17[r] = s;
    }

#pragma unroll
    for (int kk = 0; kk < 2; ++kk) {
        int klocal = kk * 8 + ks;
        int k2 = kt * 16 + klocal;
        float vr[17], vi[17];
#pragma unroll
        for (int m = 0; m < 17; ++m) { vr[m] = 0.f; vi[m] = 0.f; }
        if (k2 <= 240) {
#pragma unroll
            for (int s = 0; s < 9; ++s) {
                int f = k2 + 241 * s;
                if (f < F_) {
                    float e = energy[b * F_ + f];
                    float m = (e / denom > thr[f]) ? 1.0f : 0.0f;
                    float wer = wr + m * whr, wei = wi + m * whi;
                    float cf = ((f == 0) ? 1.0f : 2.0f) * INV_SQRT_N;
                    const unsigned short* Xrow = X + ((size_t)(b * F_ + f) * 2) * C_;
                    float Xr = bf2f(Xrow[c]), Xi = bf2f(Xrow[C_ + c]);
                    float Zr = (Xr * wer - Xi * wei) * cf;
                    float Zi = (Xr * wei + Xi * wer) * cf;
#pragma unroll
                    for (int m2 = 0; m2 < 17; ++m2) {
                        int r = (s * m2) % 17;
                        vr[m2] += Zr * C17[r] - Zi * S17[r];
                        vi[m2] += Zr * S17[r] + Zi * C17[r];
                    }
                }
            }
        }
#pragma unroll
        for (int m2 = 0; m2 < 17; ++m2)
            stage[(m2 * 32 + cl) * 17 + klocal] =
                (unsigned)f2bf(vr[m2]) | ((unsigned)f2bf(vi[m2]) << 16);
    }
    __syncthreads();
    unsigned* vt32 = (unsigned*)vt;
    for (int r = tid; r < 544; r += 256) {
        int m2 = r >> 5, c2 = r & 31;
        size_t ubase = ((size_t)((b * 17 + m2) * 256 + ct * 32 + c2)) * 256 + kt * 16;
        const unsigned* srow = &stage[(m2 * 32 + c2) * 17];
#pragma unroll
        for (int g = 0; g < 4; ++g) {
            uint4 w;
            w.x = srow[g * 4]; w.y = srow[g * 4 + 1];
            w.z = srow[g * 4 + 2]; w.w = srow[g * 4 + 3];
            *(uint4*)(vt32 + ubase + g * 4) = w;
        }
    }
}

// ---------------------------------------------------------------------------
// Stage C v2: LDS-staged MFMA GEMM (m97 structure, BK=64).
// ---------------------------------------------------------------------------
__global__ __launch_bounds__(256) void k_stageC_v2(const short* __restrict__ vt,
                                                   const short* __restrict__ twA,
                                                   float* __restrict__ out) {
    int bid = (blockIdx.x & 7) * 272 + (blockIdx.x >> 3);
    int b = bid / 68, rem = bid % 68;
    int m2 = rem >> 2, mt = (rem >> 1) & 1, ct = rem & 1;

    int tid = threadIdx.x, lane = tid & 63, wid = tid >> 6;
    int wr = wid >> 1, wc = wid & 1;
    int l15 = lane & 15, lg = lane >> 4;
    int srow = lane >> 3, sch = lane & 7;      // staging: 8 rows x 8 chunks

    const short* vtb = vt + (size_t)((b * 17 + m2) * 256 + ct * 128) * Q_;

    __shared__ __align__(16) short lds[16384];   // A [128][64] | B [128][64]

    f32x4 acc[4][4];
#pragma unroll
    for (int rt = 0; rt < 4; ++rt)
#pragma unroll
        for (int nt = 0; nt < 4; ++nt) acc[rt][nt] = (f32x4){0.f, 0.f, 0.f, 0.f};

    for (int ks = 0; ks < 8; ++ks) {
        int q0 = ks * 64;
#pragma unroll
        for (int r = 0; r < 8; ++r) {
            int row = (r & 3) * 32 + wid * 8 + srow;           // 0..127
            int ch = sch ^ ((row >> 1) & 7);
            const short* g;
            if (r < 4) {
                int n = 17 * (mt * 128 + row) + m2;
                g = twA + (size_t)n * Q_ + q0 + ch * 8;
            } else {
                g = vtb + (size_t)row * Q_ + q0 + ch * 8;
            }
            gload16(g, &lds[(r * 4 + wid) * 512]);
        }
        __syncthreads();
        short8v a[2][4], bb[2][4];
#pragma unroll
        for (int rt = 0; rt < 4; ++rt) {
            int row = wr * 64 + rt * 16 + l15;
            int s = (row >> 1) & 7;
            a[0][rt] = *(const short8v*)&lds[(row * 8 + (lg ^ s)) * 8];
            a[1][rt] = *(const short8v*)&lds[(row * 8 + ((4 + lg) ^ s)) * 8];
        }
#pragma unroll
        for (int nt = 0; nt < 4; ++nt) {
            int row = wc * 64 + nt * 16 + l15;
            int s = (row >> 1) & 7;
            bb[0][nt] = *(const short8v*)&lds[8192 + (row * 8 + (lg ^ s)) * 8];
            bb[1][nt] = *(const short8v*)&lds[8192 + (row * 8 + ((4 + lg) ^ s)) * 8];
        }
#pragma unroll
        for (int kh = 0; kh < 2; ++kh)
#pragma unroll
            for (int rt = 0; rt < 4; ++rt)
#pragma unroll
                for (int nt = 0; nt < 4; ++nt)
                    acc[rt][nt] = __builtin_amdgcn_mfma_f32_16x16x32_bf16(
                        a[kh][rt], bb[kh][nt], acc[rt][nt], 0, 0, 0);
        __syncthreads();
    }

#pragma unroll
    for (int rt = 0; rt < 4; ++rt) {
#pragma unroll
        for (int jj = 0; jj < 4; ++jj) {
            int m1 = mt * 128 + wr * 64 + rt * 16 + lg * 4 + jj;
            if (m1 < N2_) {
                int n = 17 * m1 + m2;
                float* orow = out + ((size_t)b * N_ + n) * C_ + ct * 128 + wc * 64;
#pragma unroll
                for (int nt = 0; nt < 4; ++nt)
                    orow[nt * 16 + l15] = acc[rt][nt][jj];
            }
        }
    }
}

// ---------------------------------------------------------------------------
extern "C" void kernel_launch(void* const* d_in, const int* in_sizes, int n_in,
                              void* d_out, int out_size, void* d_ws, size_t ws_size,
                              hipStream_t stream) {
    const float* x   = (const float*)d_in[0];
    const float* cw  = (const float*)d_in[1];
    const float* cwh = (const float*)d_in[2];
    const float* thr = (const float*)d_in[3];
    float* out = (float*)d_out;

    // workspace (~219 MB), v_t aliases the dead y_t region:
    //   X     bf16 [B][F][2][C]          :  67,141,632
    //   SH    region (y_t | v_t):
    //     y_t  fp16 [B][9][256][512]     :  75,497,472
    //     v_t  bf16 [B][17][256][512]    : 142,606,336 (aliased at SH base)
    //   twA   bf16 [4352][512]           :   4,456,448
    //   twB   fp16 [17][256][512]        :   4,456,448
    //   energy f32 [B][F]                :     262,272
    //   med    f32 [B]                   :         128
    char* ws = (char*)d_ws;
    unsigned short* Xb    = (unsigned short*)ws;
    char* sh = ws + 67141632ull;
    unsigned short* yt    = (unsigned short*)sh;
    unsigned short* vtb   = (unsigned short*)sh;                 // alias
    char* tail = sh + 142606336ull;
    unsigned short* twA   = (unsigned short*)tail;
    unsigned short* twB   = (unsigned short*)(tail + 4456448ull);
    float* energy = (float*)(tail + 8912896ull);
    float* med    = (float*)(tail + 8912896ull + 262272ull);

    hipMemsetAsync(energy, 0, B_ * F_ * sizeof(float), stream);
    k_twfill_all<<<TWROWS + 17 * 256, 256, 0, stream>>>(twA, twB);
    k_stageA_t<<<B_ * 32, 256, 0, stream>>>(x, yt);
    k_stageB_v4<<<B_ * 68, 256, 0, stream>>>(yt, twB, Xb, energy);
    k_median<<<B_, 256, 0, stream>>>(energy, med);
    k_vbuild_t<<<B_ * 128, 256, 0, stream>>>(Xb, energy, med, thr, cw, cwh, vtb);
    k_stageC_v2<<<B_ * 68, 256, 0, stream>>>((const short*)vtb, (const short*)twA, out);
}

// Round 9
// 302.957 us; speedup vs baseline: 4.7537x; 1.0132x over previous
//
#include <hip/hip_runtime.h>
#include <math.h>
#include <float.h>

#define B_ 32
#define N_ 4097
#define C_ 256
#define F_ 2049
#define N2_ 241
#define Q_ 512                        // padded K (q = 2*n2 + p, zeros q>=482)
#define TWROWS 4352                   // stageC twiddle rows (m1-tail padded)
#define INV_SQRT_N 0.0156230927f      // 1/sqrt(4097)
#define W_N 0.0015336063f             // 2*pi/4097
#define W_17 0.36959913571644626f     // 2*pi/17

typedef __attribute__((ext_vector_type(8))) short short8v;
typedef _Float16 f16x8 __attribute__((ext_vector_type(8)));
typedef __attribute__((ext_vector_type(4))) float f32x4;

__device__ __forceinline__ float bf2f(unsigned short u) {
    return __uint_as_float(((unsigned)u) << 16);
}
__device__ __forceinline__ unsigned short f2bf(float v) {
    unsigned u = __float_as_uint(v);
    u += 0x7FFFu + ((u >> 16) & 1u);
    return (unsigned short)(u >> 16);
}
__device__ __forceinline__ unsigned short f2h(float v) {
    union { _Float16 h; unsigned short u; } cv;
    cv.h = (_Float16)v;               // v_cvt_f16_f32, RTN
    return cv.u;
}
__device__ __forceinline__ void gload16(const void* gptr, void* ldsptr) {
    __builtin_amdgcn_global_load_lds(
        (const __attribute__((address_space(1))) void*)gptr,
        (__attribute__((address_space(3))) void*)ldsptr,
        16, 0, 0);
}

// ---------------------------------------------------------------------------
// Fused Stage A + transpose: x[B][N][C] f32 -> y_t fp16 [b][j][c][q].
// ---------------------------------------------------------------------------
__global__ __launch_bounds__(256) void k_stageA_t(const float* __restrict__ x,
                                                  unsigned short* __restrict__ yt) {
    int bid = blockIdx.x;
    int b = bid >> 5; int rem = bid & 31;
    int n2t = rem >> 2, ct = rem & 3;
    int tid = threadIdx.x;
    int cl = tid & 63, sub = tid >> 6;
    int c = ct * 64 + cl;

    float C17[17], S17[17];
#pragma unroll
    for (int r = 0; r < 17; ++r) {
        float s, cth; sincosf(W_17 * (float)r, &s, &cth);
        C17[r] = cth; S17[r] = s;
    }

    float ar[9][8], ai[8][8];
#pragma unroll
    for (int k = 0; k < 9; ++k)
#pragma unroll
        for (int i = 0; i < 8; ++i) ar[k][i] = 0.f;
#pragma unroll
    for (int k = 0; k < 8; ++k)
#pragma unroll
        for (int i = 0; i < 8; ++i) ai[k][i] = 0.f;

    const float* xb = x + (size_t)b * N_ * C_ + c;
#pragma unroll
    for (int n1 = 0; n1 < 17; ++n1) {
        float xv[8];
#pragma unroll
        for (int i = 0; i < 8; ++i) {
            int n2 = n2t * 32 + sub * 8 + i;
            xv[i] = (n2 <= 240) ? xb[(size_t)(n1 * N2_ + n2) * C_] : 0.f;
        }
#pragma unroll
        for (int k1 = 0; k1 < 9; ++k1) {
            int r = (k1 * n1) % 17;       // compile-time after unroll
            float cc = C17[r], ss = S17[r];
#pragma unroll
            for (int i = 0; i < 8; ++i) {
                ar[k1][i] += xv[i] * cc;
                if (k1 > 0) ai[k1 - 1][i] += xv[i] * ss;
            }
        }
    }

    __shared__ float lre[32 * 65], lim[32 * 65];
    int c2 = tid >> 2, qg = tid & 3;
#pragma unroll
    for (int j = 0; j < 9; ++j) {
        __syncthreads();                  // protect previous j's reads
#pragma unroll
        for (int i = 0; i < 8; ++i) {
            int row = sub * 8 + i;
            lre[row * 65 + cl] = ar[j][i] * INV_SQRT_N;
            lim[row * 65 + cl] = (j > 0) ? (-ai[j - 1][i] * INV_SQRT_N) : 0.f;
        }
        __syncthreads();
        unsigned wh[8];
#pragma unroll
        for (int i = 0; i < 8; ++i) {
            int row = qg * 8 + i;
            float re = lre[row * 65 + c2], im = lim[row * 65 + c2];
            wh[i] = (unsigned)f2h(re) | ((unsigned)f2h(im) << 16);
        }
        size_t ubase = ((size_t)((b * 9 + j) * 256 + ct * 64 + c2)) * 256 + n2t * 32 + qg * 8;
        uint4 v0; v0.x = wh[0]; v0.y = wh[1]; v0.z = wh[2]; v0.w = wh[3];
        uint4 v1; v1.x = wh[4]; v1.y = wh[5]; v1.z = wh[6]; v1.w = wh[7];
        *(uint4*)((unsigned*)yt + ubase) = v0;
        *(uint4*)((unsigned*)yt + ubase + 4) = v1;
    }
}

// ---------------------------------------------------------------------------
// Fused twiddle fill: blocks [0, TWROWS) -> twA (bf16, stageC);
// blocks [TWROWS, TWROWS+17*256) -> twB (fp16, stageB).
// ---------------------------------------------------------------------------
__global__ __launch_bounds__(256) void k_twfill_all(unsigned short* __restrict__ twA,
                                                    unsigned short* __restrict__ twB) {
    int blk = blockIdx.x;
    if (blk < TWROWS) {
        int n = blk;                 // 0..4351
        int k2 = threadIdx.x;        // 0..255
        unsigned pack = 0u;
        if (n <= 4096 && k2 <= 240) {
            int rr = (n * k2) % N_;
            float s, cth; sincosf(W_N * (float)rr, &s, &cth);
            pack = (unsigned)f2bf(cth) | ((unsigned)f2bf(-s) << 16);
        }
        *(unsigned*)(twA + (size_t)n * Q_ + 2 * k2) = pack;
    } else {
        int idx = blk - TWROWS;      // 0..4351
        int m = idx & 255; int k1 = idx >> 8;
        int n2 = threadIdx.x;
        int t = m >> 1, r = m & 1;
        int f = k1 + 17 * t;
        unsigned ph = 0u;
        if (t <= 120 && f < F_ && n2 <= 240) {
            float s_ = (k1 <= 8) ? 1.f : -1.f;
            int rr = (f * n2) % N_;
            float sn, cs; sincosf(W_N * (float)rr, &sn, &cs);
            float a0 = (r == 0) ? cs : -sn;
            float a1 = (r == 0) ? s_ * sn : s_ * cs;
            ph = (unsigned)f2h(a0) | ((unsigned)f2h(a1) << 16);
        }
        size_t ub = ((size_t)(k1 * 256 + m)) * 256 + n2;
        *((unsigned*)twB + ub) = ph;
    }
}

// ---------------------------------------------------------------------------
// Stage B v5: double-buffered fp16 MFMA GEMM (T3 minimum-2-phase).
// Per (b,j,k1,mh,ct): OUT[m][c] = sum_q twB[k1][mh*128+m][q] * y_t[b][j][c][q].
// Tile 128x128, BK=32, lds[2][8KB]; next tile's global_load_lds issued BEFORE
// current tile's MFMA -> loads in flight across the compute phase; one barrier
// per K-step (compiler's vmcnt(0)-before-s_barrier is the producer wait).
// grid 2176 = B*68, chunk-swizzled.
// ---------------------------------------------------------------------------
__global__ __launch_bounds__(256) void k_stageB_v5(
        const unsigned short* __restrict__ yt, const unsigned short* __restrict__ twb,
        unsigned short* __restrict__ X, float* __restrict__ energy) {
    int bid = (blockIdx.x & 7) * 272 + (blockIdx.x >> 3);   // 2176 = 8*272
    int b = bid / 68, rem = bid % 68;
    int j, mt, ct;
    if (rem < 4) { j = 0; mt = rem >> 1; ct = rem & 1; }
    else { int r2 = rem - 4; j = 1 + (r2 >> 3); int sub = r2 & 7; mt = sub >> 1; ct = sub & 1; }
    int k1 = (mt < 2) ? j : 17 - j;
    int mh = mt & 1;
    const unsigned short* pA = twb + (size_t)(k1 * 256 + mh * 128) * Q_;
    const unsigned short* pB = yt + (size_t)((b * 9 + j) * 256 + ct * 128) * Q_;

    int tid = threadIdx.x, lane = tid & 63, wid = tid >> 6;
    int wr = wid >> 1, wc = wid & 1;
    int l15 = lane & 15, lg = lane >> 4;
    int srow = lane >> 2, sch = lane & 3;      // staging: 16 rows x 4 chunks of 16B

    __shared__ __align__(16) unsigned short lds[2][8192];  // A[128][32] | B[128][32]
    __shared__ float eL[2][2][4][4][2];

    // per-round global sources (q0 added later); round r: r<2 -> A, else B
    const unsigned short* gsrc[4];
#pragma unroll
    for (int r = 0; r < 4; ++r) {
        int row = (r & 1) * 64 + wid * 16 + srow;
        int ch = sch ^ ((row >> 1) & 3);
        gsrc[r] = ((r < 2) ? pA : pB) + (size_t)row * Q_ + ch * 8;
    }
    // fragment LDS offsets (shorts, within one buffer)
    int aoff[4], boff[4];
#pragma unroll
    for (int rt = 0; rt < 4; ++rt) {
        int row = wr * 64 + rt * 16 + l15;
        aoff[rt] = row * 32 + (lg ^ ((row >> 1) & 3)) * 8;
    }
#pragma unroll
    for (int nt = 0; nt < 4; ++nt) {
        int row = wc * 64 + nt * 16 + l15;
        boff[nt] = 4096 + row * 32 + (lg ^ ((row >> 1) & 3)) * 8;
    }

    f32x4 acc[4][4];
#pragma unroll
    for (int rt = 0; rt < 4; ++rt)
#pragma unroll
        for (int nt = 0; nt < 4; ++nt) acc[rt][nt] = (f32x4){0.f, 0.f, 0.f, 0.f};

#define STAGE_B(bufi, q0) do {                                      \
        gload16(gsrc[0] + (q0), &lds[bufi][wid * 512]);             \
        gload16(gsrc[1] + (q0), &lds[bufi][2048 + wid * 512]);      \
        gload16(gsrc[2] + (q0), &lds[bufi][4096 + wid * 512]);      \
        gload16(gsrc[3] + (q0), &lds[bufi][6144 + wid * 512]);      \
    } while (0)

#define COMP_B(bufi) do {                                           \
        f16x8 a_[4], b_[4];                                         \
        _Pragma("unroll")                                           \
        for (int rt = 0; rt < 4; ++rt)                              \
            a_[rt] = *(const f16x8*)&lds[bufi][aoff[rt]];           \
        _Pragma("unroll")                                           \
        for (int nt = 0; nt < 4; ++nt)                              \
            b_[nt] = *(const f16x8*)&lds[bufi][boff[nt]];           \
        _Pragma("unroll")                                           \
        for (int rt = 0; rt < 4; ++rt)                              \
            _Pragma("unroll")                                       \
            for (int nt = 0; nt < 4; ++nt)                          \
                acc[rt][nt] = __builtin_amdgcn_mfma_f32_16x16x32_f16( \
                    a_[rt], b_[nt], acc[rt][nt], 0, 0, 0);          \
    } while (0)

    STAGE_B(0, 0);
    __syncthreads();
    for (int ks = 0; ks < 16; ks += 2) {
        STAGE_B(1, (ks + 1) * 32);      // ks <= 14 so ks+1 <= 15 always valid
        COMP_B(0);
        __syncthreads();
        if (ks + 2 < 16) STAGE_B(0, (ks + 2) * 32);
        COMP_B(1);
        __syncthreads();
    }
#undef STAGE_B
#undef COMP_B

    // ---- energy: partial sum over this block's 128 c, atomicAdd ----
#pragma unroll
    for (int rt = 0; rt < 4; ++rt) {
        float e0 = 0.f, e1 = 0.f;
#pragma unroll
        for (int nt = 0; nt < 4; ++nt) {
            e0 += acc[rt][nt][0] * acc[rt][nt][0] + acc[rt][nt][1] * acc[rt][nt][1];
            e1 += acc[rt][nt][2] * acc[rt][nt][2] + acc[rt][nt][3] * acc[rt][nt][3];
        }
#pragma unroll
        for (int off = 1; off < 16; off <<= 1) {
            e0 += __shfl_xor(e0, off, 64);
            e1 += __shfl_xor(e1, off, 64);
        }
        if (l15 == 0) { eL[wr][wc][rt][lg][0] = e0; eL[wr][wc][rt][lg][1] = e1; }
    }
    __syncthreads();
    if (tid < 64) {
        int wr2 = tid >> 5, rt2 = (tid >> 3) & 3, lg2 = (tid >> 1) & 3, pr = tid & 1;
        int mrow = mh * 128 + wr2 * 64 + rt2 * 16 + lg2 * 4 + pr * 2;
        int f = k1 + 17 * (mrow >> 1);
        if (f < F_) {
            float e = eL[wr2][0][rt2][lg2][pr] + eL[wr2][1][rt2][lg2][pr];
            atomicAdd(&energy[b * F_ + f], e);
        }
    }

    // ---- X store (bf16) ----
#pragma unroll
    for (int rt = 0; rt < 4; ++rt) {
#pragma unroll
        for (int jj = 0; jj < 4; ++jj) {
            int mrow = mh * 128 + wr * 64 + rt * 16 + lg * 4 + jj;
            int t = mrow >> 1, p = mrow & 1;
            int f = k1 + 17 * t;
            if (f < F_) {
                size_t base = ((size_t)((b * F_ + f) * 2 + p)) * C_ + ct * 128 + wc * 64 + l15;
#pragma unroll
                for (int nt = 0; nt < 4; ++nt)
                    X[base + nt * 16] = f2bf(acc[rt][nt][jj]);
            }
        }
    }
}

// ---------------------------------------------------------------------------
// Median per batch via exact 4-pass radix select.
// ---------------------------------------------------------------------------
__global__ __launch_bounds__(256) void k_median(const float* __restrict__ energy,
                                                float* __restrict__ med) {
    int b = blockIdx.x, tid = threadIdx.x;
    __shared__ unsigned vals[F_];
    __shared__ unsigned hist[256];
    __shared__ unsigned scanbuf[256];
    __shared__ unsigned sh_prefix;
    __shared__ int sh_rank;
    for (int i = tid; i < F_; i += 256)
        vals[i] = __float_as_uint(energy[b * F_ + i]);
    if (tid == 0) { sh_prefix = 0u; sh_rank = 1024; }
    __syncthreads();
#pragma unroll
    for (int shift = 24; shift >= 0; shift -= 8) {
        hist[tid] = 0u;
        __syncthreads();
        unsigned prefix = sh_prefix;
        unsigned hmask = (shift == 24) ? 0u : (0xFFFFFFFFu << (shift + 8));
        for (int i = tid; i < F_; i += 256) {
            unsigned v = vals[i];
            if (((v ^ prefix) & hmask) == 0u)
                atomicAdd(&hist[(v >> shift) & 255], 1u);
        }
        __syncthreads();
        scanbuf[tid] = hist[tid];
        __syncthreads();
#pragma unroll
        for (int off = 1; off < 256; off <<= 1) {
            unsigned y = (tid >= off) ? scanbuf[tid - off] : 0u;
            __syncthreads();
            scanbuf[tid] += y;
            __syncthreads();
        }
        int rank = sh_rank;
        unsigned cumP = (tid == 0) ? 0u : scanbuf[tid - 1];
        unsigned cumI = scanbuf[tid];
        __syncthreads();
        if ((unsigned)rank >= cumP && (unsigned)rank < cumI) {
            sh_prefix = prefix | ((unsigned)tid << shift);
            sh_rank = rank - (int)cumP;
        }
        __syncthreads();
    }
    if (tid == 0) med[b] = __uint_as_float(sh_prefix);
}

// ---------------------------------------------------------------------------
// vbuild (tiled, 16-k2 tiles): mask + weights + inverse inner 17-point stage.
// ---------------------------------------------------------------------------
__global__ __launch_bounds__(256) void k_vbuild_t(
        const unsigned short* __restrict__ X, const float* __restrict__ energy,
        const float* __restrict__ med, const float* __restrict__ thr,
        const float* __restrict__ cw, const float* __restrict__ cwh,
        unsigned short* __restrict__ vt) {
    int bid = blockIdx.x;            // 32*16*8 = 4096
    int b = bid >> 7; int rem = bid & 127;
    int kt = rem >> 3, ct = rem & 7;
    int tid = threadIdx.x;
    int cl = tid & 31, ks = tid >> 5;
    int c = ct * 32 + cl;

    __shared__ unsigned stage[17 * 32 * 17];   // [m2][cl][klocal(16) pad->17] ~37KB

    float wr = cw[2 * c], wi = cw[2 * c + 1];
    float whr = cwh[2 * c], whi = cwh[2 * c + 1];
    float denom = med[b] + 1e-6f;

    float C17[17], S17[17];
#pragma unroll
    for (int r = 0; r < 17; ++r) {
        float s, cth; sincosf(W_17 * (float)r, &s, &cth);
        C17[r] = cth; S17[r] = s;
    }

#pragma unroll
    for (int kk = 0; kk < 2; ++kk) {
        int klocal = kk * 8 + ks;
        int k2 = kt * 16 + klocal;
        float vr[17], vi[17];
#pragma unroll
        for (int m = 0; m < 17; ++m) { vr[m] = 0.f; vi[m] = 0.f; }
        if (k2 <= 240) {
#pragma unroll
            for (int s = 0; s < 9; ++s) {
                int f = k2 + 241 * s;
                if (f < F_) {
                    float e = energy[b * F_ + f];
                    float m = (e / denom > thr[f]) ? 1.0f : 0.0f;
                    float wer = wr + m * whr, wei = wi + m * whi;
                    float cf = ((f == 0) ? 1.0f : 2.0f) * INV_SQRT_N;
                    const unsigned short* Xrow = X + ((size_t)(b * F_ + f) * 2) * C_;
                    float Xr = bf2f(Xrow[c]), Xi = bf2f(Xrow[C_ + c]);
                    float Zr = (Xr * wer - Xi * wei) * cf;
                    float Zi = (Xr * wei + Xi * wer) * cf;
#pragma unroll
                    for (int m2 = 0; m2 < 17; ++m2) {
                        int r = (s * m2) % 17;
                        vr[m2] += Zr * C17[r] - Zi * S17[r];
                        vi[m2] += Zr * S17[r] + Zi * C17[r];
                    }
                }
            }
        }
#pragma unroll
        for (int m2 = 0; m2 < 17; ++m2)
            stage[(m2 * 32 + cl) * 17 + klocal] =
                (unsigned)f2bf(vr[m2]) | ((unsigned)f2bf(vi[m2]) << 16);
    }
    __syncthreads();
    unsigned* vt32 = (unsigned*)vt;
    for (int r = tid; r < 544; r += 256) {
        int m2 = r >> 5, c2 = r & 31;
        size_t ubase = ((size_t)((b * 17 + m2) * 256 + ct * 32 + c2)) * 256 + kt * 16;
        const unsigned* srow = &stage[(m2 * 32 + c2) * 17];
#pragma unroll
        for (int g = 0; g < 4; ++g) {
            uint4 w;
            w.x = srow[g * 4]; w.y = srow[g * 4 + 1];
            w.z = srow[g * 4 + 2]; w.w = srow[g * 4 + 3];
            *(uint4*)(vt32 + ubase + g * 4) = w;
        }
    }
}

// ---------------------------------------------------------------------------
// Stage C v3: double-buffered bf16 MFMA GEMM (T3 minimum-2-phase, BK=32).
// Per (b,m2): OUT[m1][c] = sum_q twA[17*m1+m2][q] * v_t[b][m2][c][q].
// Same dbuf/one-barrier-per-step structure as stageB_v5; K-order identical to
// v2 (BK=32 sequential == BK=64 kh0,kh1) -> bit-identical output.
// grid 2176 = B*68, chunk-swizzled.
// ---------------------------------------------------------------------------
__global__ __launch_bounds__(256) void k_stageC_v3(const short* __restrict__ vt,
                                                   const short* __restrict__ twA,
                                                   float* __restrict__ out) {
    int bid = (blockIdx.x & 7) * 272 + (blockIdx.x >> 3);
    int b = bid / 68, rem = bid % 68;
    int m2 = rem >> 2, mt = (rem >> 1) & 1, ct = rem & 1;

    int tid = threadIdx.x, lane = tid & 63, wid = tid >> 6;
    int wr = wid >> 1, wc = wid & 1;
    int l15 = lane & 15, lg = lane >> 4;
    int srow = lane >> 2, sch = lane & 3;      // staging: 16 rows x 4 chunks of 16B

    const short* vtb = vt + (size_t)((b * 17 + m2) * 256 + ct * 128) * Q_;

    __shared__ __align__(16) short lds[2][8192];   // A[128][32] | B[128][32]

    const short* gsrc[4];
#pragma unroll
    for (int r = 0; r < 4; ++r) {
        int row = (r & 1) * 64 + wid * 16 + srow;
        int ch = sch ^ ((row >> 1) & 3);
        if (r < 2) {
            int n = 17 * (mt * 128 + row) + m2;
            gsrc[r] = twA + (size_t)n * Q_ + ch * 8;
        } else {
            gsrc[r] = vtb + (size_t)row * Q_ + ch * 8;
        }
    }
    int aoff[4], boff[4];
#pragma unroll
    for (int rt = 0; rt < 4; ++rt) {
        int row = wr * 64 + rt * 16 + l15;
        aoff[rt] = row * 32 + (lg ^ ((row >> 1) & 3)) * 8;
    }
#pragma unroll
    for (int nt = 0; nt < 4; ++nt) {
        int row = wc * 64 + nt * 16 + l15;
        boff[nt] = 4096 + row * 32 + (lg ^ ((row >> 1) & 3)) * 8;
    }

    f32x4 acc[4][4];
#pragma unroll
    for (int rt = 0; rt < 4; ++rt)
#pragma unroll
        for (int nt = 0; nt < 4; ++nt) acc[rt][nt] = (f32x4){0.f, 0.f, 0.f, 0.f};

#define STAGE_C(bufi, q0) do {                                      \
        gload16(gsrc[0] + (q0), &lds[bufi][wid * 512]);             \
        gload16(gsrc[1] + (q0), &lds[bufi][2048 + wid * 512]);      \
        gload16(gsrc[2] + (q0), &lds[bufi][4096 + wid * 512]);      \
        gload16(gsrc[3] + (q0), &lds[bufi][6144 + wid * 512]);      \
    } while (0)

#define COMP_C(bufi) do {                                           \
        short8v a_[4], b_[4];                                       \
        _Pragma("unroll")                                           \
        for (int rt = 0; rt < 4; ++rt)                              \
            a_[rt] = *(const short8v*)&lds[bufi][aoff[rt]];         \
        _Pragma("unroll")                                           \
        for (int nt = 0; nt < 4; ++nt)                              \
            b_[nt] = *(const short8v*)&lds[bufi][boff[nt]];         \
        _Pragma("unroll")                                           \
        for (int rt = 0; rt < 4; ++rt)                              \
            _Pragma("unroll")                                       \
            for (int nt = 0; nt < 4; ++nt)                          \
                acc[rt][nt] = __builtin_amdgcn_mfma_f32_16x16x32_bf16( \
                    a_[rt], b_[nt], acc[rt][nt], 0, 0, 0);          \
    } while (0)

    STAGE_C(0, 0);
    __syncthreads();
    for (int ks = 0; ks < 16; ks += 2) {
        STAGE_C(1, (ks + 1) * 32);
        COMP_C(0);
        __syncthreads();
        if (ks + 2 < 16) STAGE_C(0, (ks + 2) * 32);
        COMP_C(1);
        __syncthreads();
    }
#undef STAGE_C
#undef COMP_C

#pragma unroll
    for (int rt = 0; rt < 4; ++rt) {
#pragma unroll
        for (int jj = 0; jj < 4; ++jj) {
            int m1 = mt * 128 + wr * 64 + rt * 16 + lg * 4 + jj;
            if (m1 < N2_) {
                int n = 17 * m1 + m2;
                float* orow = out + ((size_t)b * N_ + n) * C_ + ct * 128 + wc * 64;
#pragma unroll
                for (int nt = 0; nt < 4; ++nt)
                    orow[nt * 16 + l15] = acc[rt][nt][jj];
            }
        }
    }
}

// ---------------------------------------------------------------------------
extern "C" void kernel_launch(void* const* d_in, const int* in_sizes, int n_in,
                              void* d_out, int out_size, void* d_ws, size_t ws_size,
                              hipStream_t stream) {
    const float* x   = (const float*)d_in[0];
    const float* cw  = (const float*)d_in[1];
    const float* cwh = (const float*)d_in[2];
    const float* thr = (const float*)d_in[3];
    float* out = (float*)d_out;

    // workspace (~219 MB), v_t aliases the dead y_t region:
    //   X     bf16 [B][F][2][C]          :  67,141,632
    //   SH    region (y_t | v_t):
    //     y_t  fp16 [B][9][256][512]     :  75,497,472
    //     v_t  bf16 [B][17][256][512]    : 142,606,336 (aliased at SH base)
    //   twA   bf16 [4352][512]           :   4,456,448
    //   twB   fp16 [17][256][512]        :   4,456,448
    //   energy f32 [B][F]                :     262,272
    //   med    f32 [B]                   :         128
    char* ws = (char*)d_ws;
    unsigned short* Xb    = (unsigned short*)ws;
    char* sh = ws + 67141632ull;
    unsigned short* yt    = (unsigned short*)sh;
    unsigned short* vtb   = (unsigned short*)sh;                 // alias
    char* tail = sh + 142606336ull;
    unsigned short* twA   = (unsigned short*)tail;
    unsigned short* twB   = (unsigned short*)(tail + 4456448ull);
    float* energy = (float*)(tail + 8912896ull);
    float* med    = (float*)(tail + 8912896ull + 262272ull);

    hipMemsetAsync(energy, 0, B_ * F_ * sizeof(float), stream);
    k_twfill_all<<<TWROWS + 17 * 256, 256, 0, stream>>>(twA, twB);
    k_stageA_t<<<B_ * 32, 256, 0, stream>>>(x, yt);
    k_stageB_v5<<<B_ * 68, 256, 0, stream>>>(yt, twB, Xb, energy);
    k_median<<<B_, 256, 0, stream>>>(energy, med);
    k_vbuild_t<<<B_ * 128, 256, 0, stream>>>(Xb, energy, med, thr, cw, cwh, vtb);
    k_stageC_v3<<<B_ * 68, 256, 0, stream>>>((const short*)vtb, (const short*)twA, out);
}